// Round 1
// baseline (546.660 us; speedup 1.0000x reference)
//
#include <hip/hip_runtime.h>
#include <math.h>

#define HW     65536
#define WIDTH  256
#define HEIGHT 256
#define CB     64
#define BB     8
#define PP     16

__device__ __forceinline__ float relu_f(float x){ return x > 0.f ? x : 0.f; }

// ---------------- K1: channel mean over C (edge_input) ----------------
__global__ __launch_bounds__(256) void k_chanmean(const float* __restrict__ feat,
                                                  float* __restrict__ edge_input){
    int gid = blockIdx.x * 256 + threadIdx.x;      // 0 .. B*HW-1
    int b = gid >> 16;
    int l = gid & 65535;
    const float* p = feat + ((size_t)b * CB) * HW + l;
    float s = 0.f;
    #pragma unroll
    for (int c = 0; c < CB; c++) s += p[(size_t)c * HW];
    edge_input[gid] = s * (1.f / 64.f);
}

// ---------------- K3: Sobel -> es, ori_x, ori_y + partial sums ----------------
__global__ __launch_bounds__(256) void k_sobel(const float* __restrict__ ei,
                                               float* __restrict__ es,
                                               float* __restrict__ ox,
                                               float* __restrict__ oy,
                                               float* __restrict__ part){
    int b = blockIdx.y, ch = blockIdx.x, t = threadIdx.x;
    const float* e = ei + (size_t)b * HW;
    float s1 = 0.f, s2 = 0.f;
    for (int i = 0; i < 4; i++){
        int l = ch * 1024 + i * 256 + t;
        int h = l >> 8, w = l & 255;
        float v[3][3];
        #pragma unroll
        for (int dh = -1; dh <= 1; dh++)
            #pragma unroll
            for (int dw = -1; dw <= 1; dw++){
                int hh = h + dh, ww = w + dw;
                v[dh+1][dw+1] = (hh >= 0 && hh < HEIGHT && ww >= 0 && ww < WIDTH)
                                ? e[hh * WIDTH + ww] : 0.f;
            }
        float gx = -v[0][0] + v[0][2] - 2.f*v[1][0] + 2.f*v[1][2] - v[2][0] + v[2][2];
        float gy = -v[0][0] - 2.f*v[0][1] - v[0][2] + v[2][0] + 2.f*v[2][1] + v[2][2];
        float g2 = gx*gx + gy*gy;
        float denom = g2 + 1e-6f;
        float esv = sqrtf(denom);
        size_t o = (size_t)b * HW + l;
        es[o] = esv;
        ox[o] = (gx*gx - gy*gy) / denom;
        oy[o] = 2.f * gx * gy / denom;
        s1 += esv; s2 += esv * esv;
    }
    __shared__ float r1[256], r2[256];
    r1[t] = s1; r2[t] = s2; __syncthreads();
    for (int s = 128; s > 0; s >>= 1){
        if (t < s){ r1[t] += r1[t+s]; r2[t] += r2[t+s]; }
        __syncthreads();
    }
    if (t == 0){ part[(b*64+ch)*2] = r1[0]; part[(b*64+ch)*2+1] = r2[0]; }
}

// ---------------- K3b: per-batch edge stats + normalized proto dirs ----------------
__global__ void k_stats(const float* __restrict__ part,
                        const float* __restrict__ proto_orient,
                        float* __restrict__ stats, float* __restrict__ pd){
    int t = threadIdx.x;
    if (t < 8){
        float s1 = 0.f, s2 = 0.f;
        for (int i = 0; i < 64; i++){ s1 += part[(t*64+i)*2]; s2 += part[(t*64+i)*2+1]; }
        float mean = s1 / 65536.f;
        float var  = (s2 - 65536.f * mean * mean) / 65535.f;
        var = var > 0.f ? var : 0.f;
        float sd = sqrtf(var);
        stats[t*4+0] = mean;
        stats[t*4+1] = 1.f / (sd + 1e-5f);
        stats[t*4+2] = 1.f / (mean + 1e-6f);
    }
    if (t >= 32 && t < 48){
        int p = t - 32;
        float nx = proto_orient[p*2], ny = proto_orient[p*2+1];
        float n = sqrtf(nx*nx + ny*ny);
        n = n > 1e-12f ? n : 1e-12f;
        pd[p*2] = nx / n; pd[p*2+1] = ny / n;
    }
}

// ---------------- K2: fused dw-conv+BN+ReLU -> 1x1+BN+ReLU -> affinity -> logits ----------------
__global__ __launch_bounds__(256) void k_conv_aff(
    const float* __restrict__ feat, const float* __restrict__ dw_w,
    const float* __restrict__ g1, const float* __restrict__ b1,
    const float* __restrict__ m1, const float* __restrict__ v1,
    const float* __restrict__ pw_w,
    const float* __restrict__ g2, const float* __restrict__ b2,
    const float* __restrict__ m2, const float* __restrict__ v2,
    const float* __restrict__ aff_w,
    const float* __restrict__ es, const float* __restrict__ ox, const float* __restrict__ oy,
    const float* __restrict__ stats, const float* __restrict__ pd,
    const float* __restrict__ topo_s, const float* __restrict__ orient_s,
    float* __restrict__ logits)
{
    __shared__ float x1[64][64];      // [ci][px]
    __shared__ float ylds[64][65];    // [px][co], padded
    __shared__ float sc1[64], sh1[64], sc2[64], sh2[64];
    __shared__ float ew_t[64], conf_t[64], ox_t[64], oy_t[64];
    __shared__ float pdl[32];

    int t  = threadIdx.x;
    int b  = blockIdx.z;
    int h0 = blockIdx.y * 8, w0 = blockIdx.x * 8;

    if (t < 64){
        float s = g1[t] * rsqrtf(v1[t] + 1e-5f);
        sc1[t] = s; sh1[t] = b1[t] - m1[t] * s;
        float s2v = g2[t] * rsqrtf(v2[t] + 1e-5f);
        sc2[t] = s2v; sh2[t] = b2[t] - m2[t] * s2v;
    }
    if (t < 32) pdl[t] = pd[t];
    if (t < 64){
        int py = t >> 3, pxx = t & 7;
        size_t l = (size_t)b * HW + (h0 + py) * WIDTH + (w0 + pxx);
        float esv = es[l];
        float mean = stats[b*4], rstd = stats[b*4+1], cinv = stats[b*4+2];
        ew_t[t] = (esv - mean) * rstd;
        float cf = esv * cinv; cf = cf < 0.f ? 0.f : (cf > 3.f ? 3.f : cf);
        conf_t[t] = cf;
        ox_t[t] = ox[l]; oy_t[t] = oy[l];
    }
    __syncthreads();

    // Phase A: depthwise 3x3 conv + BN1 + ReLU  (c wave-uniform -> scalar weights)
    for (int i = 0; i < 16; i++){
        int task = t + 256 * i;
        int c  = __builtin_amdgcn_readfirstlane(task >> 6);
        int px = task & 63;
        int py = px >> 3, pxx = px & 7;
        int h = h0 + py, w = w0 + pxx;
        const float* fp = feat + ((size_t)(b * 64 + c)) * HW;
        float acc = 0.f;
        #pragma unroll
        for (int kh = 0; kh < 3; kh++){
            int hh = h + kh - 1;
            if (hh < 0 || hh >= HEIGHT) continue;
            #pragma unroll
            for (int kw = 0; kw < 3; kw++){
                int ww = w + kw - 1;
                if (ww < 0 || ww >= WIDTH) continue;
                acc += fp[hh * WIDTH + ww] * dw_w[c * 9 + kh * 3 + kw];
            }
        }
        x1[c][px] = relu_f(acc * sc1[c] + sh1[c]);
    }
    __syncthreads();

    // Phase B: pointwise 1x1 conv + BN2 + ReLU (weights via scalar loads)
    {
        int px  = t & 63;
        int cog = __builtin_amdgcn_readfirstlane(t >> 6);
        float acc[16];
        #pragma unroll
        for (int j = 0; j < 16; j++) acc[j] = 0.f;
        for (int ci = 0; ci < 64; ci++){
            float xv = x1[ci][px];
            #pragma unroll
            for (int j = 0; j < 16; j++)
                acc[j] += pw_w[(cog * 16 + j) * 64 + ci] * xv;
        }
        #pragma unroll
        for (int j = 0; j < 16; j++){
            int co = cog * 16 + j;
            ylds[px][co] = relu_f(acc[j] * sc2[co] + sh2[co]);
        }
    }
    __syncthreads();

    // Phase C: affinity + edge/orientation bias -> logits [B][P][L]
    float topo = topo_s[0], orient = orient_s[0];
    for (int rep = 0; rep < 4; rep++){
        int idx = t + 256 * rep;
        int px  = idx & 63;
        int p   = __builtin_amdgcn_readfirstlane(idx >> 6);
        float acc = 0.f;
        #pragma unroll
        for (int co = 0; co < 64; co++)
            acc += aff_w[p * 64 + co] * ylds[px][co];
        int py = px >> 3, pxx = px & 7;
        int l = (h0 + py) * WIDTH + (w0 + pxx);
        float ob = (ox_t[px] * pdl[p*2] + oy_t[px] * pdl[p*2+1]) * conf_t[px];
        logits[((size_t)(b * 16 + p)) * HW + l] = acc + topo * ew_t[px] + orient * ob;
    }
}

// ---------------- K4: per-(b,p) chunk max + sumexp partials ----------------
__global__ __launch_bounds__(256) void k_softmax_part(const float* __restrict__ logits,
                                                      float* __restrict__ smpart){
    int bp = blockIdx.y, ch = blockIdx.x, t = threadIdx.x;
    size_t base = (size_t)bp * HW + ch * 1024;
    float x[4];
    #pragma unroll
    for (int i = 0; i < 4; i++) x[i] = logits[base + i * 256 + t];
    float m = fmaxf(fmaxf(x[0], x[1]), fmaxf(x[2], x[3]));
    __shared__ float red[256];
    red[t] = m; __syncthreads();
    for (int s = 128; s > 0; s >>= 1){
        if (t < s) red[t] = fmaxf(red[t], red[t+s]);
        __syncthreads();
    }
    m = red[0]; __syncthreads();
    float s = 0.f;
    #pragma unroll
    for (int i = 0; i < 4; i++) s += expf(x[i] - m);
    red[t] = s; __syncthreads();
    for (int st = 128; st > 0; st >>= 1){
        if (t < st) red[t] += red[t+st];
        __syncthreads();
    }
    if (t == 0){ smpart[(bp*64+ch)*2] = m; smpart[(bp*64+ch)*2+1] = red[0]; }
}

// ---------------- K4b: combine softmax partials ----------------
__global__ void k_softmax_comb(const float* __restrict__ smpart, float* __restrict__ smstats){
    int bp = threadIdx.x;  // 128
    float M = -1e30f;
    for (int i = 0; i < 64; i++) M = fmaxf(M, smpart[(bp*64+i)*2]);
    float S = 0.f;
    for (int i = 0; i < 64; i++) S += smpart[(bp*64+i)*2+1] * expf(smpart[(bp*64+i)*2] - M);
    smstats[bp*2] = M; smstats[bp*2+1] = 1.f / S;
}

// ---------------- K5: prototype partials (one key_tokens read, all 16 p) ----------------
__global__ __launch_bounds__(256) void k_proto_part(
    const float* __restrict__ logits, const float* __restrict__ smstats,
    const float* __restrict__ key, float* __restrict__ ppart)
{
    __shared__ float klds[128][64];
    __shared__ float wlds[128][17];
    __shared__ float Ml[16], Sl[16];
    int ch = blockIdx.x, b = blockIdx.y, t = threadIdx.x;
    if (t < 16){ Ml[t] = smstats[(b*16+t)*2]; Sl[t] = smstats[(b*16+t)*2+1]; }
    int p = t & 15, cg = t >> 4;
    float acc[4] = {0.f, 0.f, 0.f, 0.f};
    for (int sub = 0; sub < 8; sub++){
        int l0 = ch * 1024 + sub * 128;
        __syncthreads();
        for (int i = 0; i < 32; i++){
            int idx = t + 256 * i;
            int l = idx >> 6, c = idx & 63;
            klds[l][c] = key[((size_t)b * HW + l0 + l) * 64 + c];
        }
        for (int i = 0; i < 8; i++){
            int idx = t + 256 * i;
            int pp = idx >> 7, off = idx & 127;
            float x = logits[((size_t)(b * 16 + pp)) * HW + l0 + off];
            wlds[off][pp] = expf(x - Ml[pp]) * Sl[pp];
        }
        __syncthreads();
        for (int l = 0; l < 128; l++){
            float wv = wlds[l][p];
            #pragma unroll
            for (int i = 0; i < 4; i++) acc[i] += wv * klds[l][cg * 4 + i];
        }
    }
    size_t o = (((size_t)(b * 64 + ch)) * 16 + p) * 64 + cg * 4;
    #pragma unroll
    for (int i = 0; i < 4; i++) ppart[o + i] = acc[i];
}

// ---------------- K6b: reduce prototype partials ----------------
__global__ void k_proto_reduce(const float* __restrict__ ppart, float* __restrict__ proto){
    int gid = blockIdx.x * 256 + threadIdx.x;   // 8192
    int b = gid >> 10, rest = gid & 1023;
    float s = 0.f;
    for (int ch = 0; ch < 64; ch++) s += ppart[((size_t)(b * 64 + ch)) * 1024 + rest];
    proto[gid] = s;
}

// ---------------- K7: gate MLPs + sigmoid + LayerNorm ----------------
__global__ __launch_bounds__(256) void k_gate(
    const float* __restrict__ proto, const float* __restrict__ query,
    const float* __restrict__ w1, const float* __restrict__ bb1,
    const float* __restrict__ w2, const float* __restrict__ bb2,
    const float* __restrict__ gw1, const float* __restrict__ gb1,
    const float* __restrict__ gw2, const float* __restrict__ gb2,
    const float* __restrict__ lng, const float* __restrict__ lnb,
    float* __restrict__ out)
{
    __shared__ float z[16][64], h1[16][64], loc[16][64], g[64], hg[64], glb[64];
    int b = blockIdx.x, t = threadIdx.x;
    for (int idx = t; idx < 1024; idx += 256)
        z[idx >> 6][idx & 63] = proto[b * 1024 + idx] + query[b * 1024 + idx];
    __syncthreads();
    for (int idx = t; idx < 1024; idx += 256){
        int p = idx >> 6, j = idx & 63;
        float acc = bb1[j];
        for (int i = 0; i < 64; i++) acc += z[p][i] * w1[j * 64 + i];
        h1[p][j] = relu_f(acc);
    }
    if (t < 64){
        float s = 0.f;
        for (int p = 0; p < 16; p++) s += z[p][t];
        g[t] = s * (1.f / 16.f);
    }
    __syncthreads();
    for (int idx = t; idx < 1024; idx += 256){
        int p = idx >> 6, k = idx & 63;
        float acc = bb2[k];
        for (int j = 0; j < 64; j++) acc += h1[p][j] * w2[k * 64 + j];
        loc[p][k] = acc;
    }
    if (t < 64){
        float acc = gb1[t];
        for (int i = 0; i < 64; i++) acc += g[i] * gw1[t * 64 + i];
        hg[t] = relu_f(acc);
    }
    __syncthreads();
    if (t < 64){
        float acc = gb2[t];
        for (int j = 0; j < 64; j++) acc += hg[j] * gw2[t * 64 + j];
        glb[t] = acc;
    }
    __syncthreads();
    for (int idx = t; idx < 1024; idx += 256){
        int p = idx >> 6, c = idx & 63;
        float a = loc[p][c] + glb[c];
        float sg = 1.f / (1.f + expf(-a));
        float q = query[b * 1024 + idx];
        h1[p][c] = q * sg + q;            // reuse h1 as v
    }
    __syncthreads();
    if (t < 16){
        int p = t;
        float mu = 0.f;
        for (int c = 0; c < 64; c++) mu += h1[p][c];
        mu *= (1.f / 64.f);
        float var = 0.f;
        for (int c = 0; c < 64; c++){ float d = h1[p][c] - mu; var += d * d; }
        var *= (1.f / 64.f);
        float rstd = rsqrtf(var + 1e-5f);
        for (int c = 0; c < 64; c++)
            out[b * 1024 + p * 64 + c] = (h1[p][c] - mu) * rstd * lng[c] + lnb[c];
    }
}

extern "C" void kernel_launch(void* const* d_in, const int* in_sizes, int n_in,
                              void* d_out, int out_size, void* d_ws, size_t ws_size,
                              hipStream_t stream){
    (void)in_sizes; (void)n_in; (void)out_size; (void)ws_size;
    const float* feat   = (const float*)d_in[0];
    const float* query  = (const float*)d_in[1];
    const float* key    = (const float*)d_in[2];
    const float* dw_w   = (const float*)d_in[3];
    const float* bn1_g  = (const float*)d_in[4];
    const float* bn1_b  = (const float*)d_in[5];
    const float* bn1_m  = (const float*)d_in[6];
    const float* bn1_v  = (const float*)d_in[7];
    const float* pw_w   = (const float*)d_in[8];
    const float* bn2_g  = (const float*)d_in[9];
    const float* bn2_b  = (const float*)d_in[10];
    const float* bn2_m  = (const float*)d_in[11];
    const float* bn2_v  = (const float*)d_in[12];
    const float* aff_w  = (const float*)d_in[13];
    const float* loc_w1 = (const float*)d_in[14];
    const float* loc_b1 = (const float*)d_in[15];
    const float* loc_w2 = (const float*)d_in[16];
    const float* loc_b2 = (const float*)d_in[17];
    const float* glb_w1 = (const float*)d_in[18];
    const float* glb_b1 = (const float*)d_in[19];
    const float* glb_w2 = (const float*)d_in[20];
    const float* glb_b2 = (const float*)d_in[21];
    const float* ln_g   = (const float*)d_in[22];
    const float* ln_b   = (const float*)d_in[23];
    const float* topo   = (const float*)d_in[24];
    const float* orient = (const float*)d_in[25];
    const float* proto_orient = (const float*)d_in[26];
    float* out = (float*)d_out;
    float* ws  = (float*)d_ws;

    float* edge_input = ws;                  // 524288
    float* es         = ws + 524288;         // 524288
    float* ox         = ws + 1048576;        // 524288
    float* oy         = ws + 1572864;        // 524288
    float* logits     = ws + 2097152;        // 8388608
    float* k3part     = ws + 10485760;       // 1024
    float* stats      = ws + 10486784;       // 32
    float* pd         = ws + 10486816;       // 32
    float* smpart     = ws + 10486848;       // 16384
    float* smstats    = ws + 10503232;       // 256
    float* ppart      = ws + 10503488;       // 524288
    float* proto      = ws + 11027776;       // 8192
    // total: 11,035,968 floats = 44.1 MB

    k_chanmean<<<2048, 256, 0, stream>>>(feat, edge_input);
    k_sobel<<<dim3(64, 8), 256, 0, stream>>>(edge_input, es, ox, oy, k3part);
    k_stats<<<1, 256, 0, stream>>>(k3part, proto_orient, stats, pd);
    k_conv_aff<<<dim3(32, 32, 8), 256, 0, stream>>>(
        feat, dw_w, bn1_g, bn1_b, bn1_m, bn1_v, pw_w, bn2_g, bn2_b, bn2_m, bn2_v,
        aff_w, es, ox, oy, stats, pd, topo, orient, logits);
    k_softmax_part<<<dim3(64, 128), 256, 0, stream>>>(logits, smpart);
    k_softmax_comb<<<1, 128, 0, stream>>>(smpart, smstats);
    k_proto_part<<<dim3(64, 8), 256, 0, stream>>>(logits, smstats, key, ppart);
    k_proto_reduce<<<32, 256, 0, stream>>>(ppart, proto);
    k_gate<<<8, 256, 0, stream>>>(proto, query, loc_w1, loc_b1, loc_w2, loc_b2,
                                  glb_w1, glb_b1, glb_w2, glb_b2, ln_g, ln_b, out);
}

// Round 2
// 410.178 us; speedup vs baseline: 1.3327x; 1.3327x over previous
//
#include <hip/hip_runtime.h>
#include <math.h>

#define HW     65536
#define WIDTH  256
#define HEIGHT 256

__device__ __forceinline__ float relu_f(float x){ return x > 0.f ? x : 0.f; }

// ---------------- K0: prep — transpose pw weights, fold BN params ----------------
__global__ void k_prep(const float* __restrict__ pw_w,
                       const float* __restrict__ g1, const float* __restrict__ b1,
                       const float* __restrict__ m1, const float* __restrict__ v1,
                       const float* __restrict__ g2, const float* __restrict__ b2,
                       const float* __restrict__ m2, const float* __restrict__ v2,
                       float* __restrict__ pw_wT, float* __restrict__ scsh){
    int t = threadIdx.x;
    for (int i = t; i < 4096; i += 256){
        int co = i >> 6, ci = i & 63;
        pw_wT[ci * 64 + co] = pw_w[co * 64 + ci];
    }
    if (t < 64){
        float s = g1[t] * rsqrtf(v1[t] + 1e-5f);
        scsh[t]       = s;
        scsh[64 + t]  = b1[t] - m1[t] * s;
        float s2 = g2[t] * rsqrtf(v2[t] + 1e-5f);
        scsh[128 + t] = s2;
        scsh[192 + t] = b2[t] - m2[t] * s2;
    }
}

// ---------------- K2: fused dw3x3+BN+ReLU -> 1x1+BN+ReLU -> affinity (raw logits)
//                  + channel-mean (ei) fused for free ----------------
__global__ __launch_bounds__(256) void k_conv_aff(
    const float* __restrict__ feat, const float* __restrict__ dw_w,
    const float* __restrict__ pw_wT, const float* __restrict__ scsh,
    const float* __restrict__ aff_w,
    float* __restrict__ logits, float* __restrict__ ei)
{
    int t = threadIdx.x;
    // XCD-bijective swizzle: 2048 blocks, 8 XCDs -> each XCD gets one contiguous
    // (b,h) range of 256 rows => feat rows reused in that XCD's L2.
    int orig = blockIdx.x;
    int flat = (orig & 7) * 256 + (orig >> 3);
    int b = flat >> 8, h = flat & 255;

    const float* fb = feat + (size_t)b * 64 * HW;

    float acc[64];
    #pragma unroll
    for (int co = 0; co < 64; co++) acc[co] = 0.f;
    float mean_acc = 0.f;

    for (int ci = 0; ci < 64; ci++){
        const float* wdw = dw_w + ci * 9;          // uniform -> scalar loads
        const float* rbase = fb + (size_t)ci * HW;
        float dwacc = 0.f;
        #pragma unroll
        for (int kh = 0; kh < 3; kh++){
            int hh = h + kh - 1;
            if (hh < 0 || hh >= HEIGHT) continue;  // uniform branch (h uniform)
            const float* rp = rbase + hh * WIDTH;
            float vl = (t > 0)         ? rp[t - 1] : 0.f;
            float vc =                   rp[t];
            float vr = (t < WIDTH - 1) ? rp[t + 1] : 0.f;
            dwacc += vl * wdw[kh * 3 + 0] + vc * wdw[kh * 3 + 1] + vr * wdw[kh * 3 + 2];
            if (kh == 1) mean_acc += vc;           // channel-mean (free)
        }
        float x1v = relu_f(dwacc * scsh[ci] + scsh[64 + ci]);
        const float* wrow = pw_wT + ci * 64;       // uniform contiguous -> s_load
        #pragma unroll
        for (int co = 0; co < 64; co++)
            acc[co] = fmaf(wrow[co], x1v, acc[co]);
    }

    ei[(size_t)b * HW + h * WIDTH + t] = mean_acc * (1.f / 64.f);

    #pragma unroll
    for (int co = 0; co < 64; co++)
        acc[co] = relu_f(acc[co] * scsh[128 + co] + scsh[192 + co]);

    for (int p = 0; p < 16; p++){
        const float* ar = aff_w + p * 64;          // uniform contiguous -> s_load
        float lp = 0.f;
        #pragma unroll
        for (int co = 0; co < 64; co++)
            lp = fmaf(ar[co], acc[co], lp);
        logits[((size_t)(b * 16 + p)) * HW + h * WIDTH + t] = lp;
    }
}

// ---------------- K3: Sobel -> es, ori_x, ori_y + partial sums ----------------
__global__ __launch_bounds__(256) void k_sobel(const float* __restrict__ ei,
                                               float* __restrict__ es,
                                               float* __restrict__ ox,
                                               float* __restrict__ oy,
                                               float* __restrict__ part){
    int b = blockIdx.y, ch = blockIdx.x, t = threadIdx.x;
    const float* e = ei + (size_t)b * HW;
    float s1 = 0.f, s2 = 0.f;
    for (int i = 0; i < 4; i++){
        int l = ch * 1024 + i * 256 + t;
        int h = l >> 8, w = l & 255;
        float v[3][3];
        #pragma unroll
        for (int dh = -1; dh <= 1; dh++)
            #pragma unroll
            for (int dw = -1; dw <= 1; dw++){
                int hh = h + dh, ww = w + dw;
                v[dh+1][dw+1] = (hh >= 0 && hh < HEIGHT && ww >= 0 && ww < WIDTH)
                                ? e[hh * WIDTH + ww] : 0.f;
            }
        float gx = -v[0][0] + v[0][2] - 2.f*v[1][0] + 2.f*v[1][2] - v[2][0] + v[2][2];
        float gy = -v[0][0] - 2.f*v[0][1] - v[0][2] + v[2][0] + 2.f*v[2][1] + v[2][2];
        float g2 = gx*gx + gy*gy;
        float denom = g2 + 1e-6f;
        float esv = sqrtf(denom);
        size_t o = (size_t)b * HW + l;
        es[o] = esv;
        ox[o] = (gx*gx - gy*gy) / denom;
        oy[o] = 2.f * gx * gy / denom;
        s1 += esv; s2 += esv * esv;
    }
    __shared__ float r1[256], r2[256];
    r1[t] = s1; r2[t] = s2; __syncthreads();
    for (int s = 128; s > 0; s >>= 1){
        if (t < s){ r1[t] += r1[t+s]; r2[t] += r2[t+s]; }
        __syncthreads();
    }
    if (t == 0){ part[(b*64+ch)*2] = r1[0]; part[(b*64+ch)*2+1] = r2[0]; }
}

// ---------------- K3b: per-batch edge stats + normalized proto dirs ----------------
__global__ void k_stats(const float* __restrict__ part,
                        const float* __restrict__ proto_orient,
                        float* __restrict__ stats, float* __restrict__ pd){
    int t = threadIdx.x;
    if (t < 8){
        float s1 = 0.f, s2 = 0.f;
        for (int i = 0; i < 64; i++){ s1 += part[(t*64+i)*2]; s2 += part[(t*64+i)*2+1]; }
        float mean = s1 / 65536.f;
        float var  = (s2 - 65536.f * mean * mean) / 65535.f;
        var = var > 0.f ? var : 0.f;
        float sd = sqrtf(var);
        stats[t*4+0] = mean;
        stats[t*4+1] = 1.f / (sd + 1e-5f);
        stats[t*4+2] = 1.f / (mean + 1e-6f);
    }
    if (t >= 32 && t < 48){
        int p = t - 32;
        float nx = proto_orient[p*2], ny = proto_orient[p*2+1];
        float n = sqrtf(nx*nx + ny*ny);
        n = n > 1e-12f ? n : 1e-12f;
        pd[p*2] = nx / n; pd[p*2+1] = ny / n;
    }
}

// ---------------- K4: per-(b,chunk) ALL-p online softmax partials (bias fused) ----------------
__global__ __launch_bounds__(256) void k_softmax_part(
    const float* __restrict__ logits,
    const float* __restrict__ es, const float* __restrict__ ox, const float* __restrict__ oy,
    const float* __restrict__ stats, const float* __restrict__ pd,
    const float* __restrict__ topo_s, const float* __restrict__ orient_s,
    float* __restrict__ smpart)
{
    int ch = blockIdx.x, b = blockIdx.y, t = threadIdx.x;
    float topo = topo_s[0], orient = orient_s[0];
    float mean = stats[b*4], rstd = stats[b*4+1], cinv = stats[b*4+2];
    float m[16], s[16];
    #pragma unroll
    for (int p = 0; p < 16; p++){ m[p] = -1e30f; s[p] = 0.f; }
    for (int i = 0; i < 4; i++){
        int loff = ch * 1024 + i * 256 + t;
        size_t gl = (size_t)b * HW + loff;
        float esv = es[gl];
        float cf = fminf(fmaxf(esv * cinv, 0.f), 3.f);
        float ew = (esv - mean) * rstd;
        float oxc = ox[gl] * cf, oyc = oy[gl] * cf;
        #pragma unroll
        for (int p = 0; p < 16; p++){
            float x = logits[((size_t)(b*16+p)) * HW + loff]
                    + topo * ew + orient * (oxc * pd[p*2] + oyc * pd[p*2+1]);
            float mn = fmaxf(m[p], x);
            s[p] = s[p] * __expf(m[p] - mn) + __expf(x - mn);
            m[p] = mn;
        }
    }
    // wave butterfly reduce (64 lanes)
    #pragma unroll
    for (int p = 0; p < 16; p++){
        #pragma unroll
        for (int off = 32; off >= 1; off >>= 1){
            float m2 = __shfl_xor(m[p], off, 64);
            float s2 = __shfl_xor(s[p], off, 64);
            float mn = fmaxf(m[p], m2);
            s[p] = s[p] * __expf(m[p] - mn) + s2 * __expf(m2 - mn);
            m[p] = mn;
        }
    }
    __shared__ float rm[4][16], rs[4][16];
    int wid = t >> 6, lane = t & 63;
    if (lane == 0){
        #pragma unroll
        for (int p = 0; p < 16; p++){ rm[wid][p] = m[p]; rs[wid][p] = s[p]; }
    }
    __syncthreads();
    if (t < 16){
        float M = -1e30f, S = 0.f;
        for (int w = 0; w < 4; w++){
            float mw = rm[w][t], sw = rs[w][t];
            float mn = fmaxf(M, mw);
            S = S * __expf(M - mn) + sw * __expf(mw - mn);
            M = mn;
        }
        smpart[((b*16+t)*64 + ch)*2]     = M;
        smpart[((b*16+t)*64 + ch)*2 + 1] = S;
    }
}

// ---------------- K4b: combine softmax partials ----------------
__global__ void k_softmax_comb(const float* __restrict__ smpart, float* __restrict__ smstats){
    int bp = threadIdx.x;  // 128
    float M = -1e30f;
    for (int i = 0; i < 64; i++) M = fmaxf(M, smpart[(bp*64+i)*2]);
    float S = 0.f;
    for (int i = 0; i < 64; i++) S += smpart[(bp*64+i)*2+1] * expf(smpart[(bp*64+i)*2] - M);
    smstats[bp*2] = M; smstats[bp*2+1] = 1.f / S;
}

// ---------------- K5: prototype partials (one key read, all 16 p; bias recomputed) ----------------
__global__ __launch_bounds__(256) void k_proto_part(
    const float* __restrict__ logits, const float* __restrict__ smstats,
    const float* __restrict__ key,
    const float* __restrict__ es, const float* __restrict__ ox, const float* __restrict__ oy,
    const float* __restrict__ stats, const float* __restrict__ pd,
    const float* __restrict__ topo_s, const float* __restrict__ orient_s,
    float* __restrict__ ppart)
{
    __shared__ float klds[128][64];
    __shared__ float wlds[128][17];
    __shared__ float Ml[16], Sl[16], pdl[32];
    int ch = blockIdx.x, b = blockIdx.y, t = threadIdx.x;
    if (t < 16){ Ml[t] = smstats[(b*16+t)*2]; Sl[t] = smstats[(b*16+t)*2+1]; }
    if (t < 32) pdl[t] = pd[t];
    float topo = topo_s[0], orient = orient_s[0];
    float mean = stats[b*4], rstd = stats[b*4+1], cinv = stats[b*4+2];
    int p = t & 15, cg = t >> 4;
    float acc[4] = {0.f, 0.f, 0.f, 0.f};
    for (int sub = 0; sub < 8; sub++){
        int l0 = ch * 1024 + sub * 128;
        __syncthreads();
        for (int i = 0; i < 32; i++){
            int idx = t + 256 * i;
            int l = idx >> 6, c = idx & 63;
            klds[l][c] = key[((size_t)b * HW + l0 + l) * 64 + c];
        }
        for (int i = 0; i < 8; i++){
            int idx = t + 256 * i;
            int pp = idx >> 7, off = idx & 127;
            size_t gl = (size_t)b * HW + l0 + off;
            float esv = es[gl];
            float cf = fminf(fmaxf(esv * cinv, 0.f), 3.f);
            float ew = (esv - mean) * rstd;
            float x = logits[((size_t)(b*16+pp)) * HW + l0 + off]
                    + topo * ew + orient * ((ox[gl] * pdl[pp*2] + oy[gl] * pdl[pp*2+1]) * cf);
            wlds[off][pp] = __expf(x - Ml[pp]) * Sl[pp];
        }
        __syncthreads();
        for (int l = 0; l < 128; l++){
            float wv = wlds[l][p];
            #pragma unroll
            for (int i2 = 0; i2 < 4; i2++) acc[i2] += wv * klds[l][cg * 4 + i2];
        }
    }
    size_t o = (((size_t)(b * 64 + ch)) * 16 + p) * 64 + cg * 4;
    #pragma unroll
    for (int i2 = 0; i2 < 4; i2++) ppart[o + i2] = acc[i2];
}

// ---------------- K6b: reduce prototype partials ----------------
__global__ void k_proto_reduce(const float* __restrict__ ppart, float* __restrict__ proto){
    int gid = blockIdx.x * 256 + threadIdx.x;   // 8192
    int b = gid >> 10, rest = gid & 1023;
    float s = 0.f;
    for (int ch = 0; ch < 64; ch++) s += ppart[((size_t)(b * 64 + ch)) * 1024 + rest];
    proto[gid] = s;
}

// ---------------- K7: gate MLPs + sigmoid + LayerNorm ----------------
__global__ __launch_bounds__(256) void k_gate(
    const float* __restrict__ proto, const float* __restrict__ query,
    const float* __restrict__ w1, const float* __restrict__ bb1,
    const float* __restrict__ w2, const float* __restrict__ bb2,
    const float* __restrict__ gw1, const float* __restrict__ gb1,
    const float* __restrict__ gw2, const float* __restrict__ gb2,
    const float* __restrict__ lng, const float* __restrict__ lnb,
    float* __restrict__ out)
{
    __shared__ float z[16][64], h1[16][64], loc[16][64], g[64], hg[64], glb[64];
    int b = blockIdx.x, t = threadIdx.x;
    for (int idx = t; idx < 1024; idx += 256)
        z[idx >> 6][idx & 63] = proto[b * 1024 + idx] + query[b * 1024 + idx];
    __syncthreads();
    for (int idx = t; idx < 1024; idx += 256){
        int p = idx >> 6, j = idx & 63;
        float acc = bb1[j];
        for (int i = 0; i < 64; i++) acc += z[p][i] * w1[j * 64 + i];
        h1[p][j] = relu_f(acc);
    }
    if (t < 64){
        float s = 0.f;
        for (int p = 0; p < 16; p++) s += z[p][t];
        g[t] = s * (1.f / 16.f);
    }
    __syncthreads();
    for (int idx = t; idx < 1024; idx += 256){
        int p = idx >> 6, k = idx & 63;
        float acc = bb2[k];
        for (int j = 0; j < 64; j++) acc += h1[p][j] * w2[k * 64 + j];
        loc[p][k] = acc;
    }
    if (t < 64){
        float acc = gb1[t];
        for (int i = 0; i < 64; i++) acc += g[i] * gw1[t * 64 + i];
        hg[t] = relu_f(acc);
    }
    __syncthreads();
    if (t < 64){
        float acc = gb2[t];
        for (int j = 0; j < 64; j++) acc += hg[j] * gw2[t * 64 + j];
        glb[t] = acc;
    }
    __syncthreads();
    for (int idx = t; idx < 1024; idx += 256){
        int p = idx >> 6, c = idx & 63;
        float a = loc[p][c] + glb[c];
        float sg = 1.f / (1.f + expf(-a));
        float q = query[b * 1024 + idx];
        h1[p][c] = q * sg + q;
    }
    __syncthreads();
    if (t < 16){
        int p = t;
        float mu = 0.f;
        for (int c = 0; c < 64; c++) mu += h1[p][c];
        mu *= (1.f / 64.f);
        float var = 0.f;
        for (int c = 0; c < 64; c++){ float d = h1[p][c] - mu; var += d * d; }
        var *= (1.f / 64.f);
        float rstd = rsqrtf(var + 1e-5f);
        for (int c = 0; c < 64; c++)
            out[b * 1024 + p * 64 + c] = (h1[p][c] - mu) * rstd * lng[c] + lnb[c];
    }
}

extern "C" void kernel_launch(void* const* d_in, const int* in_sizes, int n_in,
                              void* d_out, int out_size, void* d_ws, size_t ws_size,
                              hipStream_t stream){
    (void)in_sizes; (void)n_in; (void)out_size; (void)ws_size;
    const float* feat   = (const float*)d_in[0];
    const float* query  = (const float*)d_in[1];
    const float* key    = (const float*)d_in[2];
    const float* dw_w   = (const float*)d_in[3];
    const float* bn1_g  = (const float*)d_in[4];
    const float* bn1_b  = (const float*)d_in[5];
    const float* bn1_m  = (const float*)d_in[6];
    const float* bn1_v  = (const float*)d_in[7];
    const float* pw_w   = (const float*)d_in[8];
    const float* bn2_g  = (const float*)d_in[9];
    const float* bn2_b  = (const float*)d_in[10];
    const float* bn2_m  = (const float*)d_in[11];
    const float* bn2_v  = (const float*)d_in[12];
    const float* aff_w  = (const float*)d_in[13];
    const float* loc_w1 = (const float*)d_in[14];
    const float* loc_b1 = (const float*)d_in[15];
    const float* loc_w2 = (const float*)d_in[16];
    const float* loc_b2 = (const float*)d_in[17];
    const float* glb_w1 = (const float*)d_in[18];
    const float* glb_b1 = (const float*)d_in[19];
    const float* glb_w2 = (const float*)d_in[20];
    const float* glb_b2 = (const float*)d_in[21];
    const float* ln_g   = (const float*)d_in[22];
    const float* ln_b   = (const float*)d_in[23];
    const float* topo   = (const float*)d_in[24];
    const float* orient = (const float*)d_in[25];
    const float* proto_orient = (const float*)d_in[26];
    float* out = (float*)d_out;
    float* ws  = (float*)d_ws;

    float* ei      = ws;                  // 524288
    float* es      = ws + 524288;         // 524288
    float* ox      = ws + 1048576;        // 524288
    float* oy      = ws + 1572864;        // 524288
    float* logits  = ws + 2097152;        // 8388608
    float* k3part  = ws + 10485760;       // 1024
    float* stats   = ws + 10486784;       // 32
    float* pd      = ws + 10486816;       // 32
    float* smpart  = ws + 10486848;       // 16384
    float* smstats = ws + 10503232;       // 256
    float* ppart   = ws + 10503488;       // 524288
    float* proto   = ws + 11027776;       // 8192
    // prep data lives in ppart's space: K2 (reader) completes before K5 (writer) starts
    float* pw_wT   = ppart;               // 4096
    float* scsh    = ppart + 4096;        // 256

    k_prep<<<1, 256, 0, stream>>>(pw_w, bn1_g, bn1_b, bn1_m, bn1_v,
                                  bn2_g, bn2_b, bn2_m, bn2_v, pw_wT, scsh);
    k_conv_aff<<<2048, 256, 0, stream>>>(feat, dw_w, pw_wT, scsh, aff_w, logits, ei);
    k_sobel<<<dim3(64, 8), 256, 0, stream>>>(ei, es, ox, oy, k3part);
    k_stats<<<1, 256, 0, stream>>>(k3part, proto_orient, stats, pd);
    k_softmax_part<<<dim3(64, 8), 256, 0, stream>>>(logits, es, ox, oy, stats, pd,
                                                    topo, orient, smpart);
    k_softmax_comb<<<1, 128, 0, stream>>>(smpart, smstats);
    k_proto_part<<<dim3(64, 8), 256, 0, stream>>>(logits, smstats, key, es, ox, oy,
                                                  stats, pd, topo, orient, ppart);
    k_proto_reduce<<<32, 256, 0, stream>>>(ppart, proto);
    k_gate<<<8, 256, 0, stream>>>(proto, query, loc_w1, loc_b1, loc_w2, loc_b2,
                                  glb_w1, glb_b1, glb_w2, glb_b2, ln_g, ln_b, out);
}

// Round 3
// 266.582 us; speedup vs baseline: 2.0506x; 1.5387x over previous
//
#include <hip/hip_runtime.h>
#include <math.h>

#define HW     65536
#define WIDTH  256
#define HEIGHT 256

typedef __attribute__((ext_vector_type(8))) short bf16x8;
typedef __attribute__((ext_vector_type(4))) float f32x4;

__device__ __forceinline__ float relu_f(float x){ return x > 0.f ? x : 0.f; }
__device__ __forceinline__ unsigned short f2bf(float x){
    union { float f; unsigned int u; } v; v.f = x;
    unsigned int r = v.u + 0x7fffu + ((v.u >> 16) & 1u);   // RNE
    return (unsigned short)(r >> 16);
}

// ---------------- K0: prep — fold BN, pack MFMA A-fragments ----------------
__global__ void k_prep(const float* __restrict__ pw_w, const float* __restrict__ aff_w,
                       const float* __restrict__ g1, const float* __restrict__ b1,
                       const float* __restrict__ m1, const float* __restrict__ v1,
                       const float* __restrict__ g2, const float* __restrict__ b2,
                       const float* __restrict__ m2, const float* __restrict__ v2,
                       float* __restrict__ scsh, unsigned short* __restrict__ pwA,
                       unsigned short* __restrict__ affA){
    int t = threadIdx.x;
    // pwA[ct][ks][lane][8]: A-frag for co_tile ct, k-slab ks (ci 32*ks..+31)
    for (int i = t; i < 4096; i += 256){
        int e = i & 7, l = (i >> 3) & 63, ks = (i >> 9) & 1, ct = i >> 10;
        int co = ct * 16 + (l & 15);
        int ci = ks * 32 + (l >> 4) * 8 + e;
        pwA[i] = f2bf(pw_w[co * 64 + ci]);
    }
    // affA[ks][lane][8]: p = lane&15, k(co) slice
    for (int i = t; i < 1024; i += 256){
        int e = i & 7, l = (i >> 3) & 63, ks = i >> 9;
        int p = l & 15, k = ks * 32 + (l >> 4) * 8 + e;
        affA[i] = f2bf(aff_w[p * 64 + k]);
    }
    if (t < 64){
        float s = g1[t] * rsqrtf(v1[t] + 1e-5f);
        scsh[t]       = s;
        scsh[64 + t]  = b1[t] - m1[t] * s;
        float s2 = g2[t] * rsqrtf(v2[t] + 1e-5f);
        scsh[128 + t] = s2;
        scsh[192 + t] = b2[t] - m2[t] * s2;
    }
}

// ---------------- K2: dw3x3(f32) -> LDS bf16 -> MFMA pw -> MFMA affinity ----------------
__global__ __launch_bounds__(256) void k_conv_aff(
    const float* __restrict__ feat, const float* __restrict__ dw_w,
    const float* __restrict__ scsh, const unsigned short* __restrict__ pwA,
    const unsigned short* __restrict__ affA,
    float* __restrict__ logits, float* __restrict__ ei)
{
    __shared__ unsigned short x1[128][68];   // [px_local][ci] bf16, stride 136B
    __shared__ float eibuf[2][128];
    int t = threadIdx.x;
    // XCD-bijective swizzle: 4096 blocks, 512/XCD contiguous (b,h,half)
    int orig = blockIdx.x;
    int flat = (orig & 7) * 512 + (orig >> 3);
    int half = flat & 1;
    int row  = flat >> 1;                    // 0..2047
    int b = row >> 8, h = row & 255;
    int lane = t & 63, w = t >> 6;

    // hoist A-fragments + BN2 params (independent of phase A -> latency hidden)
    const bf16x8* pwA8 = (const bf16x8*)pwA;
    bf16x8 apw0 = pwA8[(w * 2 + 0) * 64 + lane];
    bf16x8 apw1 = pwA8[(w * 2 + 1) * 64 + lane];
    const bf16x8* affA8 = (const bf16x8*)affA;
    bf16x8 aaf0 = affA8[lane];
    bf16x8 aaf1 = affA8[64 + lane];
    int cb = w * 16 + (lane >> 4) * 4;       // co base for this lane's D frag
    float4 sc2v = *(const float4*)(scsh + 128 + cb);
    float4 sh2v = *(const float4*)(scsh + 192 + cb);

    // ---- phase A: depthwise 3x3 + BN1 + ReLU (f32 exact), 2 threads/px, 32 ci each
    int pxl = t & 127, g = t >> 7;           // g uniform per wave
    int px = half * 128 + pxl;
    const float* fb = feat + (size_t)b * 64 * HW;
    unsigned int buf[16];
    float mean_acc = 0.f;
    for (int k = 0; k < 32; k += 2){
        unsigned int pk = 0;
        #pragma unroll
        for (int q = 0; q < 2; q++){
            int ci = __builtin_amdgcn_readfirstlane(g * 32 + k + q);
            const float* rb = fb + (size_t)ci * HW;
            float dwacc = 0.f;
            #pragma unroll
            for (int kh = 0; kh < 3; kh++){
                int hh = h + kh - 1;
                if (hh < 0 || hh >= HEIGHT) continue;   // uniform (h uniform)
                const float* rp = rb + hh * WIDTH;
                float vc = rp[px];
                float vl = (px > 0)   ? rp[px - 1] : 0.f;
                float vr = (px < 255) ? rp[px + 1] : 0.f;
                dwacc += vl * dw_w[ci*9 + kh*3] + vc * dw_w[ci*9 + kh*3 + 1]
                       + vr * dw_w[ci*9 + kh*3 + 2];
                if (kh == 1) mean_acc += vc;            // channel-mean, free
            }
            float x1v = relu_f(fmaf(dwacc, scsh[ci], scsh[64 + ci]));
            pk |= (unsigned int)f2bf(x1v) << (16 * q);
        }
        buf[k >> 1] = pk;
    }
    eibuf[g][pxl] = mean_acc;
    #pragma unroll
    for (int s = 0; s < 8; s++)
        *(uint2*)&x1[pxl][g * 32 + s * 4] = make_uint2(buf[2*s], buf[2*s + 1]);
    __syncthreads();
    if (t < 128)
        ei[(size_t)b * HW + h * WIDTH + half * 128 + t] =
            (eibuf[0][t] + eibuf[1][t]) * (1.f / 64.f);

    // ---- phase B: pw 1x1 GEMM (64co x 128px x 64ci), y overwrites x1 in place
    int k0 = (lane >> 4) * 8;
    for (int jt = 0; jt < 8; jt++){
        int bpx = jt * 16 + (lane & 15);
        union { bf16x8 v; uint2 q[2]; } bf0, bf1;
        bf0.q[0] = *(const uint2*)&x1[bpx][k0];
        bf0.q[1] = *(const uint2*)&x1[bpx][k0 + 4];
        bf1.q[0] = *(const uint2*)&x1[bpx][32 + k0];
        bf1.q[1] = *(const uint2*)&x1[bpx][32 + k0 + 4];
        f32x4 acc = {0.f, 0.f, 0.f, 0.f};
        acc = __builtin_amdgcn_mfma_f32_16x16x32_bf16(apw0, bf0.v, acc, 0, 0, 0);
        acc = __builtin_amdgcn_mfma_f32_16x16x32_bf16(apw1, bf1.v, acc, 0, 0, 0);
        unsigned int y0 = (unsigned int)f2bf(relu_f(fmaf(acc[0], sc2v.x, sh2v.x)))
                        | ((unsigned int)f2bf(relu_f(fmaf(acc[1], sc2v.y, sh2v.y))) << 16);
        unsigned int y1 = (unsigned int)f2bf(relu_f(fmaf(acc[2], sc2v.z, sh2v.z)))
                        | ((unsigned int)f2bf(relu_f(fmaf(acc[3], sc2v.w, sh2v.w))) << 16);
        __syncthreads();                      // all reads of tile jt done
        *(uint2*)&x1[bpx][cb] = make_uint2(y0, y1);
    }
    __syncthreads();                          // y complete

    // ---- phase C: affinity GEMM (16p x 128px x 64co) -> logits
    size_t lbase = (size_t)b * 16 * HW;
    int outp0 = (lane >> 4) * 4;
    #pragma unroll
    for (int q = 0; q < 2; q++){
        int jt = w * 2 + q;
        int bpx = jt * 16 + (lane & 15);
        union { bf16x8 v; uint2 qq[2]; } bf0, bf1;
        bf0.qq[0] = *(const uint2*)&x1[bpx][k0];
        bf0.qq[1] = *(const uint2*)&x1[bpx][k0 + 4];
        bf1.qq[0] = *(const uint2*)&x1[bpx][32 + k0];
        bf1.qq[1] = *(const uint2*)&x1[bpx][32 + k0 + 4];
        f32x4 acc = {0.f, 0.f, 0.f, 0.f};
        acc = __builtin_amdgcn_mfma_f32_16x16x32_bf16(aaf0, bf0.v, acc, 0, 0, 0);
        acc = __builtin_amdgcn_mfma_f32_16x16x32_bf16(aaf1, bf1.v, acc, 0, 0, 0);
        int gx = h * WIDTH + half * 128 + jt * 16 + (lane & 15);
        #pragma unroll
        for (int r = 0; r < 4; r++)
            logits[lbase + (size_t)(outp0 + r) * HW + gx] = acc[r];
    }
}

// ---------------- K3: Sobel -> es, ori_x, ori_y + partial sums ----------------
__global__ __launch_bounds__(256) void k_sobel(const float* __restrict__ ei,
                                               float* __restrict__ es,
                                               float* __restrict__ ox,
                                               float* __restrict__ oy,
                                               float* __restrict__ part){
    int b = blockIdx.y, ch = blockIdx.x, t = threadIdx.x;
    const float* e = ei + (size_t)b * HW;
    float s1 = 0.f, s2 = 0.f;
    for (int i = 0; i < 4; i++){
        int l = ch * 1024 + i * 256 + t;
        int h = l >> 8, w = l & 255;
        float v[3][3];
        #pragma unroll
        for (int dh = -1; dh <= 1; dh++)
            #pragma unroll
            for (int dw = -1; dw <= 1; dw++){
                int hh = h + dh, ww = w + dw;
                v[dh+1][dw+1] = (hh >= 0 && hh < HEIGHT && ww >= 0 && ww < WIDTH)
                                ? e[hh * WIDTH + ww] : 0.f;
            }
        float gx = -v[0][0] + v[0][2] - 2.f*v[1][0] + 2.f*v[1][2] - v[2][0] + v[2][2];
        float gy = -v[0][0] - 2.f*v[0][1] - v[0][2] + v[2][0] + 2.f*v[2][1] + v[2][2];
        float g2 = gx*gx + gy*gy;
        float denom = g2 + 1e-6f;
        float esv = sqrtf(denom);
        size_t o = (size_t)b * HW + l;
        es[o] = esv;
        ox[o] = (gx*gx - gy*gy) / denom;
        oy[o] = 2.f * gx * gy / denom;
        s1 += esv; s2 += esv * esv;
    }
    __shared__ float r1[256], r2[256];
    r1[t] = s1; r2[t] = s2; __syncthreads();
    for (int s = 128; s > 0; s >>= 1){
        if (t < s){ r1[t] += r1[t+s]; r2[t] += r2[t+s]; }
        __syncthreads();
    }
    if (t == 0){ part[(b*64+ch)*2] = r1[0]; part[(b*64+ch)*2+1] = r2[0]; }
}

// ---------------- K3b: per-batch edge stats + normalized proto dirs ----------------
__global__ void k_stats(const float* __restrict__ part,
                        const float* __restrict__ proto_orient,
                        float* __restrict__ stats, float* __restrict__ pd){
    int t = threadIdx.x;
    if (t < 8){
        float s1 = 0.f, s2 = 0.f;
        for (int i = 0; i < 64; i++){ s1 += part[(t*64+i)*2]; s2 += part[(t*64+i)*2+1]; }
        float mean = s1 / 65536.f;
        float var  = (s2 - 65536.f * mean * mean) / 65535.f;
        var = var > 0.f ? var : 0.f;
        float sd = sqrtf(var);
        stats[t*4+0] = mean;
        stats[t*4+1] = 1.f / (sd + 1e-5f);
        stats[t*4+2] = 1.f / (mean + 1e-6f);
    }
    if (t >= 32 && t < 48){
        int p = t - 32;
        float nx = proto_orient[p*2], ny = proto_orient[p*2+1];
        float n = sqrtf(nx*nx + ny*ny);
        n = n > 1e-12f ? n : 1e-12f;
        pd[p*2] = nx / n; pd[p*2+1] = ny / n;
    }
}

// ---------------- K4: per-(b,chunk) ALL-p online softmax partials (bias fused) ----------------
__global__ __launch_bounds__(256) void k_softmax_part(
    const float* __restrict__ logits,
    const float* __restrict__ es, const float* __restrict__ ox, const float* __restrict__ oy,
    const float* __restrict__ stats, const float* __restrict__ pd,
    const float* __restrict__ topo_s, const float* __restrict__ orient_s,
    float* __restrict__ smpart)
{
    int ch = blockIdx.x, b = blockIdx.y, t = threadIdx.x;
    float topo = topo_s[0], orient = orient_s[0];
    float mean = stats[b*4], rstd = stats[b*4+1], cinv = stats[b*4+2];
    float m[16], s[16];
    #pragma unroll
    for (int p = 0; p < 16; p++){ m[p] = -1e30f; s[p] = 0.f; }
    for (int i = 0; i < 4; i++){
        int loff = ch * 1024 + i * 256 + t;
        size_t gl = (size_t)b * HW + loff;
        float esv = es[gl];
        float cf = fminf(fmaxf(esv * cinv, 0.f), 3.f);
        float ew = (esv - mean) * rstd;
        float oxc = ox[gl] * cf, oyc = oy[gl] * cf;
        #pragma unroll
        for (int p = 0; p < 16; p++){
            float x = logits[((size_t)(b*16+p)) * HW + loff]
                    + topo * ew + orient * (oxc * pd[p*2] + oyc * pd[p*2+1]);
            float mn = fmaxf(m[p], x);
            s[p] = s[p] * __expf(m[p] - mn) + __expf(x - mn);
            m[p] = mn;
        }
    }
    #pragma unroll
    for (int p = 0; p < 16; p++){
        #pragma unroll
        for (int off = 32; off >= 1; off >>= 1){
            float m2 = __shfl_xor(m[p], off, 64);
            float s2 = __shfl_xor(s[p], off, 64);
            float mn = fmaxf(m[p], m2);
            s[p] = s[p] * __expf(m[p] - mn) + s2 * __expf(m2 - mn);
            m[p] = mn;
        }
    }
    __shared__ float rm[4][16], rs[4][16];
    int wid = t >> 6, lane = t & 63;
    if (lane == 0){
        #pragma unroll
        for (int p = 0; p < 16; p++){ rm[wid][p] = m[p]; rs[wid][p] = s[p]; }
    }
    __syncthreads();
    if (t < 16){
        float M = -1e30f, S = 0.f;
        for (int w = 0; w < 4; w++){
            float mw = rm[w][t], sw = rs[w][t];
            float mn = fmaxf(M, mw);
            S = S * __expf(M - mn) + sw * __expf(mw - mn);
            M = mn;
        }
        smpart[((b*16+t)*64 + ch)*2]     = M;
        smpart[((b*16+t)*64 + ch)*2 + 1] = S;
    }
}

// ---------------- K4b: combine softmax partials ----------------
__global__ void k_softmax_comb(const float* __restrict__ smpart, float* __restrict__ smstats){
    int bp = threadIdx.x;  // 128
    float M = -1e30f;
    for (int i = 0; i < 64; i++) M = fmaxf(M, smpart[(bp*64+i)*2]);
    float S = 0.f;
    for (int i = 0; i < 64; i++) S += smpart[(bp*64+i)*2+1] * expf(smpart[(bp*64+i)*2] - M);
    smstats[bp*2] = M; smstats[bp*2+1] = 1.f / S;
}

// ---------------- K5: prototype partials (one key read, all 16 p; bias recomputed) ----------------
__global__ __launch_bounds__(256) void k_proto_part(
    const float* __restrict__ logits, const float* __restrict__ smstats,
    const float* __restrict__ key,
    const float* __restrict__ es, const float* __restrict__ ox, const float* __restrict__ oy,
    const float* __restrict__ stats, const float* __restrict__ pd,
    const float* __restrict__ topo_s, const float* __restrict__ orient_s,
    float* __restrict__ ppart)
{
    __shared__ float klds[128][64];
    __shared__ float wlds[128][17];
    __shared__ float Ml[16], Sl[16], pdl[32];
    int ch = blockIdx.x, b = blockIdx.y, t = threadIdx.x;
    if (t < 16){ Ml[t] = smstats[(b*16+t)*2]; Sl[t] = smstats[(b*16+t)*2+1]; }
    if (t < 32) pdl[t] = pd[t];
    float topo = topo_s[0], orient = orient_s[0];
    float mean = stats[b*4], rstd = stats[b*4+1], cinv = stats[b*4+2];
    int p = t & 15, cg = t >> 4;
    float acc[4] = {0.f, 0.f, 0.f, 0.f};
    for (int sub = 0; sub < 8; sub++){
        int l0 = ch * 1024 + sub * 128;
        __syncthreads();
        for (int i = 0; i < 32; i++){
            int idx = t + 256 * i;
            int l = idx >> 6, c = idx & 63;
            klds[l][c] = key[((size_t)b * HW + l0 + l) * 64 + c];
        }
        for (int i = 0; i < 8; i++){
            int idx = t + 256 * i;
            int pp = idx >> 7, off = idx & 127;
            size_t gl = (size_t)b * HW + l0 + off;
            float esv = es[gl];
            float cf = fminf(fmaxf(esv * cinv, 0.f), 3.f);
            float ew = (esv - mean) * rstd;
            float x = logits[((size_t)(b*16+pp)) * HW + l0 + off]
                    + topo * ew + orient * ((ox[gl] * pdl[pp*2] + oy[gl] * pdl[pp*2+1]) * cf);
            wlds[off][pp] = __expf(x - Ml[pp]) * Sl[pp];
        }
        __syncthreads();
        for (int l = 0; l < 128; l++){
            float wv = wlds[l][p];
            #pragma unroll
            for (int i2 = 0; i2 < 4; i2++) acc[i2] += wv * klds[l][cg * 4 + i2];
        }
    }
    size_t o = (((size_t)(b * 64 + ch)) * 16 + p) * 64 + cg * 4;
    #pragma unroll
    for (int i2 = 0; i2 < 4; i2++) ppart[o + i2] = acc[i2];
}

// ---------------- K6b: reduce prototype partials ----------------
__global__ void k_proto_reduce(const float* __restrict__ ppart, float* __restrict__ proto){
    int gid = blockIdx.x * 256 + threadIdx.x;   // 8192
    int b = gid >> 10, rest = gid & 1023;
    float s = 0.f;
    for (int ch = 0; ch < 64; ch++) s += ppart[((size_t)(b * 64 + ch)) * 1024 + rest];
    proto[gid] = s;
}

// ---------------- K7: gate MLPs + sigmoid + LayerNorm ----------------
__global__ __launch_bounds__(256) void k_gate(
    const float* __restrict__ proto, const float* __restrict__ query,
    const float* __restrict__ w1, const float* __restrict__ bb1,
    const float* __restrict__ w2, const float* __restrict__ bb2,
    const float* __restrict__ gw1, const float* __restrict__ gb1,
    const float* __restrict__ gw2, const float* __restrict__ gb2,
    const float* __restrict__ lng, const float* __restrict__ lnb,
    float* __restrict__ out)
{
    __shared__ float z[16][64], h1[16][64], loc[16][64], g[64], hg[64], glb[64];
    int b = blockIdx.x, t = threadIdx.x;
    for (int idx = t; idx < 1024; idx += 256)
        z[idx >> 6][idx & 63] = proto[b * 1024 + idx] + query[b * 1024 + idx];
    __syncthreads();
    for (int idx = t; idx < 1024; idx += 256){
        int p = idx >> 6, j = idx & 63;
        float acc = bb1[j];
        for (int i = 0; i < 64; i++) acc += z[p][i] * w1[j * 64 + i];
        h1[p][j] = relu_f(acc);
    }
    if (t < 64){
        float s = 0.f;
        for (int p = 0; p < 16; p++) s += z[p][t];
        g[t] = s * (1.f / 16.f);
    }
    __syncthreads();
    for (int idx = t; idx < 1024; idx += 256){
        int p = idx >> 6, k = idx & 63;
        float acc = bb2[k];
        for (int j = 0; j < 64; j++) acc += h1[p][j] * w2[k * 64 + j];
        loc[p][k] = acc;
    }
    if (t < 64){
        float acc = gb1[t];
        for (int i = 0; i < 64; i++) acc += g[i] * gw1[t * 64 + i];
        hg[t] = relu_f(acc);
    }
    __syncthreads();
    if (t < 64){
        float acc = gb2[t];
        for (int j = 0; j < 64; j++) acc += hg[j] * gw2[t * 64 + j];
        glb[t] = acc;
    }
    __syncthreads();
    for (int idx = t; idx < 1024; idx += 256){
        int p = idx >> 6, c = idx & 63;
        float a = loc[p][c] + glb[c];
        float sg = 1.f / (1.f + expf(-a));
        float q = query[b * 1024 + idx];
        h1[p][c] = q * sg + q;
    }
    __syncthreads();
    if (t < 16){
        int p = t;
        float mu = 0.f;
        for (int c = 0; c < 64; c++) mu += h1[p][c];
        mu *= (1.f / 64.f);
        float var = 0.f;
        for (int c = 0; c < 64; c++){ float d = h1[p][c] - mu; var += d * d; }
        var *= (1.f / 64.f);
        float rstd = rsqrtf(var + 1e-5f);
        for (int c = 0; c < 64; c++)
            out[b * 1024 + p * 64 + c] = (h1[p][c] - mu) * rstd * lng[c] + lnb[c];
    }
}

extern "C" void kernel_launch(void* const* d_in, const int* in_sizes, int n_in,
                              void* d_out, int out_size, void* d_ws, size_t ws_size,
                              hipStream_t stream){
    (void)in_sizes; (void)n_in; (void)out_size; (void)ws_size;
    const float* feat   = (const float*)d_in[0];
    const float* query  = (const float*)d_in[1];
    const float* key    = (const float*)d_in[2];
    const float* dw_w   = (const float*)d_in[3];
    const float* bn1_g  = (const float*)d_in[4];
    const float* bn1_b  = (const float*)d_in[5];
    const float* bn1_m  = (const float*)d_in[6];
    const float* bn1_v  = (const float*)d_in[7];
    const float* pw_w   = (const float*)d_in[8];
    const float* bn2_g  = (const float*)d_in[9];
    const float* bn2_b  = (const float*)d_in[10];
    const float* bn2_m  = (const float*)d_in[11];
    const float* bn2_v  = (const float*)d_in[12];
    const float* aff_w  = (const float*)d_in[13];
    const float* loc_w1 = (const float*)d_in[14];
    const float* loc_b1 = (const float*)d_in[15];
    const float* loc_w2 = (const float*)d_in[16];
    const float* loc_b2 = (const float*)d_in[17];
    const float* glb_w1 = (const float*)d_in[18];
    const float* glb_b1 = (const float*)d_in[19];
    const float* glb_w2 = (const float*)d_in[20];
    const float* glb_b2 = (const float*)d_in[21];
    const float* ln_g   = (const float*)d_in[22];
    const float* ln_b   = (const float*)d_in[23];
    const float* topo   = (const float*)d_in[24];
    const float* orient = (const float*)d_in[25];
    const float* proto_orient = (const float*)d_in[26];
    float* out = (float*)d_out;
    float* ws  = (float*)d_ws;

    float* ei      = ws;                  // 524288
    float* es      = ws + 524288;         // 524288
    float* ox      = ws + 1048576;        // 524288
    float* oy      = ws + 1572864;        // 524288
    float* logits  = ws + 2097152;        // 8388608
    float* k3part  = ws + 10485760;       // 1024
    float* stats   = ws + 10486784;       // 32
    float* pd      = ws + 10486816;       // 32
    float* smpart  = ws + 10486848;       // 16384
    float* smstats = ws + 10503232;       // 256
    float* ppart   = ws + 10503488;       // 524288
    float* proto   = ws + 11027776;       // 8192
    // prep data overlaid in smpart's upper region (written by k_prep, read only
    // by K2, later overwritten by K4 — serialized on the stream, deterministic)
    float* scsh            = smpart + 4096;                 // 256 floats
    unsigned short* pwA    = (unsigned short*)(smpart + 4352);  // 4096 ushort
    unsigned short* affA   = (unsigned short*)(smpart + 6400);  // 1024 ushort

    k_prep<<<1, 256, 0, stream>>>(pw_w, aff_w, bn1_g, bn1_b, bn1_m, bn1_v,
                                  bn2_g, bn2_b, bn2_m, bn2_v, scsh, pwA, affA);
    k_conv_aff<<<4096, 256, 0, stream>>>(feat, dw_w, scsh, pwA, affA, logits, ei);
    k_sobel<<<dim3(64, 8), 256, 0, stream>>>(ei, es, ox, oy, k3part);
    k_stats<<<1, 256, 0, stream>>>(k3part, proto_orient, stats, pd);
    k_softmax_part<<<dim3(64, 8), 256, 0, stream>>>(logits, es, ox, oy, stats, pd,
                                                    topo, orient, smpart);
    k_softmax_comb<<<1, 128, 0, stream>>>(smpart, smstats);
    k_proto_part<<<dim3(64, 8), 256, 0, stream>>>(logits, smstats, key, es, ox, oy,
                                                  stats, pd, topo, orient, ppart);
    k_proto_reduce<<<32, 256, 0, stream>>>(ppart, proto);
    k_gate<<<8, 256, 0, stream>>>(proto, query, loc_w1, loc_b1, loc_w2, loc_b2,
                                  glb_w1, glb_b1, glb_w2, glb_b2, ln_g, ln_b, out);
}

// Round 4
// 230.996 us; speedup vs baseline: 2.3665x; 1.1541x over previous
//
#include <hip/hip_runtime.h>
#include <hip/hip_fp16.h>
#include <math.h>

#define HW     65536
#define WIDTH  256
#define HEIGHT 256

typedef __attribute__((ext_vector_type(8))) short bf16x8;
typedef __attribute__((ext_vector_type(4))) float f32x4;

__device__ __forceinline__ float relu_f(float x){ return x > 0.f ? x : 0.f; }
__device__ __forceinline__ unsigned int f2bf(float x){
    union { float f; unsigned int u; } v; v.f = x;
    unsigned int r = v.u + 0x7fffu + ((v.u >> 16) & 1u);   // RNE
    return r >> 16;
}
__device__ __forceinline__ float bfbits2f(unsigned int lo16){
    union { unsigned int u; float f; } v; v.u = lo16 << 16; return v.f;
}

// ---------------- K0: prep — fold BN, pack MFMA A-fragments ----------------
__global__ void k_prep(const float* __restrict__ pw_w, const float* __restrict__ aff_w,
                       const float* __restrict__ g1, const float* __restrict__ b1,
                       const float* __restrict__ m1, const float* __restrict__ v1,
                       const float* __restrict__ g2, const float* __restrict__ b2,
                       const float* __restrict__ m2, const float* __restrict__ v2,
                       float* __restrict__ scsh, unsigned short* __restrict__ pwA,
                       unsigned short* __restrict__ affA){
    int t = threadIdx.x;
    for (int i = t; i < 4096; i += 256){
        int e = i & 7, l = (i >> 3) & 63, ks = (i >> 9) & 1, ct = i >> 10;
        int co = ct * 16 + (l & 15);
        int ci = ks * 32 + (l >> 4) * 8 + e;
        pwA[i] = (unsigned short)f2bf(pw_w[co * 64 + ci]);
    }
    for (int i = t; i < 1024; i += 256){
        int e = i & 7, l = (i >> 3) & 63, ks = i >> 9;
        int p = l & 15, k = ks * 32 + (l >> 4) * 8 + e;
        affA[i] = (unsigned short)f2bf(aff_w[p * 64 + k]);
    }
    if (t < 64){
        float s = g1[t] * rsqrtf(v1[t] + 1e-5f);
        scsh[t]       = s;
        scsh[64 + t]  = b1[t] - m1[t] * s;
        float s2 = g2[t] * rsqrtf(v2[t] + 1e-5f);
        scsh[128 + t] = s2;
        scsh[192 + t] = b2[t] - m2[t] * s2;
    }
}

// ---------------- K2: dw3x3(f32, branchless, float2) -> LDS bf16 (XOR swz)
//                  -> MFMA pw -> MFMA affinity -> f16 logits ----------------
__global__ __launch_bounds__(256, 4) void k_conv_aff(
    const float* __restrict__ feat, const float* __restrict__ dw_w,
    const float* __restrict__ scsh, const unsigned short* __restrict__ pwA,
    const unsigned short* __restrict__ affA,
    unsigned short* __restrict__ logitsH, float* __restrict__ ei)
{
    __shared__ unsigned short x1u[128 * 68];   // [px][ci] bf16, row 68 ushort, XOR-swz
    __shared__ float eibuf[4][128];
    int t = threadIdx.x;
    int lane = t & 63;
    int wu = __builtin_amdgcn_readfirstlane(t >> 6);
    int orig = blockIdx.x;
    int flat = (orig & 7) * 512 + (orig >> 3);   // XCD-bijective (4096 = 8*512)
    int half = flat & 1;
    int row  = flat >> 1;
    int b = row >> 8, h = row & 255;

    // hoist MFMA A-fragments + BN2 params
    const bf16x8* pwA8 = (const bf16x8*)pwA;
    bf16x8 apw0 = pwA8[(wu * 2 + 0) * 64 + lane];
    bf16x8 apw1 = pwA8[(wu * 2 + 1) * 64 + lane];
    const bf16x8* affA8 = (const bf16x8*)affA;
    bf16x8 aaf0 = affA8[lane];
    bf16x8 aaf1 = affA8[64 + lane];
    int cb = wu * 16 + ((lane >> 4) << 2);
    float4 sc2v = *(const float4*)(scsh + 128 + cb);
    float4 sh2v = *(const float4*)(scsh + 192 + cb);

    // ---- phase A: depthwise 3x3 + BN1 + ReLU, 2 px per lane, branchless rows
    int gpx = half * 128 + 2 * lane;
    const float* fb = feat + (size_t)b * 64 * HW;
    float rw0 = (h > 0) ? 1.f : 0.f;
    float rw2 = (h < 255) ? 1.f : 0.f;
    int hh0 = (h > 0) ? h - 1 : h;
    int hh2 = (h < 255) ? h + 1 : h;
    float dwa[16], dwb[16];
    #pragma unroll
    for (int k = 0; k < 16; k++){ dwa[k] = 0.f; dwb[k] = 0.f; }
    float mean0 = 0.f, mean1 = 0.f;
    for (int r = 0; r < 3; r++){
        int hh = (r == 0) ? hh0 : ((r == 1) ? h : hh2);
        float rwf = (r == 0) ? rw0 : ((r == 1) ? 1.f : rw2);
        const float* rbase = fb + hh * WIDTH;
        #pragma unroll 8
        for (int k = 0; k < 16; k++){
            int ci = wu * 16 + k;
            const float* rp = rbase + (size_t)ci * HW;
            float vl = (gpx > 0)   ? rp[gpx - 1] : 0.f;
            float2 vc = *(const float2*)(rp + gpx);
            float vr = (gpx < 254) ? rp[gpx + 2] : 0.f;
            float w0 = dw_w[ci*9 + r*3 + 0] * rwf;
            float w1 = dw_w[ci*9 + r*3 + 1] * rwf;
            float w2 = dw_w[ci*9 + r*3 + 2] * rwf;
            dwa[k] += vl * w0 + vc.x * w1 + vc.y * w2;
            dwb[k] += vc.x * w0 + vc.y * w1 + vr * w2;
            if (r == 1){ mean0 += vc.x; mean1 += vc.y; }
        }
    }
    int px0 = 2 * lane, px1 = 2 * lane + 1;
    int sw = ((px0 >> 4) & 7) << 3;   // XOR swizzle (ushort units), same for px1
    #pragma unroll
    for (int k = 0; k < 16; k += 2){
        int ci0 = wu * 16 + k, ci1 = ci0 + 1;
        float xa = relu_f(fmaf(dwa[k],   scsh[ci0], scsh[64 + ci0]));
        float xb = relu_f(fmaf(dwa[k+1], scsh[ci1], scsh[64 + ci1]));
        float ya = relu_f(fmaf(dwb[k],   scsh[ci0], scsh[64 + ci0]));
        float yb = relu_f(fmaf(dwb[k+1], scsh[ci1], scsh[64 + ci1]));
        unsigned int pk0 = f2bf(xa) | (f2bf(xb) << 16);
        unsigned int pk1 = f2bf(ya) | (f2bf(yb) << 16);
        int off = ci0 ^ sw;
        *(unsigned int*)&x1u[px0 * 68 + off] = pk0;
        *(unsigned int*)&x1u[px1 * 68 + off] = pk1;
    }
    *(float2*)&eibuf[wu][px0] = make_float2(mean0, mean1);
    __syncthreads();
    if (t < 128)
        ei[(size_t)b * HW + h * WIDTH + half * 128 + t] =
            (eibuf[0][t] + eibuf[1][t] + eibuf[2][t] + eibuf[3][t]) * (1.f / 64.f);

    // ---- phase B: pw 1x1 GEMM, all 8 jt accumulated in regs, then in-place y
    int lcol = lane & 15;
    int k0 = (lane >> 4) << 3;
    f32x4 aB[8];
    #pragma unroll
    for (int jt = 0; jt < 8; jt++){
        int bpx = jt * 16 + lcol;
        int swj = jt << 3;
        const unsigned short* rowp = &x1u[bpx * 68];
        union { bf16x8 v; uint2 q[2]; } b0, b1;
        b0.q[0] = *(const uint2*)&rowp[(k0)          ^ swj];
        b0.q[1] = *(const uint2*)&rowp[(k0 + 4)      ^ swj];
        b1.q[0] = *(const uint2*)&rowp[(32 + k0)     ^ swj];
        b1.q[1] = *(const uint2*)&rowp[(32 + k0 + 4) ^ swj];
        f32x4 acc = {0.f, 0.f, 0.f, 0.f};
        acc = __builtin_amdgcn_mfma_f32_16x16x32_bf16(apw0, b0.v, acc, 0, 0, 0);
        acc = __builtin_amdgcn_mfma_f32_16x16x32_bf16(apw1, b1.v, acc, 0, 0, 0);
        aB[jt] = acc;
    }
    __syncthreads();   // all reads of x1 done
    #pragma unroll
    for (int jt = 0; jt < 8; jt++){
        int bpx = jt * 16 + lcol;
        int swj = jt << 3;
        f32x4 acc = aB[jt];
        unsigned int y0 = f2bf(relu_f(fmaf(acc[0], sc2v.x, sh2v.x)))
                        | (f2bf(relu_f(fmaf(acc[1], sc2v.y, sh2v.y))) << 16);
        unsigned int y1 = f2bf(relu_f(fmaf(acc[2], sc2v.z, sh2v.z)))
                        | (f2bf(relu_f(fmaf(acc[3], sc2v.w, sh2v.w))) << 16);
        *(uint2*)&x1u[bpx * 68 + (cb ^ swj)] = make_uint2(y0, y1);
    }
    __syncthreads();   // y complete

    // ---- phase C: affinity GEMM -> f16 logits
    size_t lb = (size_t)(b * 16) * HW;
    int gxbase = h * WIDTH + half * 128;
    int p0 = (lane >> 4) << 2;
    #pragma unroll
    for (int q = 0; q < 2; q++){
        int jt = wu * 2 + q;
        int bpx = jt * 16 + lcol;
        int swj = jt << 3;
        const unsigned short* rowp = &x1u[bpx * 68];
        union { bf16x8 v; uint2 qq[2]; } b0, b1;
        b0.qq[0] = *(const uint2*)&rowp[(k0)          ^ swj];
        b0.qq[1] = *(const uint2*)&rowp[(k0 + 4)      ^ swj];
        b1.qq[0] = *(const uint2*)&rowp[(32 + k0)     ^ swj];
        b1.qq[1] = *(const uint2*)&rowp[(32 + k0 + 4) ^ swj];
        f32x4 acc = {0.f, 0.f, 0.f, 0.f};
        acc = __builtin_amdgcn_mfma_f32_16x16x32_bf16(aaf0, b0.v, acc, 0, 0, 0);
        acc = __builtin_amdgcn_mfma_f32_16x16x32_bf16(aaf1, b1.v, acc, 0, 0, 0);
        int gx = gxbase + jt * 16 + lcol;
        #pragma unroll
        for (int r = 0; r < 4; r++){
            __half hv = __float2half(acc[r]);
            logitsH[lb + (size_t)(p0 + r) * HW + gx] = *(unsigned short*)&hv;
        }
    }
}

// ---------------- K3: Sobel -> es, ori_x, ori_y + partial sums ----------------
__global__ __launch_bounds__(256) void k_sobel(const float* __restrict__ ei,
                                               float* __restrict__ es,
                                               float* __restrict__ ox,
                                               float* __restrict__ oy,
                                               float* __restrict__ part){
    int b = blockIdx.y, ch = blockIdx.x, t = threadIdx.x;
    const float* e = ei + (size_t)b * HW;
    float s1 = 0.f, s2 = 0.f;
    for (int i = 0; i < 4; i++){
        int l = ch * 1024 + i * 256 + t;
        int h = l >> 8, w = l & 255;
        float v[3][3];
        #pragma unroll
        for (int dh = -1; dh <= 1; dh++)
            #pragma unroll
            for (int dw = -1; dw <= 1; dw++){
                int hh = h + dh, ww = w + dw;
                v[dh+1][dw+1] = (hh >= 0 && hh < HEIGHT && ww >= 0 && ww < WIDTH)
                                ? e[hh * WIDTH + ww] : 0.f;
            }
        float gx = -v[0][0] + v[0][2] - 2.f*v[1][0] + 2.f*v[1][2] - v[2][0] + v[2][2];
        float gy = -v[0][0] - 2.f*v[0][1] - v[0][2] + v[2][0] + 2.f*v[2][1] + v[2][2];
        float g2 = gx*gx + gy*gy;
        float denom = g2 + 1e-6f;
        float esv = sqrtf(denom);
        size_t o = (size_t)b * HW + l;
        es[o] = esv;
        ox[o] = (gx*gx - gy*gy) / denom;
        oy[o] = 2.f * gx * gy / denom;
        s1 += esv; s2 += esv * esv;
    }
    __shared__ float r1[256], r2[256];
    r1[t] = s1; r2[t] = s2; __syncthreads();
    for (int s = 128; s > 0; s >>= 1){
        if (t < s){ r1[t] += r1[t+s]; r2[t] += r2[t+s]; }
        __syncthreads();
    }
    if (t == 0){ part[(b*64+ch)*2] = r1[0]; part[(b*64+ch)*2+1] = r2[0]; }
}

// ---------------- K4: stats fold + two-pass online softmax + bf16 weight write ----------------
__global__ __launch_bounds__(256) void k_softmax_w(
    const unsigned short* __restrict__ logitsH,
    const float* __restrict__ es, const float* __restrict__ ox, const float* __restrict__ oy,
    const float* __restrict__ part, const float* __restrict__ proto_orient,
    const float* __restrict__ topo_s, const float* __restrict__ orient_s,
    float* __restrict__ smpart, unsigned short* __restrict__ wbuf)
{
    int ch = blockIdx.x, b = blockIdx.y, t = threadIdx.x;
    __shared__ float sstat[3];
    __shared__ float pdl[32];
    __shared__ float Ml[16];
    __shared__ float rm[4][16], rs[4][16];
    if (t < 64){
        float s1 = part[(b*64 + t)*2], s2 = part[(b*64 + t)*2 + 1];
        #pragma unroll
        for (int off = 32; off >= 1; off >>= 1){
            s1 += __shfl_xor(s1, off, 64);
            s2 += __shfl_xor(s2, off, 64);
        }
        if (t == 0){
            float mean = s1 / 65536.f;
            float var = (s2 - 65536.f * mean * mean) / 65535.f;
            var = var > 0.f ? var : 0.f;
            sstat[0] = mean;
            sstat[1] = 1.f / (sqrtf(var) + 1e-5f);
            sstat[2] = 1.f / (mean + 1e-6f);
        }
    } else if (t < 80){
        int p = t - 64;
        float nx = proto_orient[p*2], ny = proto_orient[p*2+1];
        float n = sqrtf(nx*nx + ny*ny);
        n = n > 1e-12f ? n : 1e-12f;
        pdl[p*2] = nx / n; pdl[p*2+1] = ny / n;
    }
    __syncthreads();
    float mean = sstat[0], rstd = sstat[1], cinv = sstat[2];
    float topo = topo_s[0], orient = orient_s[0];
    float m[16], s[16];
    #pragma unroll
    for (int p = 0; p < 16; p++){ m[p] = -1e30f; s[p] = 0.f; }
    float ewv[2], oxv[2], oyv[2];
    for (int i = 0; i < 2; i++){
        int loff = ch * 512 + i * 256 + t;
        size_t gl = (size_t)b * HW + loff;
        float esv = es[gl];
        float cf = fminf(fmaxf(esv * cinv, 0.f), 3.f);
        ewv[i] = (esv - mean) * rstd;
        oxv[i] = ox[gl] * cf; oyv[i] = oy[gl] * cf;
        #pragma unroll
        for (int p = 0; p < 16; p++){
            __half hv = *(const __half*)&logitsH[(size_t)(b*16 + p) * HW + loff];
            float x = __half2float(hv) + topo * ewv[i]
                    + orient * (oxv[i]*pdl[p*2] + oyv[i]*pdl[p*2+1]);
            float mn = fmaxf(m[p], x);
            s[p] = s[p] * __expf(m[p] - mn) + __expf(x - mn);
            m[p] = mn;
        }
    }
    #pragma unroll
    for (int p = 0; p < 16; p++){
        #pragma unroll
        for (int off = 32; off >= 1; off >>= 1){
            float m2 = __shfl_xor(m[p], off, 64);
            float s2v = __shfl_xor(s[p], off, 64);
            float mn = fmaxf(m[p], m2);
            s[p] = s[p] * __expf(m[p] - mn) + s2v * __expf(m2 - mn);
            m[p] = mn;
        }
    }
    int wid = t >> 6;
    if ((t & 63) == 0){
        #pragma unroll
        for (int p = 0; p < 16; p++){ rm[wid][p] = m[p]; rs[wid][p] = s[p]; }
    }
    __syncthreads();
    if (t < 16){
        float M = -1e30f, S = 0.f;
        #pragma unroll
        for (int w2 = 0; w2 < 4; w2++){
            float mw = rm[w2][t], sw2 = rs[w2][t];
            float mn = fmaxf(M, mw);
            S = S * __expf(M - mn) + sw2 * __expf(mw - mn);
            M = mn;
        }
        smpart[((b*16 + t)*128 + ch)*2]     = M;
        smpart[((b*16 + t)*128 + ch)*2 + 1] = S;
        Ml[t] = M;
    }
    __syncthreads();
    // pass 2: w_ch = exp(x - M_ch) as bf16, layout [l][p] (p contiguous)
    for (int i = 0; i < 2; i++){
        int loff = ch * 512 + i * 256 + t;
        size_t gl = (size_t)b * HW + loff;
        unsigned int pk[8];
        #pragma unroll
        for (int p2 = 0; p2 < 8; p2++){
            int pa = p2*2, pb2 = p2*2 + 1;
            __half ha = *(const __half*)&logitsH[(size_t)(b*16 + pa)  * HW + loff];
            __half hb = *(const __half*)&logitsH[(size_t)(b*16 + pb2) * HW + loff];
            float xa = __half2float(ha) + topo*ewv[i]
                     + orient*(oxv[i]*pdl[pa*2]  + oyv[i]*pdl[pa*2+1]);
            float xb = __half2float(hb) + topo*ewv[i]
                     + orient*(oxv[i]*pdl[pb2*2] + oyv[i]*pdl[pb2*2+1]);
            pk[p2] = f2bf(__expf(xa - Ml[pa])) | (f2bf(__expf(xb - Ml[pb2])) << 16);
        }
        uint4* wp = (uint4*)&wbuf[gl * 16];
        wp[0] = make_uint4(pk[0], pk[1], pk[2], pk[3]);
        wp[1] = make_uint4(pk[4], pk[5], pk[6], pk[7]);
    }
}

// ---------------- K5: streaming prototype accumulation (no LDS hot loop) ----------------
__global__ __launch_bounds__(256) void k_proto(
    const unsigned short* __restrict__ wbuf, const float* __restrict__ key,
    const float* __restrict__ smpart, float* __restrict__ ppart)
{
    int ch2 = blockIdx.x, b = blockIdx.y, t = threadIdx.x;
    __shared__ float mm[16][17], ssb[16][17];
    __shared__ float fl[16];
    {
        int p = t & 15, grp = t >> 4;
        float M = -1e30f, S = 0.f;
        #pragma unroll
        for (int j = 0; j < 8; j++){
            int c8 = grp * 8 + j;
            float mw = smpart[((b*16 + p)*128 + c8)*2];
            float sw = smpart[((b*16 + p)*128 + c8)*2 + 1];
            float mn = fmaxf(M, mw);
            S = S * __expf(M - mn) + sw * __expf(mw - mn);
            M = mn;
        }
        mm[grp][p] = M; ssb[grp][p] = S;
    }
    __syncthreads();
    if (t < 16){
        float M = -1e30f, S = 0.f;
        #pragma unroll
        for (int g = 0; g < 16; g++){
            float mw = mm[g][t], sw = ssb[g][t];
            float mn = fmaxf(M, mw);
            S = S * __expf(M - mn) + sw * __expf(mw - mn);
            M = mn;
        }
        float Mch = smpart[((b*16 + t)*128 + ch2)*2];
        fl[t] = __expf(Mch - M) / S;
    }
    __syncthreads();
    int w = t >> 6, lane = t & 63, cg = lane & 15, pq = lane >> 4;
    size_t l0 = (size_t)b * HW + ch2 * 512 + w * 128;
    const float4* kp = (const float4*)key + l0 * 16 + cg;
    const unsigned short* wpp = wbuf + l0 * 16 + pq * 4;
    float acc[4][4];
    #pragma unroll
    for (int j = 0; j < 4; j++)
        #pragma unroll
        for (int i = 0; i < 4; i++) acc[j][i] = 0.f;
    #pragma unroll 4
    for (int i = 0; i < 128; i++){
        float4 kv = kp[i * 16];
        uint2 wp2 = *(const uint2*)&wpp[i * 16];
        float w0 = bfbits2f(wp2.x & 0xffffu);
        float w1 = bfbits2f(wp2.x >> 16);
        float w2 = bfbits2f(wp2.y & 0xffffu);
        float w3 = bfbits2f(wp2.y >> 16);
        acc[0][0] = fmaf(w0, kv.x, acc[0][0]); acc[0][1] = fmaf(w0, kv.y, acc[0][1]);
        acc[0][2] = fmaf(w0, kv.z, acc[0][2]); acc[0][3] = fmaf(w0, kv.w, acc[0][3]);
        acc[1][0] = fmaf(w1, kv.x, acc[1][0]); acc[1][1] = fmaf(w1, kv.y, acc[1][1]);
        acc[1][2] = fmaf(w1, kv.z, acc[1][2]); acc[1][3] = fmaf(w1, kv.w, acc[1][3]);
        acc[2][0] = fmaf(w2, kv.x, acc[2][0]); acc[2][1] = fmaf(w2, kv.y, acc[2][1]);
        acc[2][2] = fmaf(w2, kv.z, acc[2][2]); acc[2][3] = fmaf(w2, kv.w, acc[2][3]);
        acc[3][0] = fmaf(w3, kv.x, acc[3][0]); acc[3][1] = fmaf(w3, kv.y, acc[3][1]);
        acc[3][2] = fmaf(w3, kv.z, acc[3][2]); acc[3][3] = fmaf(w3, kv.w, acc[3][3]);
    }
    __shared__ float red[4][16][68];
    #pragma unroll
    for (int j = 0; j < 4; j++){
        float4 st = make_float4(acc[j][0], acc[j][1], acc[j][2], acc[j][3]);
        *(float4*)&red[w][pq*4 + j][cg*4] = st;
    }
    __syncthreads();
    size_t obase = ((size_t)(b * 128 + ch2)) * 1024;
    for (int idx = t; idx < 1024; idx += 256){
        int p = idx >> 6, c = idx & 63;
        float sum = red[0][p][c] + red[1][p][c] + red[2][p][c] + red[3][p][c];
        ppart[obase + idx] = sum * fl[p];
    }
}

// ---------------- K7: ppart reduce + gate MLPs + sigmoid + LayerNorm ----------------
__global__ __launch_bounds__(256) void k_gate(
    const float* __restrict__ ppart, const float* __restrict__ query,
    const float* __restrict__ w1, const float* __restrict__ bb1,
    const float* __restrict__ w2, const float* __restrict__ bb2,
    const float* __restrict__ gw1, const float* __restrict__ gb1,
    const float* __restrict__ gw2, const float* __restrict__ gb2,
    const float* __restrict__ lng, const float* __restrict__ lnb,
    float* __restrict__ out)
{
    __shared__ float z[16][64], h1[16][64], loc[16][64], g[64], hg[64], glb[64];
    int b = blockIdx.x, t = threadIdx.x;
    for (int idx = t; idx < 1024; idx += 256){
        const float* pp = ppart + (size_t)b * 128 * 1024 + idx;
        float sacc = 0.f;
        #pragma unroll 8
        for (int ch = 0; ch < 128; ch++) sacc += pp[(size_t)ch * 1024];
        z[idx >> 6][idx & 63] = sacc + query[b * 1024 + idx];
    }
    __syncthreads();
    for (int idx = t; idx < 1024; idx += 256){
        int p = idx >> 6, j = idx & 63;
        float acc = bb1[j];
        for (int i = 0; i < 64; i++) acc += z[p][i] * w1[j * 64 + i];
        h1[p][j] = relu_f(acc);
    }
    if (t < 64){
        float sg = 0.f;
        for (int p = 0; p < 16; p++) sg += z[p][t];
        g[t] = sg * (1.f / 16.f);
    }
    __syncthreads();
    for (int idx = t; idx < 1024; idx += 256){
        int p = idx >> 6, k = idx & 63;
        float acc = bb2[k];
        for (int j = 0; j < 64; j++) acc += h1[p][j] * w2[k * 64 + j];
        loc[p][k] = acc;
    }
    if (t < 64){
        float acc = gb1[t];
        for (int i = 0; i < 64; i++) acc += g[i] * gw1[t * 64 + i];
        hg[t] = relu_f(acc);
    }
    __syncthreads();
    if (t < 64){
        float acc = gb2[t];
        for (int j = 0; j < 64; j++) acc += hg[j] * gw2[t * 64 + j];
        glb[t] = acc;
    }
    __syncthreads();
    for (int idx = t; idx < 1024; idx += 256){
        int p = idx >> 6, c = idx & 63;
        float a = loc[p][c] + glb[c];
        float sg = 1.f / (1.f + expf(-a));
        float q = query[b * 1024 + idx];
        h1[p][c] = q * sg + q;
    }
    __syncthreads();
    if (t < 16){
        int p = t;
        float mu = 0.f;
        for (int c = 0; c < 64; c++) mu += h1[p][c];
        mu *= (1.f / 64.f);
        float var = 0.f;
        for (int c = 0; c < 64; c++){ float d = h1[p][c] - mu; var += d * d; }
        var *= (1.f / 64.f);
        float rstd = rsqrtf(var + 1e-5f);
        for (int c = 0; c < 64; c++)
            out[b * 1024 + p * 64 + c] = (h1[p][c] - mu) * rstd * lng[c] + lnb[c];
    }
}

extern "C" void kernel_launch(void* const* d_in, const int* in_sizes, int n_in,
                              void* d_out, int out_size, void* d_ws, size_t ws_size,
                              hipStream_t stream){
    (void)in_sizes; (void)n_in; (void)out_size; (void)ws_size;
    const float* feat   = (const float*)d_in[0];
    const float* query  = (const float*)d_in[1];
    const float* key    = (const float*)d_in[2];
    const float* dw_w   = (const float*)d_in[3];
    const float* bn1_g  = (const float*)d_in[4];
    const float* bn1_b  = (const float*)d_in[5];
    const float* bn1_m  = (const float*)d_in[6];
    const float* bn1_v  = (const float*)d_in[7];
    const float* pw_w   = (const float*)d_in[8];
    const float* bn2_g  = (const float*)d_in[9];
    const float* bn2_b  = (const float*)d_in[10];
    const float* bn2_m  = (const float*)d_in[11];
    const float* bn2_v  = (const float*)d_in[12];
    const float* aff_w  = (const float*)d_in[13];
    const float* loc_w1 = (const float*)d_in[14];
    const float* loc_b1 = (const float*)d_in[15];
    const float* loc_w2 = (const float*)d_in[16];
    const float* loc_b2 = (const float*)d_in[17];
    const float* glb_w1 = (const float*)d_in[18];
    const float* glb_b1 = (const float*)d_in[19];
    const float* glb_w2 = (const float*)d_in[20];
    const float* glb_b2 = (const float*)d_in[21];
    const float* ln_g   = (const float*)d_in[22];
    const float* ln_b   = (const float*)d_in[23];
    const float* topo   = (const float*)d_in[24];
    const float* orient = (const float*)d_in[25];
    const float* proto_orient = (const float*)d_in[26];
    float* out = (float*)d_out;
    float* ws  = (float*)d_ws;

    // workspace layout (f32 slots). ppart (written by K5) overlaps ei+es,
    // both of which are dead by then (stream-ordered, deterministic).
    float* ei      = ws;                      // 524288   [K2 -> K3]
    float* ppart   = ws;                      // 1048576  [K5 -> K7]
    float* es      = ws + 524288;             // 524288   [K3 -> K4]
    float* ox      = ws + 1048576;            // 524288
    float* oy      = ws + 1572864;            // 524288
    unsigned short* logitsH = (unsigned short*)(ws + 2097152);  // 8.39M ushort
    unsigned short* wbuf    = (unsigned short*)(ws + 6291456);  // 8.39M ushort
    float* k3part  = ws + 10485760;           // 1024
    float* smpart  = ws + 10486784;           // 32768 (8*16*128*2)
    float* scsh    = ws + 10519552;           // 256
    unsigned short* pwA  = (unsigned short*)(ws + 10519808);    // 4096 ushort
    unsigned short* affA = (unsigned short*)(ws + 10521856);    // 1024 ushort
    // total: 10,522,368 f32 = 42.1 MB

    k_prep<<<1, 256, 0, stream>>>(pw_w, aff_w, bn1_g, bn1_b, bn1_m, bn1_v,
                                  bn2_g, bn2_b, bn2_m, bn2_v, scsh, pwA, affA);
    k_conv_aff<<<4096, 256, 0, stream>>>(feat, dw_w, scsh, pwA, affA, logitsH, ei);
    k_sobel<<<dim3(64, 8), 256, 0, stream>>>(ei, es, ox, oy, k3part);
    k_softmax_w<<<dim3(128, 8), 256, 0, stream>>>(logitsH, es, ox, oy, k3part,
                                                  proto_orient, topo, orient,
                                                  smpart, wbuf);
    k_proto<<<dim3(128, 8), 256, 0, stream>>>(wbuf, key, smpart, ppart);
    k_gate<<<8, 256, 0, stream>>>(ppart, query, loc_w1, loc_b1, loc_w2, loc_b2,
                                  glb_w1, glb_b1, glb_w2, glb_b2, ln_g, ln_b, out);
}

// Round 5
// 179.828 us; speedup vs baseline: 3.0399x; 1.2845x over previous
//
#include <hip/hip_runtime.h>
#include <hip/hip_fp16.h>
#include <math.h>

#define HW     65536
#define WIDTH  256
#define HEIGHT 256

typedef __attribute__((ext_vector_type(8))) short bf16x8;
typedef __attribute__((ext_vector_type(4))) float f32x4;

__device__ __forceinline__ float relu_f(float x){ return x > 0.f ? x : 0.f; }
__device__ __forceinline__ unsigned int f2bf(float x){
    union { float f; unsigned int u; } v; v.f = x;
    unsigned int r = v.u + 0x7fffu + ((v.u >> 16) & 1u);   // RNE
    return r >> 16;
}
__device__ __forceinline__ float bfbits2f(unsigned int lo16){
    union { unsigned int u; float f; } v; v.u = lo16 << 16; return v.f;
}

// ---------------- K0: prep — fold BN, pack MFMA A-fragments ----------------
__global__ void k_prep(const float* __restrict__ pw_w, const float* __restrict__ aff_w,
                       const float* __restrict__ g1, const float* __restrict__ b1,
                       const float* __restrict__ m1, const float* __restrict__ v1,
                       const float* __restrict__ g2, const float* __restrict__ b2,
                       const float* __restrict__ m2, const float* __restrict__ v2,
                       float* __restrict__ scsh, unsigned short* __restrict__ pwA,
                       unsigned short* __restrict__ affA){
    int t = threadIdx.x;
    for (int i = t; i < 4096; i += 256){
        int e = i & 7, l = (i >> 3) & 63, ks = (i >> 9) & 1, ct = i >> 10;
        int co = ct * 16 + (l & 15);
        int ci = ks * 32 + (l >> 4) * 8 + e;
        pwA[i] = (unsigned short)f2bf(pw_w[co * 64 + ci]);
    }
    for (int i = t; i < 1024; i += 256){
        int e = i & 7, l = (i >> 3) & 63, ks = i >> 9;
        int p = l & 15, k = ks * 32 + (l >> 4) * 8 + e;
        affA[i] = (unsigned short)f2bf(aff_w[p * 64 + k]);
    }
    if (t < 64){
        float s = g1[t] * rsqrtf(v1[t] + 1e-5f);
        scsh[t]       = s;
        scsh[64 + t]  = b1[t] - m1[t] * s;
        float s2 = g2[t] * rsqrtf(v2[t] + 1e-5f);
        scsh[128 + t] = s2;
        scsh[192 + t] = b2[t] - m2[t] * s2;
    }
}

// ---------------- K2: full-row dw3x3 (float4 + shuffles) -> LDS bf16 (swz)
//                  -> MFMA pw -> MFMA affinity -> f16 logits ----------------
__global__ __launch_bounds__(256, 4) void k_conv_aff(
    const float* __restrict__ feat, const float* __restrict__ dw_w,
    const float* __restrict__ scsh, const unsigned short* __restrict__ pwA,
    const unsigned short* __restrict__ affA,
    unsigned short* __restrict__ logitsH, float* __restrict__ ei)
{
    __shared__ unsigned short x1u[256 * 68];   // [px][ci] bf16, stride 68 ushort
    __shared__ float eibuf[4][256];
    int t = threadIdx.x;
    int lane = t & 63;
    int wu = __builtin_amdgcn_readfirstlane(t >> 6);
    int orig = blockIdx.x;
    int flat = (orig & 7) * 256 + (orig >> 3);   // XCD-bijective (2048 = 8*256)
    int b = flat >> 8, h = flat & 255;

    // hoist MFMA A-fragments + BN2 params
    const bf16x8* pwA8 = (const bf16x8*)pwA;
    bf16x8 apw0 = pwA8[(wu * 2 + 0) * 64 + lane];
    bf16x8 apw1 = pwA8[(wu * 2 + 1) * 64 + lane];
    const bf16x8* affA8 = (const bf16x8*)affA;
    bf16x8 aaf0 = affA8[lane];
    bf16x8 aaf1 = affA8[64 + lane];
    int lcol = lane & 15, pq = lane >> 4;
    int cb = wu * 16 + pq * 4;
    float4 sc2v = *(const float4*)(scsh + 128 + cb);
    float4 sh2v = *(const float4*)(scsh + 192 + cb);

    // ---- phase A: depthwise 3x3 + BN1 + ReLU; 4 px/lane, 1 float4/(ci,row)
    int px0 = lane * 4;
    const float* fb = feat + (size_t)b * 64 * HW;
    int hh0 = (h > 0) ? h - 1 : 0;
    int hh2 = (h < 255) ? h + 1 : 255;
    float rw0 = (h > 0) ? 1.f : 0.f;
    float rw2 = (h < 255) ? 1.f : 0.f;
    int   roff0 = hh0 * WIDTH, roff1 = h * WIDTH, roff2 = hh2 * WIDTH;
    float mx = 0.f, my = 0.f, mz = 0.f, mw = 0.f;
    int swz = ((lane >> 2) & 7) << 1;            // dword-index XOR, bits 1-3
    #pragma unroll
    for (int cp = 0; cp < 8; cp++){
        int ci0 = wu * 16 + cp * 2;
        int ci1 = ci0 + 1;
        const float* base0 = fb + (size_t)ci0 * HW + px0;
        const float* base1 = fb + (size_t)ci1 * HW + px0;
        float a00=0.f,a01=0.f,a02=0.f,a03=0.f, a10=0.f,a11=0.f,a12=0.f,a13=0.f;
        #pragma unroll
        for (int r = 0; r < 3; r++){
            int roff = (r == 0) ? roff0 : ((r == 1) ? roff1 : roff2);
            float rwf = (r == 0) ? rw0 : ((r == 1) ? 1.f : rw2);
            float4 v0 = *(const float4*)(base0 + roff);
            float4 v1 = *(const float4*)(base1 + roff);
            float w00 = dw_w[ci0*9 + r*3 + 0] * rwf;
            float w01 = dw_w[ci0*9 + r*3 + 1] * rwf;
            float w02 = dw_w[ci0*9 + r*3 + 2] * rwf;
            float w10 = dw_w[ci1*9 + r*3 + 0] * rwf;
            float w11 = dw_w[ci1*9 + r*3 + 1] * rwf;
            float w12 = dw_w[ci1*9 + r*3 + 2] * rwf;
            float lf0 = __shfl_up(v0.w, 1);  if (lane == 0)  lf0 = 0.f;
            float rt0 = __shfl_down(v0.x, 1); if (lane == 63) rt0 = 0.f;
            float lf1 = __shfl_up(v1.w, 1);  if (lane == 0)  lf1 = 0.f;
            float rt1 = __shfl_down(v1.x, 1); if (lane == 63) rt1 = 0.f;
            a00 += lf0*w00 + v0.x*w01 + v0.y*w02;
            a01 += v0.x*w00 + v0.y*w01 + v0.z*w02;
            a02 += v0.y*w00 + v0.z*w01 + v0.w*w02;
            a03 += v0.z*w00 + v0.w*w01 + rt0*w02;
            a10 += lf1*w10 + v1.x*w11 + v1.y*w12;
            a11 += v1.x*w10 + v1.y*w11 + v1.z*w12;
            a12 += v1.y*w10 + v1.z*w11 + v1.w*w12;
            a13 += v1.z*w10 + v1.w*w11 + rt1*w12;
            if (r == 1){
                mx += v0.x + v1.x; my += v0.y + v1.y;
                mz += v0.z + v1.z; mw += v0.w + v1.w;
            }
        }
        float s0 = scsh[ci0], o0 = scsh[64 + ci0];
        float s1 = scsh[ci1], o1 = scsh[64 + ci1];
        int dwi = ((wu * 8 + cp) ^ swz) * 2;     // ushort offset within row
        unsigned int pk0 = f2bf(relu_f(fmaf(a00,s0,o0))) | (f2bf(relu_f(fmaf(a10,s1,o1))) << 16);
        unsigned int pk1 = f2bf(relu_f(fmaf(a01,s0,o0))) | (f2bf(relu_f(fmaf(a11,s1,o1))) << 16);
        unsigned int pk2 = f2bf(relu_f(fmaf(a02,s0,o0))) | (f2bf(relu_f(fmaf(a12,s1,o1))) << 16);
        unsigned int pk3 = f2bf(relu_f(fmaf(a03,s0,o0))) | (f2bf(relu_f(fmaf(a13,s1,o1))) << 16);
        *(unsigned int*)&x1u[(px0 + 0) * 68 + dwi] = pk0;
        *(unsigned int*)&x1u[(px0 + 1) * 68 + dwi] = pk1;
        *(unsigned int*)&x1u[(px0 + 2) * 68 + dwi] = pk2;
        *(unsigned int*)&x1u[(px0 + 3) * 68 + dwi] = pk3;
    }
    *(float4*)&eibuf[wu][px0] = make_float4(mx, my, mz, mw);
    __syncthreads();
    {
        float m = (eibuf[0][t] + eibuf[1][t]) + (eibuf[2][t] + eibuf[3][t]);
        ei[(size_t)b * HW + h * WIDTH + t] = m * (1.f / 64.f);
    }

    // ---- phase B: pw 1x1 GEMM (co-tile wu x 256 px x 64 ci), in-place y,
    //      two half-passes of 8 px-tiles (disjoint from writes of other half)
    int k0d = pq * 4;   // dword base of this lane's k-slice
    #pragma unroll
    for (int half = 0; half < 2; half++){
        f32x4 accB[8];
        #pragma unroll
        for (int q = 0; q < 8; q++){
            int jt = half * 8 + q;
            int swzj = (jt & 7) << 1;
            const unsigned short* rowp = &x1u[(jt * 16 + lcol) * 68];
            union { bf16x8 v; uint2 u[2]; } b0, b1;
            b0.u[0] = *(const uint2*)&rowp[((k0d)          ^ swzj) * 2];
            b0.u[1] = *(const uint2*)&rowp[((k0d + 2)      ^ swzj) * 2];
            b1.u[0] = *(const uint2*)&rowp[((16 + k0d)     ^ swzj) * 2];
            b1.u[1] = *(const uint2*)&rowp[((16 + k0d + 2) ^ swzj) * 2];
            f32x4 acc = {0.f, 0.f, 0.f, 0.f};
            acc = __builtin_amdgcn_mfma_f32_16x16x32_bf16(apw0, b0.v, acc, 0, 0, 0);
            acc = __builtin_amdgcn_mfma_f32_16x16x32_bf16(apw1, b1.v, acc, 0, 0, 0);
            accB[q] = acc;
        }
        __syncthreads();   // all reads of this half's tiles done
        #pragma unroll
        for (int q = 0; q < 8; q++){
            int jt = half * 8 + q;
            int swzj = (jt & 7) << 1;
            f32x4 acc = accB[q];
            unsigned int y0 = f2bf(relu_f(fmaf(acc[0], sc2v.x, sh2v.x)))
                            | (f2bf(relu_f(fmaf(acc[1], sc2v.y, sh2v.y))) << 16);
            unsigned int y1 = f2bf(relu_f(fmaf(acc[2], sc2v.z, sh2v.z)))
                            | (f2bf(relu_f(fmaf(acc[3], sc2v.w, sh2v.w))) << 16);
            int D = (wu * 8 + pq * 2) ^ swzj;
            *(uint2*)&x1u[(jt * 16 + lcol) * 68 + D * 2] = make_uint2(y0, y1);
        }
    }
    __syncthreads();   // y complete

    // ---- phase C: affinity GEMM (16p x px x 64co) -> f16 logits
    size_t lb = (size_t)(b * 16) * HW;
    int p0 = pq * 4;
    #pragma unroll
    for (int q = 0; q < 4; q++){
        int jt = wu * 4 + q;
        int swzj = (jt & 7) << 1;
        const unsigned short* rowp = &x1u[(jt * 16 + lcol) * 68];
        union { bf16x8 v; uint2 u[2]; } b0, b1;
        b0.u[0] = *(const uint2*)&rowp[((k0d)          ^ swzj) * 2];
        b0.u[1] = *(const uint2*)&rowp[((k0d + 2)      ^ swzj) * 2];
        b1.u[0] = *(const uint2*)&rowp[((16 + k0d)     ^ swzj) * 2];
        b1.u[1] = *(const uint2*)&rowp[((16 + k0d + 2) ^ swzj) * 2];
        f32x4 acc = {0.f, 0.f, 0.f, 0.f};
        acc = __builtin_amdgcn_mfma_f32_16x16x32_bf16(aaf0, b0.v, acc, 0, 0, 0);
        acc = __builtin_amdgcn_mfma_f32_16x16x32_bf16(aaf1, b1.v, acc, 0, 0, 0);
        int gx = h * WIDTH + jt * 16 + lcol;
        #pragma unroll
        for (int r = 0; r < 4; r++){
            __half hv = __float2half(acc[r]);
            logitsH[lb + (size_t)(p0 + r) * HW + gx] = *(unsigned short*)&hv;
        }
    }
}

// ---------------- K3: Sobel stats only (partial sums of es, es^2) ----------------
__global__ __launch_bounds__(256) void k_sobel_stats(const float* __restrict__ ei,
                                                     float* __restrict__ part){
    int b = blockIdx.y, ch = blockIdx.x, t = threadIdx.x;
    const float* e = ei + (size_t)b * HW;
    float s1 = 0.f, s2 = 0.f;
    for (int i = 0; i < 4; i++){
        int l = ch * 1024 + i * 256 + t;
        int h = l >> 8, w = l & 255;
        float v[3][3];
        #pragma unroll
        for (int dh = -1; dh <= 1; dh++)
            #pragma unroll
            for (int dw = -1; dw <= 1; dw++){
                int hh = h + dh, ww = w + dw;
                v[dh+1][dw+1] = (hh >= 0 && hh < HEIGHT && ww >= 0 && ww < WIDTH)
                                ? e[hh * WIDTH + ww] : 0.f;
            }
        float gx = -v[0][0] + v[0][2] - 2.f*v[1][0] + 2.f*v[1][2] - v[2][0] + v[2][2];
        float gy = -v[0][0] - 2.f*v[0][1] - v[0][2] + v[2][0] + 2.f*v[2][1] + v[2][2];
        float esv = sqrtf(gx*gx + gy*gy + 1e-6f);
        s1 += esv; s2 += esv * esv;
    }
    __shared__ float r1[256], r2[256];
    r1[t] = s1; r2[t] = s2; __syncthreads();
    for (int s = 128; s > 0; s >>= 1){
        if (t < s){ r1[t] += r1[t+s]; r2[t] += r2[t+s]; }
        __syncthreads();
    }
    if (t == 0){ part[(b*64+ch)*2] = r1[0]; part[(b*64+ch)*2+1] = r2[0]; }
}

// ---------------- K4: fused sobel-recompute + two-pass online softmax + bf16 w ----------------
__global__ __launch_bounds__(256) void k_softmax_w(
    const unsigned short* __restrict__ logitsH, const float* __restrict__ ei,
    const float* __restrict__ part, const float* __restrict__ proto_orient,
    const float* __restrict__ topo_s, const float* __restrict__ orient_s,
    float* __restrict__ smpart, unsigned short* __restrict__ wbuf)
{
    int ch = blockIdx.x, b = blockIdx.y, t = threadIdx.x;
    __shared__ float eit[4][258];
    __shared__ float sstat[3];
    __shared__ float pdl[32];
    __shared__ float Ml[16];
    __shared__ float rm[4][16], rs[4][16];
    // ei tile rows 2ch-1 .. 2ch+2 (zero outside image), zero side columns
    for (int i = t; i < 1024; i += 256){
        int r = i >> 8, c = i & 255;
        int row = 2 * ch - 1 + r;
        eit[r][c + 1] = (row >= 0 && row < 256) ? ei[(size_t)b * HW + row * 256 + c] : 0.f;
    }
    if (t >= 128 && t < 136){
        int q = t - 128;
        eit[q >> 1][(q & 1) * 257] = 0.f;
    }
    if (t < 64){
        float s1 = part[(b*64 + t)*2], s2 = part[(b*64 + t)*2 + 1];
        #pragma unroll
        for (int off = 32; off >= 1; off >>= 1){
            s1 += __shfl_xor(s1, off, 64);
            s2 += __shfl_xor(s2, off, 64);
        }
        if (t == 0){
            float mean = s1 / 65536.f;
            float var = (s2 - 65536.f * mean * mean) / 65535.f;
            var = var > 0.f ? var : 0.f;
            sstat[0] = mean;
            sstat[1] = 1.f / (sqrtf(var) + 1e-5f);
            sstat[2] = 1.f / (mean + 1e-6f);
        }
    } else if (t >= 64 && t < 80){
        int p = t - 64;
        float nx = proto_orient[p*2], ny = proto_orient[p*2+1];
        float n = sqrtf(nx*nx + ny*ny);
        n = n > 1e-12f ? n : 1e-12f;
        pdl[p*2] = nx / n; pdl[p*2+1] = ny / n;
    }
    __syncthreads();
    float mean = sstat[0], rstd = sstat[1], cinv = sstat[2];
    float topo = topo_s[0], orient = orient_s[0];
    float m[16], s[16];
    #pragma unroll
    for (int p = 0; p < 16; p++){ m[p] = -1e30f; s[p] = 0.f; }
    float ewv[2], oxv[2], oyv[2];
    #pragma unroll
    for (int i = 0; i < 2; i++){
        int hl = i + 1, w = t;
        float vmm = eit[hl-1][w], vm0 = eit[hl-1][w+1], vmp = eit[hl-1][w+2];
        float v0m = eit[hl][w],                          v0p = eit[hl][w+2];
        float vpm = eit[hl+1][w], vp0 = eit[hl+1][w+1], vpp = eit[hl+1][w+2];
        float gx = vmp - vmm + 2.f*(v0p - v0m) + vpp - vpm;
        float gy = vpm + 2.f*vp0 + vpp - vmm - 2.f*vm0 - vmp;
        float denom = gx*gx + gy*gy + 1e-6f;
        float esv = sqrtf(denom);
        float cf = fminf(fmaxf(esv * cinv, 0.f), 3.f);
        ewv[i] = (esv - mean) * rstd;
        oxv[i] = ((gx*gx - gy*gy) / denom) * cf;
        oyv[i] = (2.f * gx * gy / denom) * cf;
        int loff = ch * 512 + i * 256 + t;
        #pragma unroll
        for (int p = 0; p < 16; p++){
            __half hv = *(const __half*)&logitsH[(size_t)(b*16 + p) * HW + loff];
            float x = __half2float(hv) + topo * ewv[i]
                    + orient * (oxv[i]*pdl[p*2] + oyv[i]*pdl[p*2+1]);
            float mn = fmaxf(m[p], x);
            s[p] = s[p] * __expf(m[p] - mn) + __expf(x - mn);
            m[p] = mn;
        }
    }
    #pragma unroll
    for (int p = 0; p < 16; p++){
        #pragma unroll
        for (int off = 32; off >= 1; off >>= 1){
            float m2 = __shfl_xor(m[p], off, 64);
            float s2v = __shfl_xor(s[p], off, 64);
            float mn = fmaxf(m[p], m2);
            s[p] = s[p] * __expf(m[p] - mn) + s2v * __expf(m2 - mn);
            m[p] = mn;
        }
    }
    int wid = t >> 6;
    if ((t & 63) == 0){
        #pragma unroll
        for (int p = 0; p < 16; p++){ rm[wid][p] = m[p]; rs[wid][p] = s[p]; }
    }
    __syncthreads();
    if (t < 16){
        float M = -1e30f, S = 0.f;
        #pragma unroll
        for (int w2 = 0; w2 < 4; w2++){
            float mw = rm[w2][t], sw2 = rs[w2][t];
            float mn = fmaxf(M, mw);
            S = S * __expf(M - mn) + sw2 * __expf(mw - mn);
            M = mn;
        }
        smpart[((b*16 + t)*128 + ch)*2]     = M;
        smpart[((b*16 + t)*128 + ch)*2 + 1] = S;
        Ml[t] = M;
    }
    __syncthreads();
    // pass 2: w_ch = exp(x - M_ch) as bf16, layout [l][p]
    #pragma unroll
    for (int i = 0; i < 2; i++){
        int loff = ch * 512 + i * 256 + t;
        size_t gl = (size_t)b * HW + loff;
        unsigned int pk[8];
        #pragma unroll
        for (int p2 = 0; p2 < 8; p2++){
            int pa = p2*2, pb2 = p2*2 + 1;
            __half ha = *(const __half*)&logitsH[(size_t)(b*16 + pa)  * HW + loff];
            __half hb = *(const __half*)&logitsH[(size_t)(b*16 + pb2) * HW + loff];
            float xa = __half2float(ha) + topo*ewv[i]
                     + orient*(oxv[i]*pdl[pa*2]  + oyv[i]*pdl[pa*2+1]);
            float xb = __half2float(hb) + topo*ewv[i]
                     + orient*(oxv[i]*pdl[pb2*2] + oyv[i]*pdl[pb2*2+1]);
            pk[p2] = f2bf(__expf(xa - Ml[pa])) | (f2bf(__expf(xb - Ml[pb2])) << 16);
        }
        uint4* wp = (uint4*)&wbuf[gl * 16];
        wp[0] = make_uint4(pk[0], pk[1], pk[2], pk[3]);
        wp[1] = make_uint4(pk[4], pk[5], pk[6], pk[7]);
    }
}

// ---------------- K5: streaming prototype accumulation ----------------
__global__ __launch_bounds__(256) void k_proto(
    const unsigned short* __restrict__ wbuf, const float* __restrict__ key,
    const float* __restrict__ smpart, float* __restrict__ ppart)
{
    int ch2 = blockIdx.x, b = blockIdx.y, t = threadIdx.x;
    __shared__ float mm[16][17], ssb[16][17];
    __shared__ float fl[16];
    {
        int p = t & 15, grp = t >> 4;
        float M = -1e30f, S = 0.f;
        #pragma unroll
        for (int j = 0; j < 8; j++){
            int c8 = grp * 8 + j;
            float mw = smpart[((b*16 + p)*128 + c8)*2];
            float sw = smpart[((b*16 + p)*128 + c8)*2 + 1];
            float mn = fmaxf(M, mw);
            S = S * __expf(M - mn) + sw * __expf(mw - mn);
            M = mn;
        }
        mm[grp][p] = M; ssb[grp][p] = S;
    }
    __syncthreads();
    if (t < 16){
        float M = -1e30f, S = 0.f;
        #pragma unroll
        for (int g = 0; g < 16; g++){
            float mw = mm[g][t], sw = ssb[g][t];
            float mn = fmaxf(M, mw);
            S = S * __expf(M - mn) + sw * __expf(mw - mn);
            M = mn;
        }
        float Mch = smpart[((b*16 + t)*128 + ch2)*2];
        fl[t] = __expf(Mch - M) / S;
    }
    __syncthreads();
    int w = t >> 6, lane = t & 63, cg = lane & 15, pq = lane >> 4;
    size_t l0 = (size_t)b * HW + ch2 * 512 + w * 128;
    const float4* kp = (const float4*)key + l0 * 16 + cg;
    const unsigned short* wpp = wbuf + l0 * 16 + pq * 4;
    float acc[4][4];
    #pragma unroll
    for (int j = 0; j < 4; j++)
        #pragma unroll
        for (int i = 0; i < 4; i++) acc[j][i] = 0.f;
    #pragma unroll 4
    for (int i = 0; i < 128; i++){
        float4 kv = kp[i * 16];
        uint2 wp2 = *(const uint2*)&wpp[i * 16];
        float w0 = bfbits2f(wp2.x & 0xffffu);
        float w1 = bfbits2f(wp2.x >> 16);
        float w2 = bfbits2f(wp2.y & 0xffffu);
        float w3 = bfbits2f(wp2.y >> 16);
        acc[0][0] = fmaf(w0, kv.x, acc[0][0]); acc[0][1] = fmaf(w0, kv.y, acc[0][1]);
        acc[0][2] = fmaf(w0, kv.z, acc[0][2]); acc[0][3] = fmaf(w0, kv.w, acc[0][3]);
        acc[1][0] = fmaf(w1, kv.x, acc[1][0]); acc[1][1] = fmaf(w1, kv.y, acc[1][1]);
        acc[1][2] = fmaf(w1, kv.z, acc[1][2]); acc[1][3] = fmaf(w1, kv.w, acc[1][3]);
        acc[2][0] = fmaf(w2, kv.x, acc[2][0]); acc[2][1] = fmaf(w2, kv.y, acc[2][1]);
        acc[2][2] = fmaf(w2, kv.z, acc[2][2]); acc[2][3] = fmaf(w2, kv.w, acc[2][3]);
        acc[3][0] = fmaf(w3, kv.x, acc[3][0]); acc[3][1] = fmaf(w3, kv.y, acc[3][1]);
        acc[3][2] = fmaf(w3, kv.z, acc[3][2]); acc[3][3] = fmaf(w3, kv.w, acc[3][3]);
    }
    __shared__ float red[4][16][68];
    #pragma unroll
    for (int j = 0; j < 4; j++){
        float4 st = make_float4(acc[j][0], acc[j][1], acc[j][2], acc[j][3]);
        *(float4*)&red[w][pq*4 + j][cg*4] = st;
    }
    __syncthreads();
    size_t obase = ((size_t)(b * 128 + ch2)) * 1024;
    for (int idx = t; idx < 1024; idx += 256){
        int p = idx >> 6;
        float sum = red[0][p][idx & 63] + red[1][p][idx & 63]
                  + red[2][p][idx & 63] + red[3][p][idx & 63];
        ppart[obase + idx] = sum * fl[p];
    }
}

// ---------------- K7: ppart reduce + gate MLPs + sigmoid + LayerNorm ----------------
__global__ __launch_bounds__(256) void k_gate(
    const float* __restrict__ ppart, const float* __restrict__ query,
    const float* __restrict__ w1, const float* __restrict__ bb1,
    const float* __restrict__ w2, const float* __restrict__ bb2,
    const float* __restrict__ gw1, const float* __restrict__ gb1,
    const float* __restrict__ gw2, const float* __restrict__ gb2,
    const float* __restrict__ lng, const float* __restrict__ lnb,
    float* __restrict__ out)
{
    __shared__ float z[16][64], h1[16][64], loc[16][64], g[64], hg[64], glb[64];
    int b = blockIdx.x, t = threadIdx.x;
    for (int idx = t; idx < 1024; idx += 256){
        const float* pp = ppart + (size_t)b * 128 * 1024 + idx;
        float sacc = 0.f;
        #pragma unroll 8
        for (int ch = 0; ch < 128; ch++) sacc += pp[(size_t)ch * 1024];
        z[idx >> 6][idx & 63] = sacc + query[b * 1024 + idx];
    }
    __syncthreads();
    for (int idx = t; idx < 1024; idx += 256){
        int p = idx >> 6, j = idx & 63;
        float acc = bb1[j];
        for (int i = 0; i < 64; i++) acc += z[p][i] * w1[j * 64 + i];
        h1[p][j] = relu_f(acc);
    }
    if (t < 64){
        float sg = 0.f;
        for (int p = 0; p < 16; p++) sg += z[p][t];
        g[t] = sg * (1.f / 16.f);
    }
    __syncthreads();
    for (int idx = t; idx < 1024; idx += 256){
        int p = idx >> 6, k = idx & 63;
        float acc = bb2[k];
        for (int j = 0; j < 64; j++) acc += h1[p][j] * w2[k * 64 + j];
        loc[p][k] = acc;
    }
    if (t < 64){
        float acc = gb1[t];
        for (int i = 0; i < 64; i++) acc += g[i] * gw1[t * 64 + i];
        hg[t] = relu_f(acc);
    }
    __syncthreads();
    if (t < 64){
        float acc = gb2[t];
        for (int j = 0; j < 64; j++) acc += hg[j] * gw2[t * 64 + j];
        glb[t] = acc;
    }
    __syncthreads();
    for (int idx = t; idx < 1024; idx += 256){
        int p = idx >> 6, c = idx & 63;
        float a = loc[p][c] + glb[c];
        float sg = 1.f / (1.f + expf(-a));
        float q = query[b * 1024 + idx];
        h1[p][c] = q * sg + q;
    }
    __syncthreads();
    if (t < 16){
        int p = t;
        float mu = 0.f;
        for (int c = 0; c < 64; c++) mu += h1[p][c];
        mu *= (1.f / 64.f);
        float var = 0.f;
        for (int c = 0; c < 64; c++){ float d = h1[p][c] - mu; var += d * d; }
        var *= (1.f / 64.f);
        float rstd = rsqrtf(var + 1e-5f);
        for (int c = 0; c < 64; c++)
            out[b * 1024 + p * 64 + c] = (h1[p][c] - mu) * rstd * lng[c] + lnb[c];
    }
}

extern "C" void kernel_launch(void* const* d_in, const int* in_sizes, int n_in,
                              void* d_out, int out_size, void* d_ws, size_t ws_size,
                              hipStream_t stream){
    (void)in_sizes; (void)n_in; (void)out_size; (void)ws_size;
    const float* feat   = (const float*)d_in[0];
    const float* query  = (const float*)d_in[1];
    const float* key    = (const float*)d_in[2];
    const float* dw_w   = (const float*)d_in[3];
    const float* bn1_g  = (const float*)d_in[4];
    const float* bn1_b  = (const float*)d_in[5];
    const float* bn1_m  = (const float*)d_in[6];
    const float* bn1_v  = (const float*)d_in[7];
    const float* pw_w   = (const float*)d_in[8];
    const float* bn2_g  = (const float*)d_in[9];
    const float* bn2_b  = (const float*)d_in[10];
    const float* bn2_m  = (const float*)d_in[11];
    const float* bn2_v  = (const float*)d_in[12];
    const float* aff_w  = (const float*)d_in[13];
    const float* loc_w1 = (const float*)d_in[14];
    const float* loc_b1 = (const float*)d_in[15];
    const float* loc_w2 = (const float*)d_in[16];
    const float* loc_b2 = (const float*)d_in[17];
    const float* glb_w1 = (const float*)d_in[18];
    const float* glb_b1 = (const float*)d_in[19];
    const float* glb_w2 = (const float*)d_in[20];
    const float* glb_b2 = (const float*)d_in[21];
    const float* ln_g   = (const float*)d_in[22];
    const float* ln_b   = (const float*)d_in[23];
    const float* topo   = (const float*)d_in[24];
    const float* orient = (const float*)d_in[25];
    const float* proto_orient = (const float*)d_in[26];
    float* out = (float*)d_out;
    float* ws  = (float*)d_ws;

    // workspace (f32 slots). ppart (K5 output) overlaps ei (dead after K4).
    float* ei      = ws;                                       // 524288
    float* ppart   = ws;                                       // 1048576
    unsigned short* logitsH = (unsigned short*)(ws + 1048576); // 8,388,608 ushort
    unsigned short* wbuf    = (unsigned short*)(ws + 5242880); // 8,388,608 ushort
    float* k3part  = ws + 9437184;                             // 1024
    float* smpart  = ws + 9438208;                             // 32768
    float* scsh    = ws + 9470976;                             // 256
    unsigned short* pwA  = (unsigned short*)(ws + 9471232);    // 4096 ushort
    unsigned short* affA = (unsigned short*)(ws + 9473280);    // 1024 ushort
    // total ~9,473,792 f32 = 37.9 MB

    k_prep<<<1, 256, 0, stream>>>(pw_w, aff_w, bn1_g, bn1_b, bn1_m, bn1_v,
                                  bn2_g, bn2_b, bn2_m, bn2_v, scsh, pwA, affA);
    k_conv_aff<<<2048, 256, 0, stream>>>(feat, dw_w, scsh, pwA, affA, logitsH, ei);
    k_sobel_stats<<<dim3(64, 8), 256, 0, stream>>>(ei, k3part);
    k_softmax_w<<<dim3(128, 8), 256, 0, stream>>>(logitsH, ei, k3part,
                                                  proto_orient, topo, orient,
                                                  smpart, wbuf);
    k_proto<<<dim3(128, 8), 256, 0, stream>>>(wbuf, key, smpart, ppart);
    k_gate<<<8, 256, 0, stream>>>(ppart, query, loc_w1, loc_b1, loc_w2, loc_b2,
                                  glb_w1, glb_b1, glb_w2, glb_b2, ln_g, ln_b, out);
}

// Round 6
// 175.137 us; speedup vs baseline: 3.1213x; 1.0268x over previous
//
#include <hip/hip_runtime.h>
#include <hip/hip_fp16.h>
#include <math.h>

#define HW     65536
#define WIDTH  256
#define HEIGHT 256

typedef __attribute__((ext_vector_type(8))) short bf16x8;
typedef __attribute__((ext_vector_type(4))) float f32x4;

__device__ __forceinline__ float relu_f(float x){ return x > 0.f ? x : 0.f; }
__device__ __forceinline__ unsigned int f2bf(float x){
    union { float f; unsigned int u; } v; v.f = x;
    unsigned int r = v.u + 0x7fffu + ((v.u >> 16) & 1u);   // RNE
    return r >> 16;
}
__device__ __forceinline__ float bfbits2f(unsigned int lo16){
    union { unsigned int u; float f; } v; v.u = lo16 << 16; return v.f;
}
__device__ __forceinline__ float h2f(unsigned int bits16){
    __half h = *(__half*)&bits16; return __half2float(h);
}

// ---------------- K0: prep — fold BN, pack MFMA A-fragments ----------------
__global__ void k_prep(const float* __restrict__ pw_w, const float* __restrict__ aff_w,
                       const float* __restrict__ g1, const float* __restrict__ b1,
                       const float* __restrict__ m1, const float* __restrict__ v1,
                       const float* __restrict__ g2, const float* __restrict__ b2,
                       const float* __restrict__ m2, const float* __restrict__ v2,
                       float* __restrict__ scsh, unsigned short* __restrict__ pwA,
                       unsigned short* __restrict__ affA){
    int t = threadIdx.x;
    for (int i = t; i < 4096; i += 256){
        int e = i & 7, l = (i >> 3) & 63, ks = (i >> 9) & 1, ct = i >> 10;
        int co = ct * 16 + (l & 15);
        int ci = ks * 32 + (l >> 4) * 8 + e;
        pwA[i] = (unsigned short)f2bf(pw_w[co * 64 + ci]);
    }
    for (int i = t; i < 1024; i += 256){
        int e = i & 7, l = (i >> 3) & 63, ks = i >> 9;
        int p = l & 15, k = ks * 32 + (l >> 4) * 8 + e;
        affA[i] = (unsigned short)f2bf(aff_w[p * 64 + k]);
    }
    if (t < 64){
        float s = g1[t] * rsqrtf(v1[t] + 1e-5f);
        scsh[t]       = s;
        scsh[64 + t]  = b1[t] - m1[t] * s;
        float s2 = g2[t] * rsqrtf(v2[t] + 1e-5f);
        scsh[128 + t] = s2;
        scsh[192 + t] = b2[t] - m2[t] * s2;
    }
}

// ---------------- K2: full-row dw3x3 (float4 + shuffles) -> LDS bf16 (swz)
//                  -> MFMA pw -> MFMA affinity -> f16 logits [b][l][16] ----------------
__global__ __launch_bounds__(256, 4) void k_conv_aff(
    const float* __restrict__ feat, const float* __restrict__ dw_w,
    const float* __restrict__ scsh, const unsigned short* __restrict__ pwA,
    const unsigned short* __restrict__ affA,
    unsigned short* __restrict__ logitsH, float* __restrict__ ei)
{
    __shared__ unsigned short x1u[256 * 68];
    __shared__ float eibuf[4][256];
    int t = threadIdx.x;
    int lane = t & 63;
    int wu = __builtin_amdgcn_readfirstlane(t >> 6);
    int orig = blockIdx.x;
    int flat = (orig & 7) * 256 + (orig >> 3);   // XCD-bijective (2048 = 8*256)
    int b = flat >> 8, h = flat & 255;

    const bf16x8* pwA8 = (const bf16x8*)pwA;
    bf16x8 apw0 = pwA8[(wu * 2 + 0) * 64 + lane];
    bf16x8 apw1 = pwA8[(wu * 2 + 1) * 64 + lane];
    const bf16x8* affA8 = (const bf16x8*)affA;
    bf16x8 aaf0 = affA8[lane];
    bf16x8 aaf1 = affA8[64 + lane];
    int lcol = lane & 15, pq = lane >> 4;
    int cb = wu * 16 + pq * 4;
    float4 sc2v = *(const float4*)(scsh + 128 + cb);
    float4 sh2v = *(const float4*)(scsh + 192 + cb);

    // ---- phase A
    int px0 = lane * 4;
    const float* fb = feat + (size_t)b * 64 * HW;
    int hh0 = (h > 0) ? h - 1 : 0;
    int hh2 = (h < 255) ? h + 1 : 255;
    float rw0 = (h > 0) ? 1.f : 0.f;
    float rw2 = (h < 255) ? 1.f : 0.f;
    int   roff0 = hh0 * WIDTH, roff1 = h * WIDTH, roff2 = hh2 * WIDTH;
    float mx = 0.f, my = 0.f, mz = 0.f, mw = 0.f;
    int swz = ((lane >> 2) & 7) << 1;
    #pragma unroll
    for (int cp = 0; cp < 8; cp++){
        int ci0 = wu * 16 + cp * 2;
        int ci1 = ci0 + 1;
        const float* base0 = fb + (size_t)ci0 * HW + px0;
        const float* base1 = fb + (size_t)ci1 * HW + px0;
        float a00=0.f,a01=0.f,a02=0.f,a03=0.f, a10=0.f,a11=0.f,a12=0.f,a13=0.f;
        #pragma unroll
        for (int r = 0; r < 3; r++){
            int roff = (r == 0) ? roff0 : ((r == 1) ? roff1 : roff2);
            float rwf = (r == 0) ? rw0 : ((r == 1) ? 1.f : rw2);
            float4 v0 = *(const float4*)(base0 + roff);
            float4 v1 = *(const float4*)(base1 + roff);
            float w00 = dw_w[ci0*9 + r*3 + 0] * rwf;
            float w01 = dw_w[ci0*9 + r*3 + 1] * rwf;
            float w02 = dw_w[ci0*9 + r*3 + 2] * rwf;
            float w10 = dw_w[ci1*9 + r*3 + 0] * rwf;
            float w11 = dw_w[ci1*9 + r*3 + 1] * rwf;
            float w12 = dw_w[ci1*9 + r*3 + 2] * rwf;
            float lf0 = __shfl_up(v0.w, 1);  if (lane == 0)  lf0 = 0.f;
            float rt0 = __shfl_down(v0.x, 1); if (lane == 63) rt0 = 0.f;
            float lf1 = __shfl_up(v1.w, 1);  if (lane == 0)  lf1 = 0.f;
            float rt1 = __shfl_down(v1.x, 1); if (lane == 63) rt1 = 0.f;
            a00 += lf0*w00 + v0.x*w01 + v0.y*w02;
            a01 += v0.x*w00 + v0.y*w01 + v0.z*w02;
            a02 += v0.y*w00 + v0.z*w01 + v0.w*w02;
            a03 += v0.z*w00 + v0.w*w01 + rt0*w02;
            a10 += lf1*w10 + v1.x*w11 + v1.y*w12;
            a11 += v1.x*w10 + v1.y*w11 + v1.z*w12;
            a12 += v1.y*w10 + v1.z*w11 + v1.w*w12;
            a13 += v1.z*w10 + v1.w*w11 + rt1*w12;
            if (r == 1){
                mx += v0.x + v1.x; my += v0.y + v1.y;
                mz += v0.z + v1.z; mw += v0.w + v1.w;
            }
        }
        float s0 = scsh[ci0], o0 = scsh[64 + ci0];
        float s1 = scsh[ci1], o1 = scsh[64 + ci1];
        int dwi = ((wu * 8 + cp) ^ swz) * 2;
        unsigned int pk0 = f2bf(relu_f(fmaf(a00,s0,o0))) | (f2bf(relu_f(fmaf(a10,s1,o1))) << 16);
        unsigned int pk1 = f2bf(relu_f(fmaf(a01,s0,o0))) | (f2bf(relu_f(fmaf(a11,s1,o1))) << 16);
        unsigned int pk2 = f2bf(relu_f(fmaf(a02,s0,o0))) | (f2bf(relu_f(fmaf(a12,s1,o1))) << 16);
        unsigned int pk3 = f2bf(relu_f(fmaf(a03,s0,o0))) | (f2bf(relu_f(fmaf(a13,s1,o1))) << 16);
        *(unsigned int*)&x1u[(px0 + 0) * 68 + dwi] = pk0;
        *(unsigned int*)&x1u[(px0 + 1) * 68 + dwi] = pk1;
        *(unsigned int*)&x1u[(px0 + 2) * 68 + dwi] = pk2;
        *(unsigned int*)&x1u[(px0 + 3) * 68 + dwi] = pk3;
    }
    *(float4*)&eibuf[wu][px0] = make_float4(mx, my, mz, mw);
    __syncthreads();
    {
        float m = (eibuf[0][t] + eibuf[1][t]) + (eibuf[2][t] + eibuf[3][t]);
        ei[(size_t)b * HW + h * WIDTH + t] = m * (1.f / 64.f);
    }

    // ---- phase B
    int k0d = pq * 4;
    #pragma unroll
    for (int half = 0; half < 2; half++){
        f32x4 accB[8];
        #pragma unroll
        for (int q = 0; q < 8; q++){
            int jt = half * 8 + q;
            int swzj = (jt & 7) << 1;
            const unsigned short* rowp = &x1u[(jt * 16 + lcol) * 68];
            union { bf16x8 v; uint2 u[2]; } b0, b1;
            b0.u[0] = *(const uint2*)&rowp[((k0d)          ^ swzj) * 2];
            b0.u[1] = *(const uint2*)&rowp[((k0d + 2)      ^ swzj) * 2];
            b1.u[0] = *(const uint2*)&rowp[((16 + k0d)     ^ swzj) * 2];
            b1.u[1] = *(const uint2*)&rowp[((16 + k0d + 2) ^ swzj) * 2];
            f32x4 acc = {0.f, 0.f, 0.f, 0.f};
            acc = __builtin_amdgcn_mfma_f32_16x16x32_bf16(apw0, b0.v, acc, 0, 0, 0);
            acc = __builtin_amdgcn_mfma_f32_16x16x32_bf16(apw1, b1.v, acc, 0, 0, 0);
            accB[q] = acc;
        }
        __syncthreads();
        #pragma unroll
        for (int q = 0; q < 8; q++){
            int jt = half * 8 + q;
            int swzj = (jt & 7) << 1;
            f32x4 acc = accB[q];
            unsigned int y0 = f2bf(relu_f(fmaf(acc[0], sc2v.x, sh2v.x)))
                            | (f2bf(relu_f(fmaf(acc[1], sc2v.y, sh2v.y))) << 16);
            unsigned int y1 = f2bf(relu_f(fmaf(acc[2], sc2v.z, sh2v.z)))
                            | (f2bf(relu_f(fmaf(acc[3], sc2v.w, sh2v.w))) << 16);
            int D = (wu * 8 + pq * 2) ^ swzj;
            *(uint2*)&x1u[(jt * 16 + lcol) * 68 + D * 2] = make_uint2(y0, y1);
        }
    }
    __syncthreads();

    // ---- phase C: affinity GEMM -> f16 logits, layout [b][l][16p]
    int p0 = pq * 4;
    #pragma unroll
    for (int q = 0; q < 4; q++){
        int jt = wu * 4 + q;
        int swzj = (jt & 7) << 1;
        const unsigned short* rowp = &x1u[(jt * 16 + lcol) * 68];
        union { bf16x8 v; uint2 u[2]; } b0, b1;
        b0.u[0] = *(const uint2*)&rowp[((k0d)          ^ swzj) * 2];
        b0.u[1] = *(const uint2*)&rowp[((k0d + 2)      ^ swzj) * 2];
        b1.u[0] = *(const uint2*)&rowp[((16 + k0d)     ^ swzj) * 2];
        b1.u[1] = *(const uint2*)&rowp[((16 + k0d + 2) ^ swzj) * 2];
        f32x4 acc = {0.f, 0.f, 0.f, 0.f};
        acc = __builtin_amdgcn_mfma_f32_16x16x32_bf16(aaf0, b0.v, acc, 0, 0, 0);
        acc = __builtin_amdgcn_mfma_f32_16x16x32_bf16(aaf1, b1.v, acc, 0, 0, 0);
        int gx = h * WIDTH + jt * 16 + lcol;
        __half h0 = __float2half(acc[0]), h1v = __float2half(acc[1]);
        __half h2 = __float2half(acc[2]), h3v = __float2half(acc[3]);
        unsigned int u0 = (unsigned int)(*(unsigned short*)&h0)
                        | ((unsigned int)(*(unsigned short*)&h1v) << 16);
        unsigned int u1 = (unsigned int)(*(unsigned short*)&h2)
                        | ((unsigned int)(*(unsigned short*)&h3v) << 16);
        *(uint2*)&logitsH[((size_t)b * HW + gx) * 16 + p0] = make_uint2(u0, u1);
    }
}

// ---------------- K3: Sobel stats only ----------------
__global__ __launch_bounds__(256) void k_sobel_stats(const float* __restrict__ ei,
                                                     float* __restrict__ part){
    int b = blockIdx.y, ch = blockIdx.x, t = threadIdx.x;
    const float* e = ei + (size_t)b * HW;
    float s1 = 0.f, s2 = 0.f;
    for (int i = 0; i < 4; i++){
        int l = ch * 1024 + i * 256 + t;
        int h = l >> 8, w = l & 255;
        float v[3][3];
        #pragma unroll
        for (int dh = -1; dh <= 1; dh++)
            #pragma unroll
            for (int dw = -1; dw <= 1; dw++){
                int hh = h + dh, ww = w + dw;
                v[dh+1][dw+1] = (hh >= 0 && hh < HEIGHT && ww >= 0 && ww < WIDTH)
                                ? e[hh * WIDTH + ww] : 0.f;
            }
        float gx = -v[0][0] + v[0][2] - 2.f*v[1][0] + 2.f*v[1][2] - v[2][0] + v[2][2];
        float gy = -v[0][0] - 2.f*v[0][1] - v[0][2] + v[2][0] + 2.f*v[2][1] + v[2][2];
        float esv = sqrtf(gx*gx + gy*gy + 1e-6f);
        s1 += esv; s2 += esv * esv;
    }
    __shared__ float r1[256], r2[256];
    r1[t] = s1; r2[t] = s2; __syncthreads();
    for (int s = 128; s > 0; s >>= 1){
        if (t < s){ r1[t] += r1[t+s]; r2[t] += r2[t+s]; }
        __syncthreads();
    }
    if (t == 0){ part[(b*64+ch)*2] = r1[0]; part[(b*64+ch)*2+1] = r2[0]; }
}

// ---------------- K4: sobel-recompute + softmax, logits cached in regs ----------------
__global__ __launch_bounds__(256) void k_softmax_w(
    const unsigned short* __restrict__ logitsH, const float* __restrict__ ei,
    const float* __restrict__ part, const float* __restrict__ proto_orient,
    const float* __restrict__ topo_s, const float* __restrict__ orient_s,
    float* __restrict__ smpart, unsigned short* __restrict__ wbuf)
{
    int ch = blockIdx.x, b = blockIdx.y, t = threadIdx.x;
    __shared__ float eit[4][258];
    __shared__ float sstat[3];
    __shared__ float pdl[32];
    __shared__ float Ml[16];
    __shared__ float rm[4][16], rs[4][16];
    for (int i = t; i < 1024; i += 256){
        int r = i >> 8, c = i & 255;
        int row = 2 * ch - 1 + r;
        eit[r][c + 1] = (row >= 0 && row < 256) ? ei[(size_t)b * HW + row * 256 + c] : 0.f;
    }
    if (t >= 128 && t < 136){
        int q = t - 128;
        eit[q >> 1][(q & 1) * 257] = 0.f;
    }
    if (t < 64){
        float s1 = part[(b*64 + t)*2], s2 = part[(b*64 + t)*2 + 1];
        #pragma unroll
        for (int off = 32; off >= 1; off >>= 1){
            s1 += __shfl_xor(s1, off, 64);
            s2 += __shfl_xor(s2, off, 64);
        }
        if (t == 0){
            float mean = s1 / 65536.f;
            float var = (s2 - 65536.f * mean * mean) / 65535.f;
            var = var > 0.f ? var : 0.f;
            sstat[0] = mean;
            sstat[1] = 1.f / (sqrtf(var) + 1e-5f);
            sstat[2] = 1.f / (mean + 1e-6f);
        }
    } else if (t >= 64 && t < 80){
        int p = t - 64;
        float nx = proto_orient[p*2], ny = proto_orient[p*2+1];
        float n = sqrtf(nx*nx + ny*ny);
        n = n > 1e-12f ? n : 1e-12f;
        pdl[p*2] = nx / n; pdl[p*2+1] = ny / n;
    }
    __syncthreads();
    float mean = sstat[0], rstd = sstat[1], cinv = sstat[2];
    float topo = topo_s[0], orient = orient_s[0];
    float m[16], s[16];
    #pragma unroll
    for (int p = 0; p < 16; p++){ m[p] = -1e30f; s[p] = 0.f; }
    // packed f16 logits for both tokens, kept in regs
    uint4 pkA0, pkA1, pkB0, pkB1;
    {
        size_t gl0 = ((size_t)b * HW + ch * 512 + t) * 16;
        size_t gl1 = ((size_t)b * HW + ch * 512 + 256 + t) * 16;
        pkA0 = *(const uint4*)&logitsH[gl0];
        pkA1 = *(const uint4*)&logitsH[gl0 + 8];
        pkB0 = *(const uint4*)&logitsH[gl1];
        pkB1 = *(const uint4*)&logitsH[gl1 + 8];
    }
    float ewv[2], oxv[2], oyv[2];
    #pragma unroll
    for (int i = 0; i < 2; i++){
        int hl = i + 1, w = t;
        float vmm = eit[hl-1][w], vm0 = eit[hl-1][w+1], vmp = eit[hl-1][w+2];
        float v0m = eit[hl][w],                          v0p = eit[hl][w+2];
        float vpm = eit[hl+1][w], vp0 = eit[hl+1][w+1], vpp = eit[hl+1][w+2];
        float gx = vmp - vmm + 2.f*(v0p - v0m) + vpp - vpm;
        float gy = vpm + 2.f*vp0 + vpp - vmm - 2.f*vm0 - vmp;
        float denom = gx*gx + gy*gy + 1e-6f;
        float esv = sqrtf(denom);
        float cf = fminf(fmaxf(esv * cinv, 0.f), 3.f);
        ewv[i] = (esv - mean) * rstd;
        oxv[i] = ((gx*gx - gy*gy) / denom) * cf;
        oyv[i] = (2.f * gx * gy / denom) * cf;
        const uint4& q0 = (i == 0) ? pkA0 : pkB0;
        const uint4& q1 = (i == 0) ? pkA1 : pkB1;
        unsigned int wv[8] = {q0.x, q0.y, q0.z, q0.w, q1.x, q1.y, q1.z, q1.w};
        #pragma unroll
        for (int p = 0; p < 16; p++){
            unsigned int bits = (p & 1) ? (wv[p >> 1] >> 16) : (wv[p >> 1] & 0xffffu);
            float x = h2f(bits) + topo * ewv[i]
                    + orient * (oxv[i]*pdl[p*2] + oyv[i]*pdl[p*2+1]);
            float mn = fmaxf(m[p], x);
            s[p] = s[p] * __expf(m[p] - mn) + __expf(x - mn);
            m[p] = mn;
        }
    }
    #pragma unroll
    for (int p = 0; p < 16; p++){
        #pragma unroll
        for (int off = 32; off >= 1; off >>= 1){
            float m2 = __shfl_xor(m[p], off, 64);
            float s2v = __shfl_xor(s[p], off, 64);
            float mn = fmaxf(m[p], m2);
            s[p] = s[p] * __expf(m[p] - mn) + s2v * __expf(m2 - mn);
            m[p] = mn;
        }
    }
    int wid = t >> 6;
    if ((t & 63) == 0){
        #pragma unroll
        for (int p = 0; p < 16; p++){ rm[wid][p] = m[p]; rs[wid][p] = s[p]; }
    }
    __syncthreads();
    if (t < 16){
        float M = -1e30f, S = 0.f;
        #pragma unroll
        for (int w2 = 0; w2 < 4; w2++){
            float mw = rm[w2][t], sw2 = rs[w2][t];
            float mn = fmaxf(M, mw);
            S = S * __expf(M - mn) + sw2 * __expf(mw - mn);
            M = mn;
        }
        smpart[((b*16 + t)*128 + ch)*2]     = M;
        smpart[((b*16 + t)*128 + ch)*2 + 1] = S;
        Ml[t] = M;
    }
    __syncthreads();
    float Mloc[16];
    #pragma unroll
    for (int p = 0; p < 16; p++) Mloc[p] = Ml[p];
    // pass 2: w = exp(x - M_ch) bf16, layout [l][p], from cached regs
    #pragma unroll
    for (int i = 0; i < 2; i++){
        int loff = ch * 512 + i * 256 + t;
        size_t gl = (size_t)b * HW + loff;
        const uint4& q0 = (i == 0) ? pkA0 : pkB0;
        const uint4& q1 = (i == 0) ? pkA1 : pkB1;
        unsigned int wv[8] = {q0.x, q0.y, q0.z, q0.w, q1.x, q1.y, q1.z, q1.w};
        unsigned int pk[8];
        #pragma unroll
        for (int p2 = 0; p2 < 8; p2++){
            int pa = p2*2, pb2 = p2*2 + 1;
            float xa = h2f(wv[p2] & 0xffffu) + topo*ewv[i]
                     + orient*(oxv[i]*pdl[pa*2]  + oyv[i]*pdl[pa*2+1]);
            float xb = h2f(wv[p2] >> 16) + topo*ewv[i]
                     + orient*(oxv[i]*pdl[pb2*2] + oyv[i]*pdl[pb2*2+1]);
            pk[p2] = f2bf(__expf(xa - Mloc[pa])) | (f2bf(__expf(xb - Mloc[pb2])) << 16);
        }
        uint4* wp = (uint4*)&wbuf[gl * 16];
        wp[0] = make_uint4(pk[0], pk[1], pk[2], pk[3]);
        wp[1] = make_uint4(pk[4], pk[5], pk[6], pk[7]);
    }
}

// ---------------- K5: streaming prototype accumulation (pipelined) ----------------
__global__ __launch_bounds__(256) void k_proto(
    const unsigned short* __restrict__ wbuf, const float* __restrict__ key,
    const float* __restrict__ smpart, float* __restrict__ ppart)
{
    int ch2 = blockIdx.x, b = blockIdx.y, t = threadIdx.x;
    __shared__ float mm[16][17], ssb[16][17];
    __shared__ float fl[16];
    {
        int p = t & 15, grp = t >> 4;
        float M = -1e30f, S = 0.f;
        #pragma unroll
        for (int j = 0; j < 8; j++){
            int c8 = grp * 8 + j;
            float mw = smpart[((b*16 + p)*128 + c8)*2];
            float sw = smpart[((b*16 + p)*128 + c8)*2 + 1];
            float mn = fmaxf(M, mw);
            S = S * __expf(M - mn) + sw * __expf(mw - mn);
            M = mn;
        }
        mm[grp][p] = M; ssb[grp][p] = S;
    }
    __syncthreads();
    if (t < 16){
        float M = -1e30f, S = 0.f;
        #pragma unroll
        for (int g = 0; g < 16; g++){
            float mw = mm[g][t], sw = ssb[g][t];
            float mn = fmaxf(M, mw);
            S = S * __expf(M - mn) + sw * __expf(mw - mn);
            M = mn;
        }
        float Mch = smpart[((b*16 + t)*128 + ch2)*2];
        fl[t] = __expf(Mch - M) / S;
    }
    __syncthreads();
    int w = t >> 6, lane = t & 63, cg = lane & 15, pq = lane >> 4;
    size_t l0 = (size_t)b * HW + ch2 * 512 + w * 128;
    const float4* kp = (const float4*)key + l0 * 16 + cg;
    const unsigned short* wpp = wbuf + l0 * 16 + pq * 4;
    float acc[4][4];
    #pragma unroll
    for (int j = 0; j < 4; j++)
        #pragma unroll
        for (int i = 0; i < 4; i++) acc[j][i] = 0.f;
    for (int blk = 0; blk < 16; blk++){      // 16 blocks x 8 tokens
        float4 kv[8]; uint2 wv2[8];
        #pragma unroll
        for (int j = 0; j < 8; j++){
            kv[j]  = kp[(blk*8 + j) * 16];
            wv2[j] = *(const uint2*)&wpp[(blk*8 + j) * 16];
        }
        #pragma unroll
        for (int j = 0; j < 8; j++){
            float w0 = bfbits2f(wv2[j].x & 0xffffu);
            float w1 = bfbits2f(wv2[j].x >> 16);
            float w2 = bfbits2f(wv2[j].y & 0xffffu);
            float w3 = bfbits2f(wv2[j].y >> 16);
            float4 kv4 = kv[j];
            acc[0][0] = fmaf(w0, kv4.x, acc[0][0]); acc[0][1] = fmaf(w0, kv4.y, acc[0][1]);
            acc[0][2] = fmaf(w0, kv4.z, acc[0][2]); acc[0][3] = fmaf(w0, kv4.w, acc[0][3]);
            acc[1][0] = fmaf(w1, kv4.x, acc[1][0]); acc[1][1] = fmaf(w1, kv4.y, acc[1][1]);
            acc[1][2] = fmaf(w1, kv4.z, acc[1][2]); acc[1][3] = fmaf(w1, kv4.w, acc[1][3]);
            acc[2][0] = fmaf(w2, kv4.x, acc[2][0]); acc[2][1] = fmaf(w2, kv4.y, acc[2][1]);
            acc[2][2] = fmaf(w2, kv4.z, acc[2][2]); acc[2][3] = fmaf(w2, kv4.w, acc[2][3]);
            acc[3][0] = fmaf(w3, kv4.x, acc[3][0]); acc[3][1] = fmaf(w3, kv4.y, acc[3][1]);
            acc[3][2] = fmaf(w3, kv4.z, acc[3][2]); acc[3][3] = fmaf(w3, kv4.w, acc[3][3]);
        }
    }
    __shared__ float red[4][16][68];
    #pragma unroll
    for (int j = 0; j < 4; j++){
        float4 st = make_float4(acc[j][0], acc[j][1], acc[j][2], acc[j][3]);
        *(float4*)&red[w][pq*4 + j][cg*4] = st;
    }
    __syncthreads();
    size_t obase = ((size_t)(b * 128 + ch2)) * 1024;
    for (int idx = t; idx < 1024; idx += 256){
        int p = idx >> 6;
        float sum = red[0][p][idx & 63] + red[1][p][idx & 63]
                  + red[2][p][idx & 63] + red[3][p][idx & 63];
        ppart[obase + idx] = sum * fl[p];
    }
}

// ---------------- K7: ppart reduce + gate MLPs + sigmoid + LayerNorm ----------------
__global__ __launch_bounds__(256) void k_gate(
    const float* __restrict__ ppart, const float* __restrict__ query,
    const float* __restrict__ w1, const float* __restrict__ bb1,
    const float* __restrict__ w2, const float* __restrict__ bb2,
    const float* __restrict__ gw1, const float* __restrict__ gb1,
    const float* __restrict__ gw2, const float* __restrict__ gb2,
    const float* __restrict__ lng, const float* __restrict__ lnb,
    float* __restrict__ out)
{
    __shared__ float z[16][64], h1[16][64], loc[16][64], g[64], hg[64], glb[64];
    int b = blockIdx.x, t = threadIdx.x;
    for (int idx = t; idx < 1024; idx += 256){
        const float* pp = ppart + (size_t)b * 128 * 1024 + idx;
        float sacc = 0.f;
        #pragma unroll 8
        for (int ch = 0; ch < 128; ch++) sacc += pp[(size_t)ch * 1024];
        z[idx >> 6][idx & 63] = sacc + query[b * 1024 + idx];
    }
    __syncthreads();
    for (int idx = t; idx < 1024; idx += 256){
        int p = idx >> 6, j = idx & 63;
        float acc = bb1[j];
        for (int i = 0; i < 64; i++) acc += z[p][i] * w1[j * 64 + i];
        h1[p][j] = relu_f(acc);
    }
    if (t < 64){
        float sg = 0.f;
        for (int p = 0; p < 16; p++) sg += z[p][t];
        g[t] = sg * (1.f / 16.f);
    }
    __syncthreads();
    for (int idx = t; idx < 1024; idx += 256){
        int p = idx >> 6, k = idx & 63;
        float acc = bb2[k];
        for (int j = 0; j < 64; j++) acc += h1[p][j] * w2[k * 64 + j];
        loc[p][k] = acc;
    }
    if (t < 64){
        float acc = gb1[t];
        for (int i = 0; i < 64; i++) acc += g[i] * gw1[t * 64 + i];
        hg[t] = relu_f(acc);
    }
    __syncthreads();
    if (t < 64){
        float acc = gb2[t];
        for (int j = 0; j < 64; j++) acc += hg[j] * gw2[t * 64 + j];
        glb[t] = acc;
    }
    __syncthreads();
    for (int idx = t; idx < 1024; idx += 256){
        int p = idx >> 6, c = idx & 63;
        float a = loc[p][c] + glb[c];
        float sg = 1.f / (1.f + expf(-a));
        float q = query[b * 1024 + idx];
        h1[p][c] = q * sg + q;
    }
    __syncthreads();
    if (t < 16){
        int p = t;
        float mu = 0.f;
        for (int c = 0; c < 64; c++) mu += h1[p][c];
        mu *= (1.f / 64.f);
        float var = 0.f;
        for (int c = 0; c < 64; c++){ float d = h1[p][c] - mu; var += d * d; }
        var *= (1.f / 64.f);
        float rstd = rsqrtf(var + 1e-5f);
        for (int c = 0; c < 64; c++)
            out[b * 1024 + p * 64 + c] = (h1[p][c] - mu) * rstd * lng[c] + lnb[c];
    }
}

extern "C" void kernel_launch(void* const* d_in, const int* in_sizes, int n_in,
                              void* d_out, int out_size, void* d_ws, size_t ws_size,
                              hipStream_t stream){
    (void)in_sizes; (void)n_in; (void)out_size; (void)ws_size;
    const float* feat   = (const float*)d_in[0];
    const float* query  = (const float*)d_in[1];
    const float* key    = (const float*)d_in[2];
    const float* dw_w   = (const float*)d_in[3];
    const float* bn1_g  = (const float*)d_in[4];
    const float* bn1_b  = (const float*)d_in[5];
    const float* bn1_m  = (const float*)d_in[6];
    const float* bn1_v  = (const float*)d_in[7];
    const float* pw_w   = (const float*)d_in[8];
    const float* bn2_g  = (const float*)d_in[9];
    const float* bn2_b  = (const float*)d_in[10];
    const float* bn2_m  = (const float*)d_in[11];
    const float* bn2_v  = (const float*)d_in[12];
    const float* aff_w  = (const float*)d_in[13];
    const float* loc_w1 = (const float*)d_in[14];
    const float* loc_b1 = (const float*)d_in[15];
    const float* loc_w2 = (const float*)d_in[16];
    const float* loc_b2 = (const float*)d_in[17];
    const float* glb_w1 = (const float*)d_in[18];
    const float* glb_b1 = (const float*)d_in[19];
    const float* glb_w2 = (const float*)d_in[20];
    const float* glb_b2 = (const float*)d_in[21];
    const float* ln_g   = (const float*)d_in[22];
    const float* ln_b   = (const float*)d_in[23];
    const float* topo   = (const float*)d_in[24];
    const float* orient = (const float*)d_in[25];
    const float* proto_orient = (const float*)d_in[26];
    float* out = (float*)d_out;
    float* ws  = (float*)d_ws;

    float* ei      = ws;                                       // 524288
    float* ppart   = ws;                                       // 1048576 (after ei dead)
    unsigned short* logitsH = (unsigned short*)(ws + 1048576); // 8,388,608 ushort
    unsigned short* wbuf    = (unsigned short*)(ws + 5242880); // 8,388,608 ushort
    float* k3part  = ws + 9437184;                             // 1024
    float* smpart  = ws + 9438208;                             // 32768
    float* scsh    = ws + 9470976;                             // 256
    unsigned short* pwA  = (unsigned short*)(ws + 9471232);    // 4096 ushort
    unsigned short* affA = (unsigned short*)(ws + 9473280);    // 1024 ushort

    k_prep<<<1, 256, 0, stream>>>(pw_w, aff_w, bn1_g, bn1_b, bn1_m, bn1_v,
                                  bn2_g, bn2_b, bn2_m, bn2_v, scsh, pwA, affA);
    k_conv_aff<<<2048, 256, 0, stream>>>(feat, dw_w, scsh, pwA, affA, logitsH, ei);
    k_sobel_stats<<<dim3(64, 8), 256, 0, stream>>>(ei, k3part);
    k_softmax_w<<<dim3(128, 8), 256, 0, stream>>>(logitsH, ei, k3part,
                                                  proto_orient, topo, orient,
                                                  smpart, wbuf);
    k_proto<<<dim3(128, 8), 256, 0, stream>>>(wbuf, key, smpart, ppart);
    k_gate<<<8, 256, 0, stream>>>(ppart, query, loc_w1, loc_b1, loc_w2, loc_b2,
                                  glb_w1, glb_b1, glb_w2, glb_b2, ln_g, ln_b, out);
}

// Round 7
// 130.859 us; speedup vs baseline: 4.1775x; 1.3384x over previous
//
#include <hip/hip_runtime.h>
#include <hip/hip_fp16.h>
#include <math.h>

#define HW     65536
#define WIDTH  256
#define HEIGHT 256

typedef __attribute__((ext_vector_type(8))) short bf16x8;
typedef __attribute__((ext_vector_type(4))) float f32x4;

__device__ __forceinline__ float relu_f(float x){ return x > 0.f ? x : 0.f; }
__device__ __forceinline__ unsigned int f2bf(float x){
    union { float f; unsigned int u; } v; v.f = x;
    unsigned int r = v.u + 0x7fffu + ((v.u >> 16) & 1u);   // RNE
    return r >> 16;
}
__device__ __forceinline__ float bfbits2f(unsigned int lo16){
    union { unsigned int u; float f; } v; v.u = lo16 << 16; return v.f;
}
__device__ __forceinline__ float h2f(unsigned int bits16){
    __half h = *(__half*)&bits16; return __half2float(h);
}

// ---------------- K0: prep — fold BN, pack MFMA A-fragments ----------------
__global__ void k_prep(const float* __restrict__ pw_w, const float* __restrict__ aff_w,
                       const float* __restrict__ g1, const float* __restrict__ b1,
                       const float* __restrict__ m1, const float* __restrict__ v1,
                       const float* __restrict__ g2, const float* __restrict__ b2,
                       const float* __restrict__ m2, const float* __restrict__ v2,
                       float* __restrict__ scsh, unsigned short* __restrict__ pwA,
                       unsigned short* __restrict__ affA){
    int t = threadIdx.x;
    for (int i = t; i < 4096; i += 256){
        int e = i & 7, l = (i >> 3) & 63, ks = (i >> 9) & 1, ct = i >> 10;
        int co = ct * 16 + (l & 15);
        int ci = ks * 32 + (l >> 4) * 8 + e;
        pwA[i] = (unsigned short)f2bf(pw_w[co * 64 + ci]);
    }
    for (int i = t; i < 1024; i += 256){
        int e = i & 7, l = (i >> 3) & 63, ks = i >> 9;
        int p = l & 15, k = ks * 32 + (l >> 4) * 8 + e;
        affA[i] = (unsigned short)f2bf(aff_w[p * 64 + k]);
    }
    if (t < 64){
        float s = g1[t] * rsqrtf(v1[t] + 1e-5f);
        scsh[t]       = s;
        scsh[64 + t]  = b1[t] - m1[t] * s;
        float s2 = g2[t] * rsqrtf(v2[t] + 1e-5f);
        scsh[128 + t] = s2;
        scsh[192 + t] = b2[t] - m2[t] * s2;
    }
}

// ---------------- K2: full-row dw3x3 -> MFMA pw -> MFMA affinity -> f16 logits [b][l][16] ----------------
__global__ __launch_bounds__(256, 4) void k_conv_aff(
    const float* __restrict__ feat, const float* __restrict__ dw_w,
    const float* __restrict__ scsh, const unsigned short* __restrict__ pwA,
    const unsigned short* __restrict__ affA,
    unsigned short* __restrict__ logitsH, float* __restrict__ ei)
{
    __shared__ unsigned short x1u[256 * 68];
    __shared__ float eibuf[4][256];
    int t = threadIdx.x;
    int lane = t & 63;
    int wu = __builtin_amdgcn_readfirstlane(t >> 6);
    int orig = blockIdx.x;
    int flat = (orig & 7) * 256 + (orig >> 3);   // XCD-bijective (2048 = 8*256)
    int b = flat >> 8, h = flat & 255;

    const bf16x8* pwA8 = (const bf16x8*)pwA;
    bf16x8 apw0 = pwA8[(wu * 2 + 0) * 64 + lane];
    bf16x8 apw1 = pwA8[(wu * 2 + 1) * 64 + lane];
    const bf16x8* affA8 = (const bf16x8*)affA;
    bf16x8 aaf0 = affA8[lane];
    bf16x8 aaf1 = affA8[64 + lane];
    int lcol = lane & 15, pq = lane >> 4;
    int cb = wu * 16 + pq * 4;
    float4 sc2v = *(const float4*)(scsh + 128 + cb);
    float4 sh2v = *(const float4*)(scsh + 192 + cb);

    // ---- phase A
    int px0 = lane * 4;
    const float* fb = feat + (size_t)b * 64 * HW;
    int hh0 = (h > 0) ? h - 1 : 0;
    int hh2 = (h < 255) ? h + 1 : 255;
    float rw0 = (h > 0) ? 1.f : 0.f;
    float rw2 = (h < 255) ? 1.f : 0.f;
    int   roff0 = hh0 * WIDTH, roff1 = h * WIDTH, roff2 = hh2 * WIDTH;
    float mx = 0.f, my = 0.f, mz = 0.f, mw = 0.f;
    int swz = ((lane >> 2) & 7) << 1;
    #pragma unroll
    for (int cp = 0; cp < 8; cp++){
        int ci0 = wu * 16 + cp * 2;
        int ci1 = ci0 + 1;
        const float* base0 = fb + (size_t)ci0 * HW + px0;
        const float* base1 = fb + (size_t)ci1 * HW + px0;
        float a00=0.f,a01=0.f,a02=0.f,a03=0.f, a10=0.f,a11=0.f,a12=0.f,a13=0.f;
        #pragma unroll
        for (int r = 0; r < 3; r++){
            int roff = (r == 0) ? roff0 : ((r == 1) ? roff1 : roff2);
            float rwf = (r == 0) ? rw0 : ((r == 1) ? 1.f : rw2);
            float4 v0 = *(const float4*)(base0 + roff);
            float4 v1 = *(const float4*)(base1 + roff);
            float w00 = dw_w[ci0*9 + r*3 + 0] * rwf;
            float w01 = dw_w[ci0*9 + r*3 + 1] * rwf;
            float w02 = dw_w[ci0*9 + r*3 + 2] * rwf;
            float w10 = dw_w[ci1*9 + r*3 + 0] * rwf;
            float w11 = dw_w[ci1*9 + r*3 + 1] * rwf;
            float w12 = dw_w[ci1*9 + r*3 + 2] * rwf;
            float lf0 = __shfl_up(v0.w, 1);  if (lane == 0)  lf0 = 0.f;
            float rt0 = __shfl_down(v0.x, 1); if (lane == 63) rt0 = 0.f;
            float lf1 = __shfl_up(v1.w, 1);  if (lane == 0)  lf1 = 0.f;
            float rt1 = __shfl_down(v1.x, 1); if (lane == 63) rt1 = 0.f;
            a00 += lf0*w00 + v0.x*w01 + v0.y*w02;
            a01 += v0.x*w00 + v0.y*w01 + v0.z*w02;
            a02 += v0.y*w00 + v0.z*w01 + v0.w*w02;
            a03 += v0.z*w00 + v0.w*w01 + rt0*w02;
            a10 += lf1*w10 + v1.x*w11 + v1.y*w12;
            a11 += v1.x*w10 + v1.y*w11 + v1.z*w12;
            a12 += v1.y*w10 + v1.z*w11 + v1.w*w12;
            a13 += v1.z*w10 + v1.w*w11 + rt1*w12;
            if (r == 1){
                mx += v0.x + v1.x; my += v0.y + v1.y;
                mz += v0.z + v1.z; mw += v0.w + v1.w;
            }
        }
        float s0 = scsh[ci0], o0 = scsh[64 + ci0];
        float s1 = scsh[ci1], o1 = scsh[64 + ci1];
        int dwi = ((wu * 8 + cp) ^ swz) * 2;
        unsigned int pk0 = f2bf(relu_f(fmaf(a00,s0,o0))) | (f2bf(relu_f(fmaf(a10,s1,o1))) << 16);
        unsigned int pk1 = f2bf(relu_f(fmaf(a01,s0,o0))) | (f2bf(relu_f(fmaf(a11,s1,o1))) << 16);
        unsigned int pk2 = f2bf(relu_f(fmaf(a02,s0,o0))) | (f2bf(relu_f(fmaf(a12,s1,o1))) << 16);
        unsigned int pk3 = f2bf(relu_f(fmaf(a03,s0,o0))) | (f2bf(relu_f(fmaf(a13,s1,o1))) << 16);
        *(unsigned int*)&x1u[(px0 + 0) * 68 + dwi] = pk0;
        *(unsigned int*)&x1u[(px0 + 1) * 68 + dwi] = pk1;
        *(unsigned int*)&x1u[(px0 + 2) * 68 + dwi] = pk2;
        *(unsigned int*)&x1u[(px0 + 3) * 68 + dwi] = pk3;
    }
    *(float4*)&eibuf[wu][px0] = make_float4(mx, my, mz, mw);
    __syncthreads();
    {
        float m = (eibuf[0][t] + eibuf[1][t]) + (eibuf[2][t] + eibuf[3][t]);
        ei[(size_t)b * HW + h * WIDTH + t] = m * (1.f / 64.f);
    }

    // ---- phase B
    int k0d = pq * 4;
    #pragma unroll
    for (int half = 0; half < 2; half++){
        f32x4 accB[8];
        #pragma unroll
        for (int q = 0; q < 8; q++){
            int jt = half * 8 + q;
            int swzj = (jt & 7) << 1;
            const unsigned short* rowp = &x1u[(jt * 16 + lcol) * 68];
            union { bf16x8 v; uint2 u[2]; } b0, b1;
            b0.u[0] = *(const uint2*)&rowp[((k0d)          ^ swzj) * 2];
            b0.u[1] = *(const uint2*)&rowp[((k0d + 2)      ^ swzj) * 2];
            b1.u[0] = *(const uint2*)&rowp[((16 + k0d)     ^ swzj) * 2];
            b1.u[1] = *(const uint2*)&rowp[((16 + k0d + 2) ^ swzj) * 2];
            f32x4 acc = {0.f, 0.f, 0.f, 0.f};
            acc = __builtin_amdgcn_mfma_f32_16x16x32_bf16(apw0, b0.v, acc, 0, 0, 0);
            acc = __builtin_amdgcn_mfma_f32_16x16x32_bf16(apw1, b1.v, acc, 0, 0, 0);
            accB[q] = acc;
        }
        __syncthreads();
        #pragma unroll
        for (int q = 0; q < 8; q++){
            int jt = half * 8 + q;
            int swzj = (jt & 7) << 1;
            f32x4 acc = accB[q];
            unsigned int y0 = f2bf(relu_f(fmaf(acc[0], sc2v.x, sh2v.x)))
                            | (f2bf(relu_f(fmaf(acc[1], sc2v.y, sh2v.y))) << 16);
            unsigned int y1 = f2bf(relu_f(fmaf(acc[2], sc2v.z, sh2v.z)))
                            | (f2bf(relu_f(fmaf(acc[3], sc2v.w, sh2v.w))) << 16);
            int D = (wu * 8 + pq * 2) ^ swzj;
            *(uint2*)&x1u[(jt * 16 + lcol) * 68 + D * 2] = make_uint2(y0, y1);
        }
    }
    __syncthreads();

    // ---- phase C: affinity GEMM -> f16 logits, layout [b][l][16p]
    int p0 = pq * 4;
    #pragma unroll
    for (int q = 0; q < 4; q++){
        int jt = wu * 4 + q;
        int swzj = (jt & 7) << 1;
        const unsigned short* rowp = &x1u[(jt * 16 + lcol) * 68];
        union { bf16x8 v; uint2 u[2]; } b0, b1;
        b0.u[0] = *(const uint2*)&rowp[((k0d)          ^ swzj) * 2];
        b0.u[1] = *(const uint2*)&rowp[((k0d + 2)      ^ swzj) * 2];
        b1.u[0] = *(const uint2*)&rowp[((16 + k0d)     ^ swzj) * 2];
        b1.u[1] = *(const uint2*)&rowp[((16 + k0d + 2) ^ swzj) * 2];
        f32x4 acc = {0.f, 0.f, 0.f, 0.f};
        acc = __builtin_amdgcn_mfma_f32_16x16x32_bf16(aaf0, b0.v, acc, 0, 0, 0);
        acc = __builtin_amdgcn_mfma_f32_16x16x32_bf16(aaf1, b1.v, acc, 0, 0, 0);
        int gx = h * WIDTH + jt * 16 + lcol;
        __half h0 = __float2half(acc[0]), h1v = __float2half(acc[1]);
        __half h2 = __float2half(acc[2]), h3v = __float2half(acc[3]);
        unsigned int u0 = (unsigned int)(*(unsigned short*)&h0)
                        | ((unsigned int)(*(unsigned short*)&h1v) << 16);
        unsigned int u1 = (unsigned int)(*(unsigned short*)&h2)
                        | ((unsigned int)(*(unsigned short*)&h3v) << 16);
        *(uint2*)&logitsH[((size_t)b * HW + gx) * 16 + p0] = make_uint2(u0, u1);
    }
}

// ---------------- K3: Sobel stats only ----------------
__global__ __launch_bounds__(256) void k_sobel_stats(const float* __restrict__ ei,
                                                     float* __restrict__ part){
    int b = blockIdx.y, ch = blockIdx.x, t = threadIdx.x;
    const float* e = ei + (size_t)b * HW;
    float s1 = 0.f, s2 = 0.f;
    for (int i = 0; i < 4; i++){
        int l = ch * 1024 + i * 256 + t;
        int h = l >> 8, w = l & 255;
        float v[3][3];
        #pragma unroll
        for (int dh = -1; dh <= 1; dh++)
            #pragma unroll
            for (int dw = -1; dw <= 1; dw++){
                int hh = h + dh, ww = w + dw;
                v[dh+1][dw+1] = (hh >= 0 && hh < HEIGHT && ww >= 0 && ww < WIDTH)
                                ? e[hh * WIDTH + ww] : 0.f;
            }
        float gx = -v[0][0] + v[0][2] - 2.f*v[1][0] + 2.f*v[1][2] - v[2][0] + v[2][2];
        float gy = -v[0][0] - 2.f*v[0][1] - v[0][2] + v[2][0] + 2.f*v[2][1] + v[2][2];
        float esv = sqrtf(gx*gx + gy*gy + 1e-6f);
        s1 += esv; s2 += esv * esv;
    }
    __shared__ float r1[256], r2[256];
    r1[t] = s1; r2[t] = s2; __syncthreads();
    for (int s = 128; s > 0; s >>= 1){
        if (t < s){ r1[t] += r1[t+s]; r2[t] += r2[t+s]; }
        __syncthreads();
    }
    if (t == 0){ part[(b*64+ch)*2] = r1[0]; part[(b*64+ch)*2+1] = r2[0]; }
}

// ---------------- K4+K5 merged: softmax (weights stay in LDS) + prototype partials ----------------
__global__ __launch_bounds__(256) void k_smproto(
    const unsigned short* __restrict__ logitsH, const float* __restrict__ ei,
    const float* __restrict__ part, const float* __restrict__ proto_orient,
    const float* __restrict__ topo_s, const float* __restrict__ orient_s,
    const float* __restrict__ key,
    float* __restrict__ smpart, float* __restrict__ ppart)
{
    int ch = blockIdx.x, b = blockIdx.y, t = threadIdx.x;
    __shared__ float eit[4][258];
    __shared__ float sstat[3];
    __shared__ float pdl[32];
    __shared__ float Ml[16];
    __shared__ float rm[4][16], rs[4][16];
    __shared__ unsigned int wlds[512][10];   // bf16-pair weights [tok][p-pair], pad->8B align

    // ---- pass 0: ei tile + batch stats + proto dirs
    for (int i = t; i < 1024; i += 256){
        int r = i >> 8, c = i & 255;
        int row = 2 * ch - 1 + r;
        eit[r][c + 1] = (row >= 0 && row < 256) ? ei[(size_t)b * HW + row * 256 + c] : 0.f;
    }
    if (t >= 128 && t < 136){
        int q = t - 128;
        eit[q >> 1][(q & 1) * 257] = 0.f;
    }
    if (t < 64){
        float s1 = part[(b*64 + t)*2], s2 = part[(b*64 + t)*2 + 1];
        #pragma unroll
        for (int off = 32; off >= 1; off >>= 1){
            s1 += __shfl_xor(s1, off, 64);
            s2 += __shfl_xor(s2, off, 64);
        }
        if (t == 0){
            float mean = s1 / 65536.f;
            float var = (s2 - 65536.f * mean * mean) / 65535.f;
            var = var > 0.f ? var : 0.f;
            sstat[0] = mean;
            sstat[1] = 1.f / (sqrtf(var) + 1e-5f);
            sstat[2] = 1.f / (mean + 1e-6f);
        }
    } else if (t >= 64 && t < 80){
        int p = t - 64;
        float nx = proto_orient[p*2], ny = proto_orient[p*2+1];
        float n = sqrtf(nx*nx + ny*ny);
        n = n > 1e-12f ? n : 1e-12f;
        pdl[p*2] = nx / n; pdl[p*2+1] = ny / n;
    }
    __syncthreads();
    float mean = sstat[0], rstd = sstat[1], cinv = sstat[2];
    float topo = topo_s[0], orient = orient_s[0];

    // ---- pass 1: softmax stats from register-cached logits
    float m[16], s[16];
    #pragma unroll
    for (int p = 0; p < 16; p++){ m[p] = -1e30f; s[p] = 0.f; }
    uint4 pkA0, pkA1, pkB0, pkB1;
    {
        size_t gl0 = ((size_t)b * HW + ch * 512 + t) * 16;
        size_t gl1 = ((size_t)b * HW + ch * 512 + 256 + t) * 16;
        pkA0 = *(const uint4*)&logitsH[gl0];
        pkA1 = *(const uint4*)&logitsH[gl0 + 8];
        pkB0 = *(const uint4*)&logitsH[gl1];
        pkB1 = *(const uint4*)&logitsH[gl1 + 8];
    }
    float ewv[2], oxv[2], oyv[2];
    #pragma unroll
    for (int i = 0; i < 2; i++){
        int hl = i + 1, w = t;
        float vmm = eit[hl-1][w], vm0 = eit[hl-1][w+1], vmp = eit[hl-1][w+2];
        float v0m = eit[hl][w],                          v0p = eit[hl][w+2];
        float vpm = eit[hl+1][w], vp0 = eit[hl+1][w+1], vpp = eit[hl+1][w+2];
        float gx = vmp - vmm + 2.f*(v0p - v0m) + vpp - vpm;
        float gy = vpm + 2.f*vp0 + vpp - vmm - 2.f*vm0 - vmp;
        float denom = gx*gx + gy*gy + 1e-6f;
        float esv = sqrtf(denom);
        float cf = fminf(fmaxf(esv * cinv, 0.f), 3.f);
        ewv[i] = (esv - mean) * rstd;
        oxv[i] = ((gx*gx - gy*gy) / denom) * cf;
        oyv[i] = (2.f * gx * gy / denom) * cf;
        const uint4& q0 = (i == 0) ? pkA0 : pkB0;
        const uint4& q1 = (i == 0) ? pkA1 : pkB1;
        unsigned int wv[8] = {q0.x, q0.y, q0.z, q0.w, q1.x, q1.y, q1.z, q1.w};
        #pragma unroll
        for (int p = 0; p < 16; p++){
            unsigned int bits = (p & 1) ? (wv[p >> 1] >> 16) : (wv[p >> 1] & 0xffffu);
            float x = h2f(bits) + topo * ewv[i]
                    + orient * (oxv[i]*pdl[p*2] + oyv[i]*pdl[p*2+1]);
            float mn = fmaxf(m[p], x);
            s[p] = s[p] * __expf(m[p] - mn) + __expf(x - mn);
            m[p] = mn;
        }
    }
    #pragma unroll
    for (int p = 0; p < 16; p++){
        #pragma unroll
        for (int off = 32; off >= 1; off >>= 1){
            float m2 = __shfl_xor(m[p], off, 64);
            float s2v = __shfl_xor(s[p], off, 64);
            float mn = fmaxf(m[p], m2);
            s[p] = s[p] * __expf(m[p] - mn) + s2v * __expf(m2 - mn);
            m[p] = mn;
        }
    }
    int wid = t >> 6;
    if ((t & 63) == 0){
        #pragma unroll
        for (int p = 0; p < 16; p++){ rm[wid][p] = m[p]; rs[wid][p] = s[p]; }
    }
    __syncthreads();
    if (t < 16){
        float M = -1e30f, S = 0.f;
        #pragma unroll
        for (int w2 = 0; w2 < 4; w2++){
            float mw = rm[w2][t], sw2 = rs[w2][t];
            float mn = fmaxf(M, mw);
            S = S * __expf(M - mn) + sw2 * __expf(mw - mn);
            M = mn;
        }
        smpart[((b*16 + t)*128 + ch)*2]     = M;
        smpart[((b*16 + t)*128 + ch)*2 + 1] = S;
        Ml[t] = M;
    }
    __syncthreads();
    float Mloc[16];
    #pragma unroll
    for (int p = 0; p < 16; p++) Mloc[p] = Ml[p];

    // ---- pass 2: per-token weights (bf16 pairs) -> LDS
    #pragma unroll
    for (int i = 0; i < 2; i++){
        int tok = i * 256 + t;
        const uint4& q0 = (i == 0) ? pkA0 : pkB0;
        const uint4& q1 = (i == 0) ? pkA1 : pkB1;
        unsigned int wv[8] = {q0.x, q0.y, q0.z, q0.w, q1.x, q1.y, q1.z, q1.w};
        #pragma unroll
        for (int p2 = 0; p2 < 8; p2++){
            int pa = p2*2, pb2 = p2*2 + 1;
            float xa = h2f(wv[p2] & 0xffffu) + topo*ewv[i]
                     + orient*(oxv[i]*pdl[pa*2]  + oyv[i]*pdl[pa*2+1]);
            float xb = h2f(wv[p2] >> 16) + topo*ewv[i]
                     + orient*(oxv[i]*pdl[pb2*2] + oyv[i]*pdl[pb2*2+1]);
            wlds[tok][p2] = f2bf(__expf(xa - Mloc[pa])) | (f2bf(__expf(xb - Mloc[pb2])) << 16);
        }
    }
    __syncthreads();

    // ---- pass 3: unscaled prototype partial, key streamed from HBM
    int w = t >> 6, lane = t & 63, cg = lane & 15, pq = lane >> 4;
    const float4* kp = (const float4*)key + ((size_t)b * HW + ch * 512 + w * 128) * 16 + cg;
    float acc[4][4];
    #pragma unroll
    for (int j = 0; j < 4; j++)
        #pragma unroll
        for (int i = 0; i < 4; i++) acc[j][i] = 0.f;
    for (int blk = 0; blk < 16; blk++){
        float4 kv[8]; uint2 wv2[8];
        #pragma unroll
        for (int j = 0; j < 8; j++){
            kv[j]  = kp[(blk*8 + j) * 16];
            wv2[j] = *(const uint2*)&wlds[w*128 + blk*8 + j][pq*2];
        }
        #pragma unroll
        for (int j = 0; j < 8; j++){
            float w0 = bfbits2f(wv2[j].x & 0xffffu);
            float w1 = bfbits2f(wv2[j].x >> 16);
            float w2 = bfbits2f(wv2[j].y & 0xffffu);
            float w3 = bfbits2f(wv2[j].y >> 16);
            float4 kv4 = kv[j];
            acc[0][0] = fmaf(w0, kv4.x, acc[0][0]); acc[0][1] = fmaf(w0, kv4.y, acc[0][1]);
            acc[0][2] = fmaf(w0, kv4.z, acc[0][2]); acc[0][3] = fmaf(w0, kv4.w, acc[0][3]);
            acc[1][0] = fmaf(w1, kv4.x, acc[1][0]); acc[1][1] = fmaf(w1, kv4.y, acc[1][1]);
            acc[1][2] = fmaf(w1, kv4.z, acc[1][2]); acc[1][3] = fmaf(w1, kv4.w, acc[1][3]);
            acc[2][0] = fmaf(w2, kv4.x, acc[2][0]); acc[2][1] = fmaf(w2, kv4.y, acc[2][1]);
            acc[2][2] = fmaf(w2, kv4.z, acc[2][2]); acc[2][3] = fmaf(w2, kv4.w, acc[2][3]);
            acc[3][0] = fmaf(w3, kv4.x, acc[3][0]); acc[3][1] = fmaf(w3, kv4.y, acc[3][1]);
            acc[3][2] = fmaf(w3, kv4.z, acc[3][2]); acc[3][3] = fmaf(w3, kv4.w, acc[3][3]);
        }
    }
    __syncthreads();                 // all wlds reads done
    float (*red)[16][68] = (float (*)[16][68])wlds;   // alias: 17408 B <= 20480 B
    #pragma unroll
    for (int j = 0; j < 4; j++)
        *(float4*)&red[w][pq*4 + j][cg*4] =
            make_float4(acc[j][0], acc[j][1], acc[j][2], acc[j][3]);
    __syncthreads();
    size_t obase = ((size_t)(b * 128 + ch)) * 1024;
    for (int idx = t; idx < 1024; idx += 256){
        int p = idx >> 6, c = idx & 63;
        ppart[obase + idx] = red[0][p][c] + red[1][p][c] + red[2][p][c] + red[3][p][c];
    }
}

// ---------------- K6: apply per-chunk softmax scale + reduce -> proto ----------------
__global__ __launch_bounds__(256) void k_reduce(
    const float* __restrict__ smpart, const float* __restrict__ ppart,
    float* __restrict__ proto)
{
    int p = blockIdx.x, b = blockIdx.y, t = threadIdx.x;
    __shared__ float arr[128], flv[128], partial[4][64];
    float Mt = -1e30f, St = 0.f;
    if (t < 128){
        Mt = smpart[((b*16 + p)*128 + t)*2];
        St = smpart[((b*16 + p)*128 + t)*2 + 1];
        arr[t] = Mt;
    }
    __syncthreads();
    for (int s = 64; s > 0; s >>= 1){
        if (t < s) arr[t] = fmaxf(arr[t], arr[t + s]);
        __syncthreads();
    }
    float M = arr[0];
    __syncthreads();
    if (t < 128) arr[t] = St * __expf(Mt - M);
    __syncthreads();
    for (int s = 64; s > 0; s >>= 1){
        if (t < s) arr[t] += arr[t + s];
        __syncthreads();
    }
    float Stot = arr[0];
    __syncthreads();
    if (t < 128) flv[t] = __expf(Mt - M) / Stot;
    __syncthreads();
    int c = t & 63, half = t >> 6;
    float acc = 0.f;
    #pragma unroll 8
    for (int j = 0; j < 32; j++){
        int ch = half * 32 + j;
        acc += flv[ch] * ppart[((size_t)(b * 128 + ch)) * 1024 + p * 64 + c];
    }
    partial[half][c] = acc;
    __syncthreads();
    if (t < 64)
        proto[b * 1024 + p * 64 + t] =
            (partial[0][t] + partial[1][t]) + (partial[2][t] + partial[3][t]);
}

// ---------------- K7: gate MLPs + sigmoid + LayerNorm ----------------
__global__ __launch_bounds__(256) void k_gate(
    const float* __restrict__ proto, const float* __restrict__ query,
    const float* __restrict__ w1, const float* __restrict__ bb1,
    const float* __restrict__ w2, const float* __restrict__ bb2,
    const float* __restrict__ gw1, const float* __restrict__ gb1,
    const float* __restrict__ gw2, const float* __restrict__ gb2,
    const float* __restrict__ lng, const float* __restrict__ lnb,
    float* __restrict__ out)
{
    __shared__ float z[16][64], h1[16][64], loc[16][64], g[64], hg[64], glb[64];
    int b = blockIdx.x, t = threadIdx.x;
    for (int idx = t; idx < 1024; idx += 256)
        z[idx >> 6][idx & 63] = proto[b * 1024 + idx] + query[b * 1024 + idx];
    __syncthreads();
    for (int idx = t; idx < 1024; idx += 256){
        int p = idx >> 6, j = idx & 63;
        float acc = bb1[j];
        for (int i = 0; i < 64; i++) acc += z[p][i] * w1[j * 64 + i];
        h1[p][j] = relu_f(acc);
    }
    if (t < 64){
        float sg = 0.f;
        for (int p = 0; p < 16; p++) sg += z[p][t];
        g[t] = sg * (1.f / 16.f);
    }
    __syncthreads();
    for (int idx = t; idx < 1024; idx += 256){
        int p = idx >> 6, k = idx & 63;
        float acc = bb2[k];
        for (int j = 0; j < 64; j++) acc += h1[p][j] * w2[k * 64 + j];
        loc[p][k] = acc;
    }
    if (t < 64){
        float acc = gb1[t];
        for (int i = 0; i < 64; i++) acc += g[i] * gw1[t * 64 + i];
        hg[t] = relu_f(acc);
    }
    __syncthreads();
    if (t < 64){
        float acc = gb2[t];
        for (int j = 0; j < 64; j++) acc += hg[j] * gw2[t * 64 + j];
        glb[t] = acc;
    }
    __syncthreads();
    for (int idx = t; idx < 1024; idx += 256){
        int p = idx >> 6, c = idx & 63;
        float a = loc[p][c] + glb[c];
        float sg = 1.f / (1.f + expf(-a));
        float q = query[b * 1024 + idx];
        h1[p][c] = q * sg + q;
    }
    __syncthreads();
    if (t < 16){
        int p = t;
        float mu = 0.f;
        for (int c = 0; c < 64; c++) mu += h1[p][c];
        mu *= (1.f / 64.f);
        float var = 0.f;
        for (int c = 0; c < 64; c++){ float d = h1[p][c] - mu; var += d * d; }
        var *= (1.f / 64.f);
        float rstd = rsqrtf(var + 1e-5f);
        for (int c = 0; c < 64; c++)
            out[b * 1024 + p * 64 + c] = (h1[p][c] - mu) * rstd * lng[c] + lnb[c];
    }
}

extern "C" void kernel_launch(void* const* d_in, const int* in_sizes, int n_in,
                              void* d_out, int out_size, void* d_ws, size_t ws_size,
                              hipStream_t stream){
    (void)in_sizes; (void)n_in; (void)out_size; (void)ws_size;
    const float* feat   = (const float*)d_in[0];
    const float* query  = (const float*)d_in[1];
    const float* key    = (const float*)d_in[2];
    const float* dw_w   = (const float*)d_in[3];
    const float* bn1_g  = (const float*)d_in[4];
    const float* bn1_b  = (const float*)d_in[5];
    const float* bn1_m  = (const float*)d_in[6];
    const float* bn1_v  = (const float*)d_in[7];
    const float* pw_w   = (const float*)d_in[8];
    const float* bn2_g  = (const float*)d_in[9];
    const float* bn2_b  = (const float*)d_in[10];
    const float* bn2_m  = (const float*)d_in[11];
    const float* bn2_v  = (const float*)d_in[12];
    const float* aff_w  = (const float*)d_in[13];
    const float* loc_w1 = (const float*)d_in[14];
    const float* loc_b1 = (const float*)d_in[15];
    const float* loc_w2 = (const float*)d_in[16];
    const float* loc_b2 = (const float*)d_in[17];
    const float* glb_w1 = (const float*)d_in[18];
    const float* glb_b1 = (const float*)d_in[19];
    const float* glb_w2 = (const float*)d_in[20];
    const float* glb_b2 = (const float*)d_in[21];
    const float* ln_g   = (const float*)d_in[22];
    const float* ln_b   = (const float*)d_in[23];
    const float* topo   = (const float*)d_in[24];
    const float* orient = (const float*)d_in[25];
    const float* proto_orient = (const float*)d_in[26];
    float* out = (float*)d_out;
    float* ws  = (float*)d_ws;

    float* ei      = ws;                                       // 524288 f
    unsigned short* logitsH = (unsigned short*)(ws + 1048576); // 8,388,608 ushort
    float* ppart   = ws + 5242880;                             // 1,048,576 f
    float* k3part  = ws + 6291456;                             // 1024
    float* smpart  = ws + 6292480;                             // 32768
    float* proto   = ws + 6325248;                             // 8192
    float* scsh    = ws + 6333440;                             // 256
    unsigned short* pwA  = (unsigned short*)(ws + 6333696);    // 4096 ushort
    unsigned short* affA = (unsigned short*)(ws + 6335744);    // 1024 ushort
    // total ~6,336,256 f32 = 25.3 MB

    k_prep<<<1, 256, 0, stream>>>(pw_w, aff_w, bn1_g, bn1_b, bn1_m, bn1_v,
                                  bn2_g, bn2_b, bn2_m, bn2_v, scsh, pwA, affA);
    k_conv_aff<<<2048, 256, 0, stream>>>(feat, dw_w, scsh, pwA, affA, logitsH, ei);
    k_sobel_stats<<<dim3(64, 8), 256, 0, stream>>>(ei, k3part);
    k_smproto<<<dim3(128, 8), 256, 0, stream>>>(logitsH, ei, k3part, proto_orient,
                                                topo, orient, key, smpart, ppart);
    k_reduce<<<dim3(16, 8), 256, 0, stream>>>(smpart, ppart, proto);
    k_gate<<<8, 256, 0, stream>>>(proto, query, loc_w1, loc_b1, loc_w2, loc_b2,
                                  glb_w1, glb_b1, glb_w2, glb_b2, ln_g, ln_b, out);
}

// Round 9
// 128.210 us; speedup vs baseline: 4.2638x; 1.0207x over previous
//
#include <hip/hip_runtime.h>
#include <hip/hip_fp16.h>
#include <math.h>

#define HW     65536
#define WIDTH  256
#define HEIGHT 256

typedef __attribute__((ext_vector_type(8))) short bf16x8;
typedef __attribute__((ext_vector_type(4))) float f32x4;

__device__ __forceinline__ float relu_f(float x){ return x > 0.f ? x : 0.f; }
__device__ __forceinline__ unsigned int f2bf(float x){
    union { float f; unsigned int u; } v; v.f = x;
    unsigned int r = v.u + 0x7fffu + ((v.u >> 16) & 1u);   // RNE
    return r >> 16;
}
__device__ __forceinline__ float bfbits2f(unsigned int lo16){
    union { unsigned int u; float f; } v; v.u = lo16 << 16; return v.f;
}
__device__ __forceinline__ float h2f(unsigned int bits16){
    __half h = *(__half*)&bits16; return __half2float(h);
}

// ---------------- K0: prep — fold BN, pack MFMA A-fragments ----------------
__global__ void k_prep(const float* __restrict__ pw_w, const float* __restrict__ aff_w,
                       const float* __restrict__ g1, const float* __restrict__ b1,
                       const float* __restrict__ m1, const float* __restrict__ v1,
                       const float* __restrict__ g2, const float* __restrict__ b2,
                       const float* __restrict__ m2, const float* __restrict__ v2,
                       float* __restrict__ scsh, unsigned short* __restrict__ pwA,
                       unsigned short* __restrict__ affA){
    int t = threadIdx.x;
    for (int i = t; i < 4096; i += 256){
        int e = i & 7, l = (i >> 3) & 63, ks = (i >> 9) & 1, ct = i >> 10;
        int co = ct * 16 + (l & 15);
        int ci = ks * 32 + (l >> 4) * 8 + e;
        pwA[i] = (unsigned short)f2bf(pw_w[co * 64 + ci]);
    }
    for (int i = t; i < 1024; i += 256){
        int e = i & 7, l = (i >> 3) & 63, ks = i >> 9;
        int p = l & 15, k = ks * 32 + (l >> 4) * 8 + e;
        affA[i] = (unsigned short)f2bf(aff_w[p * 64 + k]);
    }
    if (t < 64){
        float s = g1[t] * rsqrtf(v1[t] + 1e-5f);
        scsh[t]       = s;
        scsh[64 + t]  = b1[t] - m1[t] * s;
        float s2 = g2[t] * rsqrtf(v2[t] + 1e-5f);
        scsh[128 + t] = s2;
        scsh[192 + t] = b2[t] - m2[t] * s2;
    }
}

// ---------------- K2: full-row dw3x3 -> MFMA pw -> MFMA affinity -> f16 logits [b][l][16] ----------------
__global__ __launch_bounds__(256, 4) void k_conv_aff(
    const float* __restrict__ feat, const float* __restrict__ dw_w,
    const float* __restrict__ scsh, const unsigned short* __restrict__ pwA,
    const unsigned short* __restrict__ affA,
    unsigned short* __restrict__ logitsH, float* __restrict__ ei)
{
    __shared__ unsigned short x1u[256 * 68];
    __shared__ float eibuf[4][256];
    int t = threadIdx.x;
    int lane = t & 63;
    int wu = __builtin_amdgcn_readfirstlane(t >> 6);
    int orig = blockIdx.x;
    int flat = (orig & 7) * 256 + (orig >> 3);   // XCD-bijective (2048 = 8*256)
    int b = flat >> 8, h = flat & 255;

    const bf16x8* pwA8 = (const bf16x8*)pwA;
    bf16x8 apw0 = pwA8[(wu * 2 + 0) * 64 + lane];
    bf16x8 apw1 = pwA8[(wu * 2 + 1) * 64 + lane];
    const bf16x8* affA8 = (const bf16x8*)affA;
    bf16x8 aaf0 = affA8[lane];
    bf16x8 aaf1 = affA8[64 + lane];
    int lcol = lane & 15, pq = lane >> 4;
    int cb = wu * 16 + pq * 4;
    float4 sc2v = *(const float4*)(scsh + 128 + cb);
    float4 sh2v = *(const float4*)(scsh + 192 + cb);

    // ---- phase A
    int px0 = lane * 4;
    const float* fb = feat + (size_t)b * 64 * HW;
    int hh0 = (h > 0) ? h - 1 : 0;
    int hh2 = (h < 255) ? h + 1 : 255;
    float rw0 = (h > 0) ? 1.f : 0.f;
    float rw2 = (h < 255) ? 1.f : 0.f;
    int   roff0 = hh0 * WIDTH, roff1 = h * WIDTH, roff2 = hh2 * WIDTH;
    float mx = 0.f, my = 0.f, mz = 0.f, mw = 0.f;
    int swz = ((lane >> 2) & 7) << 1;
    #pragma unroll
    for (int cp = 0; cp < 8; cp++){
        int ci0 = wu * 16 + cp * 2;
        int ci1 = ci0 + 1;
        const float* base0 = fb + (size_t)ci0 * HW + px0;
        const float* base1 = fb + (size_t)ci1 * HW + px0;
        float a00=0.f,a01=0.f,a02=0.f,a03=0.f, a10=0.f,a11=0.f,a12=0.f,a13=0.f;
        #pragma unroll
        for (int r = 0; r < 3; r++){
            int roff = (r == 0) ? roff0 : ((r == 1) ? roff1 : roff2);
            float rwf = (r == 0) ? rw0 : ((r == 1) ? 1.f : rw2);
            float4 v0 = *(const float4*)(base0 + roff);
            float4 v1 = *(const float4*)(base1 + roff);
            float w00 = dw_w[ci0*9 + r*3 + 0] * rwf;
            float w01 = dw_w[ci0*9 + r*3 + 1] * rwf;
            float w02 = dw_w[ci0*9 + r*3 + 2] * rwf;
            float w10 = dw_w[ci1*9 + r*3 + 0] * rwf;
            float w11 = dw_w[ci1*9 + r*3 + 1] * rwf;
            float w12 = dw_w[ci1*9 + r*3 + 2] * rwf;
            float lf0 = __shfl_up(v0.w, 1);  if (lane == 0)  lf0 = 0.f;
            float rt0 = __shfl_down(v0.x, 1); if (lane == 63) rt0 = 0.f;
            float lf1 = __shfl_up(v1.w, 1);  if (lane == 0)  lf1 = 0.f;
            float rt1 = __shfl_down(v1.x, 1); if (lane == 63) rt1 = 0.f;
            a00 += lf0*w00 + v0.x*w01 + v0.y*w02;
            a01 += v0.x*w00 + v0.y*w01 + v0.z*w02;
            a02 += v0.y*w00 + v0.z*w01 + v0.w*w02;
            a03 += v0.z*w00 + v0.w*w01 + rt0*w02;
            a10 += lf1*w10 + v1.x*w11 + v1.y*w12;
            a11 += v1.x*w10 + v1.y*w11 + v1.z*w12;
            a12 += v1.y*w10 + v1.z*w11 + v1.w*w12;
            a13 += v1.z*w10 + v1.w*w11 + rt1*w12;
            if (r == 1){
                mx += v0.x + v1.x; my += v0.y + v1.y;
                mz += v0.z + v1.z; mw += v0.w + v1.w;
            }
        }
        float s0 = scsh[ci0], o0 = scsh[64 + ci0];
        float s1 = scsh[ci1], o1 = scsh[64 + ci1];
        int dwi = ((wu * 8 + cp) ^ swz) * 2;
        unsigned int pk0 = f2bf(relu_f(fmaf(a00,s0,o0))) | (f2bf(relu_f(fmaf(a10,s1,o1))) << 16);
        unsigned int pk1 = f2bf(relu_f(fmaf(a01,s0,o0))) | (f2bf(relu_f(fmaf(a11,s1,o1))) << 16);
        unsigned int pk2 = f2bf(relu_f(fmaf(a02,s0,o0))) | (f2bf(relu_f(fmaf(a12,s1,o1))) << 16);
        unsigned int pk3 = f2bf(relu_f(fmaf(a03,s0,o0))) | (f2bf(relu_f(fmaf(a13,s1,o1))) << 16);
        *(unsigned int*)&x1u[(px0 + 0) * 68 + dwi] = pk0;
        *(unsigned int*)&x1u[(px0 + 1) * 68 + dwi] = pk1;
        *(unsigned int*)&x1u[(px0 + 2) * 68 + dwi] = pk2;
        *(unsigned int*)&x1u[(px0 + 3) * 68 + dwi] = pk3;
    }
    *(float4*)&eibuf[wu][px0] = make_float4(mx, my, mz, mw);
    __syncthreads();
    {
        float m = (eibuf[0][t] + eibuf[1][t]) + (eibuf[2][t] + eibuf[3][t]);
        ei[(size_t)b * HW + h * WIDTH + t] = m * (1.f / 64.f);
    }

    // ---- phase B
    int k0d = pq * 4;
    #pragma unroll
    for (int half = 0; half < 2; half++){
        f32x4 accB[8];
        #pragma unroll
        for (int q = 0; q < 8; q++){
            int jt = half * 8 + q;
            int swzj = (jt & 7) << 1;
            const unsigned short* rowp = &x1u[(jt * 16 + lcol) * 68];
            union { bf16x8 v; uint2 u[2]; } b0, b1;
            b0.u[0] = *(const uint2*)&rowp[((k0d)          ^ swzj) * 2];
            b0.u[1] = *(const uint2*)&rowp[((k0d + 2)      ^ swzj) * 2];
            b1.u[0] = *(const uint2*)&rowp[((16 + k0d)     ^ swzj) * 2];
            b1.u[1] = *(const uint2*)&rowp[((16 + k0d + 2) ^ swzj) * 2];
            f32x4 acc = {0.f, 0.f, 0.f, 0.f};
            acc = __builtin_amdgcn_mfma_f32_16x16x32_bf16(apw0, b0.v, acc, 0, 0, 0);
            acc = __builtin_amdgcn_mfma_f32_16x16x32_bf16(apw1, b1.v, acc, 0, 0, 0);
            accB[q] = acc;
        }
        __syncthreads();
        #pragma unroll
        for (int q = 0; q < 8; q++){
            int jt = half * 8 + q;
            int swzj = (jt & 7) << 1;
            f32x4 acc = accB[q];
            unsigned int y0 = f2bf(relu_f(fmaf(acc[0], sc2v.x, sh2v.x)))
                            | (f2bf(relu_f(fmaf(acc[1], sc2v.y, sh2v.y))) << 16);
            unsigned int y1 = f2bf(relu_f(fmaf(acc[2], sc2v.z, sh2v.z)))
                            | (f2bf(relu_f(fmaf(acc[3], sc2v.w, sh2v.w))) << 16);
            int D = (wu * 8 + pq * 2) ^ swzj;
            *(uint2*)&x1u[(jt * 16 + lcol) * 68 + D * 2] = make_uint2(y0, y1);
        }
    }
    __syncthreads();

    // ---- phase C: affinity GEMM -> f16 logits, layout [b][l][16p]
    int p0 = pq * 4;
    #pragma unroll
    for (int q = 0; q < 4; q++){
        int jt = wu * 4 + q;
        int swzj = (jt & 7) << 1;
        const unsigned short* rowp = &x1u[(jt * 16 + lcol) * 68];
        union { bf16x8 v; uint2 u[2]; } b0, b1;
        b0.u[0] = *(const uint2*)&rowp[((k0d)          ^ swzj) * 2];
        b0.u[1] = *(const uint2*)&rowp[((k0d + 2)      ^ swzj) * 2];
        b1.u[0] = *(const uint2*)&rowp[((16 + k0d)     ^ swzj) * 2];
        b1.u[1] = *(const uint2*)&rowp[((16 + k0d + 2) ^ swzj) * 2];
        f32x4 acc = {0.f, 0.f, 0.f, 0.f};
        acc = __builtin_amdgcn_mfma_f32_16x16x32_bf16(aaf0, b0.v, acc, 0, 0, 0);
        acc = __builtin_amdgcn_mfma_f32_16x16x32_bf16(aaf1, b1.v, acc, 0, 0, 0);
        int gx = h * WIDTH + jt * 16 + lcol;
        __half h0 = __float2half(acc[0]), h1v = __float2half(acc[1]);
        __half h2 = __float2half(acc[2]), h3v = __float2half(acc[3]);
        unsigned int u0 = (unsigned int)(*(unsigned short*)&h0)
                        | ((unsigned int)(*(unsigned short*)&h1v) << 16);
        unsigned int u1 = (unsigned int)(*(unsigned short*)&h2)
                        | ((unsigned int)(*(unsigned short*)&h3v) << 16);
        *(uint2*)&logitsH[((size_t)b * HW + gx) * 16 + p0] = make_uint2(u0, u1);
    }
}

// ---------------- K3: Sobel stats, row-based (coalesced float4 + shuffles) ----------------
__global__ __launch_bounds__(256) void k_sobel_stats(const float* __restrict__ ei,
                                                     float* __restrict__ part){
    int ch = blockIdx.x, b = blockIdx.y, t = threadIdx.x;
    int lane = t & 63, w = t >> 6;
    int h = ch * 4 + w;
    int px0 = lane * 4;
    const float* e = ei + (size_t)b * HW;
    int hh0 = (h > 0) ? h - 1 : 0;
    int hh2 = (h < 255) ? h + 1 : 255;
    float rw0 = (h > 0) ? 1.f : 0.f;
    float rw2 = (h < 255) ? 1.f : 0.f;
    float4 v0 = *(const float4*)(e + hh0 * WIDTH + px0);
    float4 v1 = *(const float4*)(e + h   * WIDTH + px0);
    float4 v2 = *(const float4*)(e + hh2 * WIDTH + px0);
    v0.x *= rw0; v0.y *= rw0; v0.z *= rw0; v0.w *= rw0;
    v2.x *= rw2; v2.y *= rw2; v2.z *= rw2; v2.w *= rw2;
    float l0 = __shfl_up(v0.w, 1);   if (lane == 0)  l0 = 0.f;
    float r0 = __shfl_down(v0.x, 1); if (lane == 63) r0 = 0.f;
    float l1 = __shfl_up(v1.w, 1);   if (lane == 0)  l1 = 0.f;
    float r1 = __shfl_down(v1.x, 1); if (lane == 63) r1 = 0.f;
    float l2 = __shfl_up(v2.w, 1);   if (lane == 0)  l2 = 0.f;
    float r2 = __shfl_down(v2.x, 1); if (lane == 63) r2 = 0.f;
    // columns: [l, v.x, v.y, v.z, v.w, r] per row
    float t0[6]  = {l0, v0.x, v0.y, v0.z, v0.w, r0};
    float m1a[6] = {l1, v1.x, v1.y, v1.z, v1.w, r1};
    float b2a[6] = {l2, v2.x, v2.y, v2.z, v2.w, r2};
    float s1 = 0.f, s2 = 0.f;
    #pragma unroll
    for (int j = 0; j < 4; j++){
        float gx = (t0[j+2] - t0[j]) + 2.f*(m1a[j+2] - m1a[j]) + (b2a[j+2] - b2a[j]);
        float gy = (b2a[j] + 2.f*b2a[j+1] + b2a[j+2]) - (t0[j] + 2.f*t0[j+1] + t0[j+2]);
        float esv = sqrtf(gx*gx + gy*gy + 1e-6f);
        s1 += esv; s2 += esv * esv;
    }
    #pragma unroll
    for (int off = 32; off >= 1; off >>= 1){
        s1 += __shfl_xor(s1, off, 64);
        s2 += __shfl_xor(s2, off, 64);
    }
    __shared__ float rs1[4], rs2[4];
    if (lane == 0){ rs1[w] = s1; rs2[w] = s2; }
    __syncthreads();
    if (t == 0)
        part[(b*64+ch)*2]     = (rs1[0] + rs1[1]) + (rs1[2] + rs1[3]);
    if (t == 1)
        part[(b*64+ch)*2 + 1] = (rs2[0] + rs2[1]) + (rs2[2] + rs2[3]);
}

// ---------------- K4+K5 merged: softmax (weights in LDS) + prototype partials ----------------
__global__ __launch_bounds__(256) void k_smproto(
    const unsigned short* __restrict__ logitsH, const float* __restrict__ ei,
    const float* __restrict__ part, const float* __restrict__ proto_orient,
    const float* __restrict__ topo_s, const float* __restrict__ orient_s,
    const float* __restrict__ key,
    float* __restrict__ smpart, float* __restrict__ ppart)
{
    int ch = blockIdx.x, b = blockIdx.y, t = threadIdx.x;
    __shared__ float eit[4][258];
    __shared__ float sstat[3];
    __shared__ float pdl[32];
    __shared__ float Ml[16];
    __shared__ float rm[4][16], rs[4][16];
    __shared__ unsigned int wlds[512][10];   // bf16-pair weights [tok][p-pair]

    // ---- pass 0: ei tile + batch stats + proto dirs
    for (int i = t; i < 1024; i += 256){
        int r = i >> 8, c = i & 255;
        int row = 2 * ch - 1 + r;
        eit[r][c + 1] = (row >= 0 && row < 256) ? ei[(size_t)b * HW + row * 256 + c] : 0.f;
    }
    if (t >= 128 && t < 136){
        int q = t - 128;
        eit[q >> 1][(q & 1) * 257] = 0.f;
    }
    if (t < 64){
        float s1 = part[(b*64 + t)*2], s2 = part[(b*64 + t)*2 + 1];
        #pragma unroll
        for (int off = 32; off >= 1; off >>= 1){
            s1 += __shfl_xor(s1, off, 64);
            s2 += __shfl_xor(s2, off, 64);
        }
        if (t == 0){
            float mean = s1 / 65536.f;
            float var = (s2 - 65536.f * mean * mean) / 65535.f;
            var = var > 0.f ? var : 0.f;
            sstat[0] = mean;
            sstat[1] = 1.f / (sqrtf(var) + 1e-5f);
            sstat[2] = 1.f / (mean + 1e-6f);
        }
    } else if (t >= 64 && t < 80){
        int p = t - 64;
        float nx = proto_orient[p*2], ny = proto_orient[p*2+1];
        float n = sqrtf(nx*nx + ny*ny);
        n = n > 1e-12f ? n : 1e-12f;
        pdl[p*2] = nx / n; pdl[p*2+1] = ny / n;
    }
    __syncthreads();
    float mean = sstat[0], rstd = sstat[1], cinv = sstat[2];
    float topo = topo_s[0], orient = orient_s[0];

    // ---- pass 1: softmax stats from register-cached logits
    float m[16], s[16];
    #pragma unroll
    for (int p = 0; p < 16; p++){ m[p] = -1e30f; s[p] = 0.f; }
    uint4 pkA0, pkA1, pkB0, pkB1;
    {
        size_t gl0 = ((size_t)b * HW + ch * 512 + t) * 16;
        size_t gl1 = ((size_t)b * HW + ch * 512 + 256 + t) * 16;
        pkA0 = *(const uint4*)&logitsH[gl0];
        pkA1 = *(const uint4*)&logitsH[gl0 + 8];
        pkB0 = *(const uint4*)&logitsH[gl1];
        pkB1 = *(const uint4*)&logitsH[gl1 + 8];
    }
    float ewv[2], oxv[2], oyv[2];
    #pragma unroll
    for (int i = 0; i < 2; i++){
        int hl = i + 1, w = t;
        float vmm = eit[hl-1][w], vm0 = eit[hl-1][w+1], vmp = eit[hl-1][w+2];
        float v0m = eit[hl][w],                          v0p = eit[hl][w+2];
        float vpm = eit[hl+1][w], vp0 = eit[hl+1][w+1], vpp = eit[hl+1][w+2];
        float gx = vmp - vmm + 2.f*(v0p - v0m) + vpp - vpm;
        float gy = vpm + 2.f*vp0 + vpp - vmm - 2.f*vm0 - vmp;
        float denom = gx*gx + gy*gy + 1e-6f;
        float esv = sqrtf(denom);
        float cf = fminf(fmaxf(esv * cinv, 0.f), 3.f);
        ewv[i] = (esv - mean) * rstd;
        oxv[i] = ((gx*gx - gy*gy) / denom) * cf;
        oyv[i] = (2.f * gx * gy / denom) * cf;
        const uint4& q0 = (i == 0) ? pkA0 : pkB0;
        const uint4& q1 = (i == 0) ? pkA1 : pkB1;
        unsigned int wv[8] = {q0.x, q0.y, q0.z, q0.w, q1.x, q1.y, q1.z, q1.w};
        #pragma unroll
        for (int p = 0; p < 16; p++){
            unsigned int bits = (p & 1) ? (wv[p >> 1] >> 16) : (wv[p >> 1] & 0xffffu);
            float x = h2f(bits) + topo * ewv[i]
                    + orient * (oxv[i]*pdl[p*2] + oyv[i]*pdl[p*2+1]);
            float mn = fmaxf(m[p], x);
            s[p] = s[p] * __expf(m[p] - mn) + __expf(x - mn);
            m[p] = mn;
        }
    }
    #pragma unroll
    for (int p = 0; p < 16; p++){
        #pragma unroll
        for (int off = 32; off >= 1; off >>= 1){
            float m2 = __shfl_xor(m[p], off, 64);
            float s2v = __shfl_xor(s[p], off, 64);
            float mn = fmaxf(m[p], m2);
            s[p] = s[p] * __expf(m[p] - mn) + s2v * __expf(m2 - mn);
            m[p] = mn;
        }
    }
    int wid = t >> 6;
    if ((t & 63) == 0){
        #pragma unroll
        for (int p = 0; p < 16; p++){ rm[wid][p] = m[p]; rs[wid][p] = s[p]; }
    }
    __syncthreads();
    if (t < 16){
        float M = -1e30f, S = 0.f;
        #pragma unroll
        for (int w2 = 0; w2 < 4; w2++){
            float mw = rm[w2][t], sw2 = rs[w2][t];
            float mn = fmaxf(M, mw);
            S = S * __expf(M - mn) + sw2 * __expf(mw - mn);
            M = mn;
        }
        smpart[((b*16 + t)*128 + ch)*2]     = M;
        smpart[((b*16 + t)*128 + ch)*2 + 1] = S;
        Ml[t] = M;
    }
    __syncthreads();
    float Mloc[16];
    #pragma unroll
    for (int p = 0; p < 16; p++) Mloc[p] = Ml[p];

    // ---- pass 2: per-token weights (bf16 pairs) -> LDS
    #pragma unroll
    for (int i = 0; i < 2; i++){
        int tok = i * 256 + t;
        const uint4& q0 = (i == 0) ? pkA0 : pkB0;
        const uint4& q1 = (i == 0) ? pkA1 : pkB1;
        unsigned int wv[8] = {q0.x, q0.y, q0.z, q0.w, q1.x, q1.y, q1.z, q1.w};
        #pragma unroll
        for (int p2 = 0; p2 < 8; p2++){
            int pa = p2*2, pb2 = p2*2 + 1;
            float xa = h2f(wv[p2] & 0xffffu) + topo*ewv[i]
                     + orient*(oxv[i]*pdl[pa*2]  + oyv[i]*pdl[pa*2+1]);
            float xb = h2f(wv[p2] >> 16) + topo*ewv[i]
                     + orient*(oxv[i]*pdl[pb2*2] + oyv[i]*pdl[pb2*2+1]);
            wlds[tok][p2] = f2bf(__expf(xa - Mloc[pa])) | (f2bf(__expf(xb - Mloc[pb2])) << 16);
        }
    }
    __syncthreads();

    // ---- pass 3: coalesced key stream; each lane: one token-phase g, c-slice cg, ALL p
    int w = t >> 6, lane = t & 63, cg = lane & 15, g = lane >> 4;
    const float4* kp = (const float4*)key + ((size_t)b * HW + ch * 512 + w * 128) * 16;
    float acc[16][4];
    #pragma unroll
    for (int p = 0; p < 16; p++)
        #pragma unroll
        for (int i = 0; i < 4; i++) acc[p][i] = 0.f;
    #pragma unroll 4
    for (int blk = 0; blk < 32; blk++){
        int tok = blk * 4 + g;
        float4 kv = kp[tok * 16 + cg];          // wave covers 4 full tokens = 1 KB
        const unsigned int* wp = &wlds[w * 128 + tok][0];
        uint2 q0 = *(const uint2*)&wp[0];
        uint2 q1 = *(const uint2*)&wp[2];
        uint2 q2 = *(const uint2*)&wp[4];
        uint2 q3 = *(const uint2*)&wp[6];
        unsigned int ww[8] = {q0.x, q0.y, q1.x, q1.y, q2.x, q2.y, q3.x, q3.y};
        #pragma unroll
        for (int p2 = 0; p2 < 8; p2++){
            float wa = bfbits2f(ww[p2] & 0xffffu);
            float wb = bfbits2f(ww[p2] >> 16);
            int pa = 2*p2, pb2 = 2*p2 + 1;
            acc[pa][0] = fmaf(wa, kv.x, acc[pa][0]);
            acc[pa][1] = fmaf(wa, kv.y, acc[pa][1]);
            acc[pa][2] = fmaf(wa, kv.z, acc[pa][2]);
            acc[pa][3] = fmaf(wa, kv.w, acc[pa][3]);
            acc[pb2][0] = fmaf(wb, kv.x, acc[pb2][0]);
            acc[pb2][1] = fmaf(wb, kv.y, acc[pb2][1]);
            acc[pb2][2] = fmaf(wb, kv.z, acc[pb2][2]);
            acc[pb2][3] = fmaf(wb, kv.w, acc[pb2][3]);
        }
    }
    // fold the 4 token-phase groups (lane bits 4,5)
    #pragma unroll
    for (int p = 0; p < 16; p++)
        #pragma unroll
        for (int i = 0; i < 4; i++){
            acc[p][i] += __shfl_xor(acc[p][i], 16, 64);
            acc[p][i] += __shfl_xor(acc[p][i], 32, 64);
        }
    __syncthreads();                 // all wlds reads done
    float (*red)[16][68] = (float (*)[16][68])wlds;   // alias: 17408 B <= 20480 B
    if (g == 0){
        #pragma unroll
        for (int p = 0; p < 16; p++)
            *(float4*)&red[w][p][cg*4] =
                make_float4(acc[p][0], acc[p][1], acc[p][2], acc[p][3]);
    }
    __syncthreads();
    size_t obase = ((size_t)(b * 128 + ch)) * 1024;
    for (int idx = t; idx < 1024; idx += 256){
        int p = idx >> 6, c = idx & 63;
        ppart[obase + idx] = red[0][p][c] + red[1][p][c] + red[2][p][c] + red[3][p][c];
    }
}

// ---------------- K6: apply per-chunk softmax scale + reduce -> proto ----------------
__global__ __launch_bounds__(256) void k_reduce(
    const float* __restrict__ smpart, const float* __restrict__ ppart,
    float* __restrict__ proto)
{
    int p = blockIdx.x, b = blockIdx.y, t = threadIdx.x;
    __shared__ float arr[128], flv[128], partial[4][64];
    float Mt = -1e30f, St = 0.f;
    if (t < 128){
        Mt = smpart[((b*16 + p)*128 + t)*2];
        St = smpart[((b*16 + p)*128 + t)*2 + 1];
        arr[t] = Mt;
    }
    __syncthreads();
    for (int s = 64; s > 0; s >>= 1){
        if (t < s) arr[t] = fmaxf(arr[t], arr[t + s]);
        __syncthreads();
    }
    float M = arr[0];
    __syncthreads();
    if (t < 128) arr[t] = St * __expf(Mt - M);
    __syncthreads();
    for (int s = 64; s > 0; s >>= 1){
        if (t < s) arr[t] += arr[t + s];
        __syncthreads();
    }
    float Stot = arr[0];
    __syncthreads();
    if (t < 128) flv[t] = __expf(Mt - M) / Stot;
    __syncthreads();
    int c = t & 63, half = t >> 6;
    float acc = 0.f;
    #pragma unroll 8
    for (int j = 0; j < 32; j++){
        int ch = half * 32 + j;
        acc += flv[ch] * ppart[((size_t)(b * 128 + ch)) * 1024 + p * 64 + c];
    }
    partial[half][c] = acc;
    __syncthreads();
    if (t < 64)
        proto[b * 1024 + p * 64 + t] =
            (partial[0][t] + partial[1][t]) + (partial[2][t] + partial[3][t]);
}

// ---------------- K7: gate MLPs + sigmoid + LayerNorm ----------------
__global__ __launch_bounds__(256) void k_gate(
    const float* __restrict__ proto, const float* __restrict__ query,
    const float* __restrict__ w1, const float* __restrict__ bb1,
    const float* __restrict__ w2, const float* __restrict__ bb2,
    const float* __restrict__ gw1, const float* __restrict__ gb1,
    const float* __restrict__ gw2, const float* __restrict__ gb2,
    const float* __restrict__ lng, const float* __restrict__ lnb,
    float* __restrict__ out)
{
    __shared__ float z[16][64], h1[16][64], loc[16][64], g[64], hg[64], glb[64];
    int b = blockIdx.x, t = threadIdx.x;
    for (int idx = t; idx < 1024; idx += 256)
        z[idx >> 6][idx & 63] = proto[b * 1024 + idx] + query[b * 1024 + idx];
    __syncthreads();
    for (int idx = t; idx < 1024; idx += 256){
        int p = idx >> 6, j = idx & 63;
        float acc = bb1[j];
        for (int i = 0; i < 64; i++) acc += z[p][i] * w1[j * 64 + i];
        h1[p][j] = relu_f(acc);
    }
    if (t < 64){
        float sg = 0.f;
        for (int p = 0; p < 16; p++) sg += z[p][t];
        g[t] = sg * (1.f / 16.f);
    }
    __syncthreads();
    for (int idx = t; idx < 1024; idx += 256){
        int p = idx >> 6, k = idx & 63;
        float acc = bb2[k];
        for (int j = 0; j < 64; j++) acc += h1[p][j] * w2[k * 64 + j];
        loc[p][k] = acc;
    }
    if (t < 64){
        float acc = gb1[t];
        for (int i = 0; i < 64; i++) acc += g[i] * gw1[t * 64 + i];
        hg[t] = relu_f(acc);
    }
    __syncthreads();
    if (t < 64){
        float acc = gb2[t];
        for (int j = 0; j < 64; j++) acc += hg[j] * gw2[t * 64 + j];
        glb[t] = acc;
    }
    __syncthreads();
    for (int idx = t; idx < 1024; idx += 256){
        int p = idx >> 6, c = idx & 63;
        float a = loc[p][c] + glb[c];
        float sg = 1.f / (1.f + expf(-a));
        float q = query[b * 1024 + idx];
        h1[p][c] = q * sg + q;
    }
    __syncthreads();
    if (t < 16){
        int p = t;
        float mu = 0.f;
        for (int c = 0; c < 64; c++) mu += h1[p][c];
        mu *= (1.f / 64.f);
        float var = 0.f;
        for (int c = 0; c < 64; c++){ float d = h1[p][c] - mu; var += d * d; }
        var *= (1.f / 64.f);
        float rstd = rsqrtf(var + 1e-5f);
        for (int c = 0; c < 64; c++)
            out[b * 1024 + p * 64 + c] = (h1[p][c] - mu) * rstd * lng[c] + lnb[c];
    }
}

extern "C" void kernel_launch(void* const* d_in, const int* in_sizes, int n_in,
                              void* d_out, int out_size, void* d_ws, size_t ws_size,
                              hipStream_t stream){
    (void)in_sizes; (void)n_in; (void)out_size; (void)ws_size;
    const float* feat   = (const float*)d_in[0];
    const float* query  = (const float*)d_in[1];
    const float* key    = (const float*)d_in[2];
    const float* dw_w   = (const float*)d_in[3];
    const float* bn1_g  = (const float*)d_in[4];
    const float* bn1_b  = (const float*)d_in[5];
    const float* bn1_m  = (const float*)d_in[6];
    const float* bn1_v  = (const float*)d_in[7];
    const float* pw_w   = (const float*)d_in[8];
    const float* bn2_g  = (const float*)d_in[9];
    const float* bn2_b  = (const float*)d_in[10];
    const float* bn2_m  = (const float*)d_in[11];
    const float* bn2_v  = (const float*)d_in[12];
    const float* aff_w  = (const float*)d_in[13];
    const float* loc_w1 = (const float*)d_in[14];
    const float* loc_b1 = (const float*)d_in[15];
    const float* loc_w2 = (const float*)d_in[16];
    const float* loc_b2 = (const float*)d_in[17];
    const float* glb_w1 = (const float*)d_in[18];
    const float* glb_b1 = (const float*)d_in[19];
    const float* glb_w2 = (const float*)d_in[20];
    const float* glb_b2 = (const float*)d_in[21];
    const float* ln_g   = (const float*)d_in[22];
    const float* ln_b   = (const float*)d_in[23];
    const float* topo   = (const float*)d_in[24];
    const float* orient = (const float*)d_in[25];
    const float* proto_orient = (const float*)d_in[26];
    float* out = (float*)d_out;
    float* ws  = (float*)d_ws;

    float* ei      = ws;                                       // 524288 f
    unsigned short* logitsH = (unsigned short*)(ws + 1048576); // 8,388,608 ushort
    float* ppart   = ws + 5242880;                             // 1,048,576 f
    float* k3part  = ws + 6291456;                             // 1024
    float* smpart  = ws + 6292480;                             // 32768
    float* proto   = ws + 6325248;                             // 8192
    float* scsh    = ws + 6333440;                             // 256
    unsigned short* pwA  = (unsigned short*)(ws + 6333696);    // 4096 ushort
    unsigned short* affA = (unsigned short*)(ws + 6335744);    // 1024 ushort

    k_prep<<<1, 256, 0, stream>>>(pw_w, aff_w, bn1_g, bn1_b, bn1_m, bn1_v,
                                  bn2_g, bn2_b, bn2_m, bn2_v, scsh, pwA, affA);
    k_conv_aff<<<2048, 256, 0, stream>>>(feat, dw_w, scsh, pwA, affA, logitsH, ei);
    k_sobel_stats<<<dim3(64, 8), 256, 0, stream>>>(ei, k3part);
    k_smproto<<<dim3(128, 8), 256, 0, stream>>>(logitsH, ei, k3part, proto_orient,
                                                topo, orient, key, smpart, ppart);
    k_reduce<<<dim3(16, 8), 256, 0, stream>>>(smpart, ppart, proto);
    k_gate<<<8, 256, 0, stream>>>(proto, query, loc_w1, loc_b1, loc_w2, loc_b2,
                                  glb_w1, glb_b1, glb_w2, glb_b2, ln_g, ln_b, out);
}